// Round 7
// baseline (593.799 us; speedup 1.0000x reference)
//
#include <hip/hip_runtime.h>
#include <hip/hip_bf16.h>
#include <math.h>

typedef __hip_bfloat16 bf16;
typedef __attribute__((ext_vector_type(8))) short short8;
typedef __attribute__((ext_vector_type(4))) float floatx4;

#define SEQ    2048
#define TTOK   4096
#define DM     1024
#define NHEAD  16
#define NKVH   4
#define HD     64
#define NEXP   8
#define HIDDEN 1365
#define HIDP   1408
#define CAPT   1280
#define NSLOT  (NEXP*CAPT)      /* 10240 routed slots */
#define TSLOT  (NSLOT+TTOK)     /* 14336: + shared-expert identity slots */
#define XPE    (CAPT/128)       /* 10 routed 128-row M-blocks per expert */
#define XBT    14               /* per-XCD 128-row M-blocks: 10 routed + 4 shared */

// ---------------------------------------------------------------- utilities
__device__ __forceinline__ void gld16(const void* g, void* l) {
  __builtin_amdgcn_global_load_lds((const __attribute__((address_space(1))) void*)g,
                                   (__attribute__((address_space(3))) void*)l,
                                   16, 0, 0);
}

struct __align__(8) bf4 { bf16 x, y, z, w; };

struct EpiAux {
  const float* cosb; const float* sinb;
  bf16* qb; bf16* kb; bf16* vb; float* newk; float* newv;
};

// ---------------------------------------------------- weight convert+transpose
// src: (K,N) f32 row-major -> dst: (N,Kp) bf16 row-major, zero-fill k in [K,Kp)
__global__ __launch_bounds__(256) void transpose_cvt(
    const float* __restrict__ src, bf16* __restrict__ dst,
    int K, int N, int Kp, long srcZ, long dstZ) {
  src += (size_t)blockIdx.z * srcZ;
  dst += (size_t)blockIdx.z * dstZ;
  __shared__ float tile[64][65];
  const int tid = threadIdx.x;
  const int k0 = blockIdx.y * 64, n0 = blockIdx.x * 64;
  const int lr = tid >> 4, lc = (tid & 15) * 4;
#pragma unroll
  for (int i = 0; i < 4; ++i) {
    int k = k0 + lr + i * 16;
    int n = n0 + lc;
    float4 v = {0.f, 0.f, 0.f, 0.f};
    if (k < K) {
      if (n + 3 < N) v = *(const float4*)(src + (size_t)k * N + n);
      else {
        float* vp = (float*)&v;
        for (int e = 0; e < 4; ++e) if (n + e < N) vp[e] = src[(size_t)k * N + n + e];
      }
    }
    tile[lr + i * 16][lc] = v.x; tile[lr + i * 16][lc + 1] = v.y;
    tile[lr + i * 16][lc + 2] = v.z; tile[lr + i * 16][lc + 3] = v.w;
  }
  __syncthreads();
  const int n = tid >> 2, kk0 = (tid & 3) * 16;
  if (n0 + n < N) {
    bf16 buf[16];
#pragma unroll
    for (int e = 0; e < 16; ++e) buf[e] = (bf16)tile[kk0 + e][n];
    bf16* dp = dst + (size_t)(n0 + n) * Kp + k0 + kk0;
    *(short8*)dp = *(short8*)buf;
    *(short8*)(dp + 8) = *(short8*)(buf + 8);
  }
}

// ---------------------------------------------------------------- rmsnorm
__global__ __launch_bounds__(256) void rmsnorm_kernel(
    const float* __restrict__ x, const float* __restrict__ w, bf16* __restrict__ out) {
  int t = blockIdx.x;
  const float* xr = x + (size_t)t * DM;
  float4 xv = *(const float4*)(xr + threadIdx.x * 4);
  float ss = xv.x * xv.x + xv.y * xv.y + xv.z * xv.z + xv.w * xv.w;
#pragma unroll
  for (int off = 1; off < 64; off <<= 1) ss += __shfl_xor(ss, off);
  __shared__ float sred[4];
  if ((threadIdx.x & 63) == 0) sred[threadIdx.x >> 6] = ss;
  __syncthreads();
  float scale = rsqrtf((sred[0] + sred[1] + sred[2] + sred[3]) * (1.f / DM) + 1e-6f);
  float4 wv = *(const float4*)(w + threadIdx.x * 4);
  bf4 o;
  o.x = (bf16)(xv.x * scale * wv.x); o.y = (bf16)(xv.y * scale * wv.y);
  o.z = (bf16)(xv.z * scale * wv.z); o.w = (bf16)(xv.w * scale * wv.w);
  ((bf4*)(out + (size_t)t * DM))[threadIdx.x] = o;
}

// -------------------------------------------- rmsnorm + router (moe path)
__global__ __launch_bounds__(256) void rmsnorm_router_kernel(
    const float* __restrict__ x, const float* __restrict__ w, const float* __restrict__ rw,
    bf16* __restrict__ out, float* __restrict__ probs,
    int* __restrict__ tIdx, float* __restrict__ tW) {
  int t = blockIdx.x;
  int tid = threadIdx.x, lane = tid & 63, wv = tid >> 6;
  const float* xr = x + (size_t)t * DM;
  float4 xv = *(const float4*)(xr + tid * 4);
  float ss = xv.x * xv.x + xv.y * xv.y + xv.z * xv.z + xv.w * xv.w;
#pragma unroll
  for (int off = 1; off < 64; off <<= 1) ss += __shfl_xor(ss, off);
  __shared__ float sred[4];
  __shared__ float red[4][8];
  if (lane == 0) sred[wv] = ss;
  __syncthreads();
  float scale = rsqrtf((sred[0] + sred[1] + sred[2] + sred[3]) * (1.f / DM) + 1e-6f);
  float4 wvv = *(const float4*)(w + tid * 4);
  float y[4] = {xv.x * scale * wvv.x, xv.y * scale * wvv.y,
                xv.z * scale * wvv.z, xv.w * scale * wvv.w};
  bf4 o; o.x = (bf16)y[0]; o.y = (bf16)y[1]; o.z = (bf16)y[2]; o.w = (bf16)y[3];
  ((bf4*)(out + (size_t)t * DM))[tid] = o;
  float acc[8] = {0, 0, 0, 0, 0, 0, 0, 0};
#pragma unroll
  for (int dd = 0; dd < 4; ++dd) {
    const float* rwr = rw + (size_t)(tid * 4 + dd) * 8;
#pragma unroll
    for (int e = 0; e < 8; ++e) acc[e] += y[dd] * rwr[e];
  }
#pragma unroll
  for (int e = 0; e < 8; ++e)
#pragma unroll
    for (int off = 1; off < 64; off <<= 1) acc[e] += __shfl_xor(acc[e], off);
  if (lane == 0)
#pragma unroll
    for (int e = 0; e < 8; ++e) red[wv][e] = acc[e];
  __syncthreads();
  if (tid == 0) {
    float lg[8];
#pragma unroll
    for (int e = 0; e < 8; ++e) lg[e] = red[0][e] + red[1][e] + red[2][e] + red[3][e];
    float mx = lg[0];
#pragma unroll
    for (int e = 1; e < 8; ++e) mx = fmaxf(mx, lg[e]);
    float p[8], se = 0.f;
#pragma unroll
    for (int e = 0; e < 8; ++e) { p[e] = __expf(lg[e] - mx); se += p[e]; }
#pragma unroll
    for (int e = 0; e < 8; ++e) { p[e] /= se; probs[t * 8 + e] = p[e]; }
    int i1 = 0;
#pragma unroll
    for (int e = 1; e < 8; ++e) if (p[e] > p[i1]) i1 = e;
    int i2 = (i1 == 0) ? 1 : 0;
#pragma unroll
    for (int e = 0; e < 8; ++e) if (e != i1 && p[e] > p[i2]) i2 = e;
    float s = p[i1] + p[i2];
    tIdx[t * 2] = i1; tIdx[t * 2 + 1] = i2;
    tW[t * 2] = p[i1] / s; tW[t * 2 + 1] = p[i2] / s;
  }
}

// ---------------------------------------------------------------- dense GEMM
// 64x128 tile. EPI: 2 = Cf = resid + acc (dup-stored to out2) ; 4 = QKV+rope
template <int EPI>
__global__ __launch_bounds__(256) void gemm_bt(
    const bf16* __restrict__ A, const bf16* __restrict__ Bt,
    int M, int N, int K, int lda, int ldb, int xPerXcd,
    float* __restrict__ Cf, int ldc,
    const float* __restrict__ resid, float* __restrict__ out2, EpiAux aux) {
  __shared__ __align__(16) bf16 As[64 * 64];
  __shared__ __align__(16) bf16 Bs[128 * 64];
  const int tid = threadIdx.x, lane = tid & 63, wave = tid >> 6;
  const int f = blockIdx.x, lo = f >> 3;
  int xb = (f & 7) * xPerXcd + lo % xPerXcd;
  int n0 = (lo / xPerXcd) * 128;
  int m0 = xb * 64;

  const bf16* aSrc[2]; const bf16* bSrc[4];
  bf16* aDst[2]; bf16* bDst[4];
#pragma unroll
  for (int it = 0; it < 2; ++it) {
    int c = it * 256 + tid;
    int r = c >> 3, q = c & 7;
    int kq = q ^ (r & 7);
    aSrc[it] = A + (long)(m0 + r) * lda + kq * 8;
    aDst[it] = As + (size_t)(it * 256 + wave * 64) * 8;
  }
#pragma unroll
  for (int it = 0; it < 4; ++it) {
    int c = it * 256 + tid;
    int r = c >> 3, q = c & 7;
    int kq = q ^ (r & 7);
    bSrc[it] = Bt + (long)(n0 + r) * ldb + kq * 8;
    bDst[it] = Bs + (size_t)(it * 256 + wave * 64) * 8;
  }

  floatx4 acc[2][4];
#pragma unroll
  for (int i = 0; i < 2; ++i)
#pragma unroll
    for (int j = 0; j < 4; ++j) { floatx4 z = {0.f, 0.f, 0.f, 0.f}; acc[i][j] = z; }

  const int wm = (wave & 1) * 32, wn = (wave >> 1) * 64;
  const int l15 = lane & 15, quad = lane >> 4;
  int aOff[2][2], bOff[4][2];
#pragma unroll
  for (int h = 0; h < 2; ++h) {
#pragma unroll
    for (int i = 0; i < 2; ++i) {
      int m = wm + i * 16 + l15;
      aOff[i][h] = (((m << 3) | ((h * 4 + quad) ^ (m & 7))) << 3);
    }
#pragma unroll
    for (int j = 0; j < 4; ++j) {
      int n = wn + j * 16 + l15;
      bOff[j][h] = (((n << 3) | ((h * 4 + quad) ^ (n & 7))) << 3);
    }
  }

  const int kIters = K >> 6;
  for (int kt = 0; kt < kIters; ++kt) {
    __syncthreads();
#pragma unroll
    for (int it = 0; it < 2; ++it) { gld16(aSrc[it], aDst[it]); aSrc[it] += 64; }
#pragma unroll
    for (int it = 0; it < 4; ++it) { gld16(bSrc[it], bDst[it]); bSrc[it] += 64; }
    __syncthreads();
#pragma unroll
    for (int h = 0; h < 2; ++h) {
      short8 af[2], bfr[4];
#pragma unroll
      for (int i = 0; i < 2; ++i) af[i] = *(const short8*)(As + aOff[i][h]);
#pragma unroll
      for (int j = 0; j < 4; ++j) bfr[j] = *(const short8*)(Bs + bOff[j][h]);
#pragma unroll
      for (int i = 0; i < 2; ++i)
#pragma unroll
        for (int j = 0; j < 4; ++j)
          acc[i][j] = __builtin_amdgcn_mfma_f32_16x16x32_bf16(af[i], bfr[j], acc[i][j], 0, 0, 0);
    }
  }

  if constexpr (EPI == 4) {
#pragma unroll
    for (int i = 0; i < 2; ++i) {
#pragma unroll
      for (int r = 0; r < 4; ++r) {
        int row = wm + i * 16 + quad * 4 + r;
        int t = m0 + row;
        int s = t & (SEQ - 1);
        if (n0 < 1024) {
#pragma unroll
          for (int j = 0; j < 2; ++j) {
            int col = n0 + wn + j * 16 + l15;
            int dlo = col & 63;
            float x1 = acc[i][j][r], x2 = acc[i][j + 2][r];
            float ch = aux.cosb[s * 64 + dlo], sh = aux.sinb[s * 64 + dlo];
            aux.qb[(size_t)t * DM + col]      = (bf16)((x1 * ch - x2 * sh) * 0.125f);
            aux.qb[(size_t)t * DM + col + 32] = (bf16)((x1 * sh + x2 * ch) * 0.125f);
          }
        } else if (n0 < 1280) {
#pragma unroll
          for (int j = 0; j < 2; ++j) {
            int ck = n0 + wn + j * 16 + l15 - 1024;
            int dlo = ck & 63;
            float x1 = acc[i][j][r], x2 = acc[i][j + 2][r];
            float ch = aux.cosb[s * 64 + dlo], sh = aux.sinb[s * 64 + dlo];
            float o1 = x1 * ch - x2 * sh, o2 = x1 * sh + x2 * ch;
            aux.kb[(size_t)t * 256 + ck]        = (bf16)o1;
            aux.kb[(size_t)t * 256 + ck + 32]   = (bf16)o2;
            aux.newk[(size_t)t * 256 + ck]      = o1;
            aux.newk[(size_t)t * 256 + ck + 32] = o2;
          }
        } else {
#pragma unroll
          for (int j = 0; j < 4; ++j) {
            int cv = n0 + wn + j * 16 + l15 - 1280;
            float v = acc[i][j][r];
            aux.vb[(size_t)t * 256 + cv]   = (bf16)v;
            aux.newv[(size_t)t * 256 + cv] = v;
          }
        }
      }
    }
    return;
  }
#pragma unroll
  for (int i = 0; i < 2; ++i) {
#pragma unroll
    for (int j = 0; j < 4; ++j) {
      int col = n0 + wn + j * 16 + l15;
#pragma unroll
      for (int r = 0; r < 4; ++r) {
        int row = wm + i * 16 + quad * 4 + r;
        size_t o = (size_t)(m0 + row) * ldc + col;
        float v = resid[o] + acc[i][j][r];
        Cf[o] = v;
        out2[o] = v;
      }
    }
  }
}

// --------------------------------------------------- slot-block decode helper
__device__ __forceinline__ bool slot_block(
    int f, int NY, const int* neCnt, int& expert, int& m0, int& mLimit, int& n0) {
  int xcd = f & 7, lo = f >> 3;
  int xb = lo / NY, y = lo % NY;
  n0 = y * 64;
  if (xb < XPE) {
    expert = xcd;
    int ne = neCnt[xcd];
    if (xb * 128 >= ne) return false;
    m0 = xcd * CAPT + xb * 128;
    mLimit = ne - xb * 128;
    if (mLimit > 128) mLimit = 128;
  } else {
    expert = 8;
    int sb = xcd * 4 + (xb - XPE);
    m0 = NSLOT + sb * 128;
    mLimit = 128;
  }
  return true;
}

// ------------------------------------------------------ MoE dual GEMM + swiglu
// 128x128 tile, dual-B: 48 KB LDS, 256 thr / 4 waves, m97-style 2-barrier
// schedule. ~800 TF measured (r3) — near structural ceiling.
__global__ __launch_bounds__(256, 2) void gemm_dual9(
    const bf16* __restrict__ A, const bf16* __restrict__ B1t, const bf16* __restrict__ B3t,
    bf16* __restrict__ mact,
    const int* __restrict__ tokList, const int* __restrict__ neCnt) {
  __shared__ __align__(16) bf16 As[128 * 64];
  __shared__ __align__(16) bf16 B1s[128 * 64];
  __shared__ __align__(16) bf16 B3s[128 * 64];
  const int tid = threadIdx.x, lane = tid & 63, wave = tid >> 6;
  int expert, m0, mLimit, n0;
  if (!slot_block(blockIdx.x, 11, neCnt, expert, m0, mLimit, n0)) return;
  n0 <<= 1;  // 128-wide N-tiles
  const bf16* B1e = B1t + (long)expert * (HIDDEN * 1024);
  const bf16* B3e = B3t + (long)expert * (HIDDEN * 1024);

  const bf16* aSrc[4]; const bf16* b1Src[4]; const bf16* b3Src[4];
  bf16* aDst[4]; bf16* b1Dst[4]; bf16* b3Dst[4];
#pragma unroll
  for (int it = 0; it < 4; ++it) {
    int c = it * 256 + tid;
    int r = c >> 3, q = c & 7;
    int kq = q ^ (r & 7);
    int rr = r < mLimit ? r : (mLimit - 1);
    aSrc[it] = A + (long)tokList[m0 + rr] * 1024 + kq * 8;
    aDst[it] = As + (size_t)(it * 256 + wave * 64) * 8;
    int nn = n0 + r; if (nn > HIDDEN - 1) nn = HIDDEN - 1;
    b1Src[it] = B1e + (long)nn * 1024 + kq * 8;
    b3Src[it] = B3e + (long)nn * 1024 + kq * 8;
    b1Dst[it] = B1s + (size_t)(it * 256 + wave * 64) * 8;
    b3Dst[it] = B3s + (size_t)(it * 256 + wave * 64) * 8;
  }

  floatx4 acc1[4][4], acc3[4][4];
#pragma unroll
  for (int i = 0; i < 4; ++i)
#pragma unroll
    for (int j = 0; j < 4; ++j) {
      floatx4 z = {0.f, 0.f, 0.f, 0.f};
      acc1[i][j] = z; acc3[i][j] = z;
    }

  const int wm = (wave & 1) * 64, wn = (wave >> 1) * 64;
  const int l15 = lane & 15, quad = lane >> 4;
  int aOff[4][2], bOff[4][2];
#pragma unroll
  for (int h = 0; h < 2; ++h) {
#pragma unroll
    for (int i = 0; i < 4; ++i) {
      int m = wm + i * 16 + l15;
      aOff[i][h] = (((m << 3) | ((h * 4 + quad) ^ (m & 7))) << 3);
    }
#pragma unroll
    for (int j = 0; j < 4; ++j) {
      int n = wn + j * 16 + l15;
      bOff[j][h] = (((n << 3) | ((h * 4 + quad) ^ (n & 7))) << 3);
    }
  }

  for (int kt = 0; kt < 16; ++kt) {
    __syncthreads();
#pragma unroll
    for (int it = 0; it < 4; ++it) { gld16(aSrc[it], aDst[it]); aSrc[it] += 64; }
#pragma unroll
    for (int it = 0; it < 4; ++it) {
      gld16(b1Src[it], b1Dst[it]); b1Src[it] += 64;
      gld16(b3Src[it], b3Dst[it]); b3Src[it] += 64;
    }
    __syncthreads();
#pragma unroll
    for (int h = 0; h < 2; ++h) {
      short8 af[4];
#pragma unroll
      for (int i = 0; i < 4; ++i) af[i] = *(const short8*)(As + aOff[i][h]);
#pragma unroll
      for (int j = 0; j < 4; ++j) {
        short8 b1f = *(const short8*)(B1s + bOff[j][h]);
        short8 b3f = *(const short8*)(B3s + bOff[j][h]);
#pragma unroll
        for (int i = 0; i < 4; ++i) {
          acc1[i][j] = __builtin_amdgcn_mfma_f32_16x16x32_bf16(af[i], b1f, acc1[i][j], 0, 0, 0);
          acc3[i][j] = __builtin_amdgcn_mfma_f32_16x16x32_bf16(af[i], b3f, acc3[i][j], 0, 0, 0);
        }
      }
    }
  }

#pragma unroll
  for (int i = 0; i < 4; ++i) {
#pragma unroll
    for (int j = 0; j < 4; ++j) {
      int col = n0 + wn + j * 16 + l15;
#pragma unroll
      for (int r = 0; r < 4; ++r) {
        int row = wm + i * 16 + quad * 4 + r;
        if (row >= mLimit) continue;
        float a1 = acc1[i][j][r], a3 = acc3[i][j][r];
        float sl = a1 / (1.f + __expf(-a1));
        mact[(size_t)(m0 + row) * HIDP + col] = (col < HIDDEN) ? (bf16)(sl * a3) : (bf16)0.f;
      }
    }
  }
}

// ------------------------------------------------------ MoE down GEMM (gated)
// 128x64 tile; A = mact slots (no gather). Fused combine: epilogue atomically
// accumulates gateW[slot] * acc into outp[tok] (outp pre-seeded with h by the
// WO GEMM). Shared slots have gateW=1, tokList identity — same path.
__global__ __launch_bounds__(256) void gemm_down9(
    const bf16* __restrict__ A, const bf16* __restrict__ B2t,
    float* __restrict__ outp,
    const float* __restrict__ gateW, const int* __restrict__ tokList,
    const int* __restrict__ neCnt) {
  __shared__ __align__(16) bf16 As[128 * 64];
  __shared__ __align__(16) bf16 Bs[64 * 64];
  const int tid = threadIdx.x, lane = tid & 63, wave = tid >> 6;
  int expert, m0, mLimit, n0;
  if (!slot_block(blockIdx.x, 16, neCnt, expert, m0, mLimit, n0)) return;
  const bf16* Be = B2t + (long)expert * (1024 * HIDP);

  const bf16* aSrc[4]; const bf16* bSrc[2];
  bf16* aDst[4]; bf16* bDst[2];
#pragma unroll
  for (int it = 0; it < 4; ++it) {
    int c = it * 256 + tid;
    int r = c >> 3, q = c & 7;
    int kq = q ^ (r & 7);
    int rr = r < mLimit ? r : (mLimit - 1);
    aSrc[it] = A + (long)(m0 + rr) * HIDP + kq * 8;
    aDst[it] = As + (size_t)(it * 256 + wave * 64) * 8;
  }
#pragma unroll
  for (int it = 0; it < 2; ++it) {
    int c = it * 256 + tid;
    int r = c >> 3, q = c & 7;
    int kq = q ^ (r & 7);
    bSrc[it] = Be + (long)(n0 + r) * HIDP + kq * 8;
    bDst[it] = Bs + (size_t)(it * 256 + wave * 64) * 8;
  }

  floatx4 acc[4][2];
#pragma unroll
  for (int i = 0; i < 4; ++i)
#pragma unroll
    for (int j = 0; j < 2; ++j) { floatx4 z = {0.f, 0.f, 0.f, 0.f}; acc[i][j] = z; }

  const int wm = (wave & 1) * 64, wn = (wave >> 1) * 32;
  const int l15 = lane & 15, quad = lane >> 4;
  int aOff[4][2], bOff[2][2];
#pragma unroll
  for (int h = 0; h < 2; ++h) {
#pragma unroll
    for (int i = 0; i < 4; ++i) {
      int m = wm + i * 16 + l15;
      aOff[i][h] = (((m << 3) | ((h * 4 + quad) ^ (m & 7))) << 3);
    }
#pragma unroll
    for (int j = 0; j < 2; ++j) {
      int n = wn + j * 16 + l15;
      bOff[j][h] = (((n << 3) | ((h * 4 + quad) ^ (n & 7))) << 3);
    }
  }

  for (int kt = 0; kt < 22; ++kt) {
    __syncthreads();
#pragma unroll
    for (int it = 0; it < 4; ++it) { gld16(aSrc[it], aDst[it]); aSrc[it] += 64; }
#pragma unroll
    for (int it = 0; it < 2; ++it) { gld16(bSrc[it], bDst[it]); bSrc[it] += 64; }
    __syncthreads();
#pragma unroll
    for (int h = 0; h < 2; ++h) {
      short8 af[4];
#pragma unroll
      for (int i = 0; i < 4; ++i) af[i] = *(const short8*)(As + aOff[i][h]);
#pragma unroll
      for (int j = 0; j < 2; ++j) {
        short8 bf = *(const short8*)(Bs + bOff[j][h]);
#pragma unroll
        for (int i = 0; i < 4; ++i)
          acc[i][j] = __builtin_amdgcn_mfma_f32_16x16x32_bf16(af[i], bf, acc[i][j], 0, 0, 0);
      }
    }
  }

#pragma unroll
  for (int i = 0; i < 4; ++i) {
#pragma unroll
    for (int r = 0; r < 4; ++r) {
      int row = wm + i * 16 + quad * 4 + r;
      if (row >= mLimit) continue;
      int slot = m0 + row;
      int tok = tokList[slot];
      float gw = gateW[slot];
#pragma unroll
      for (int j = 0; j < 2; ++j) {
        int col = n0 + wn + j * 16 + l15;
        atomicAdd(outp + (size_t)tok * 1024 + col, gw * acc[i][j][r]);
      }
    }
  }
}

// ------------------------------------------- V transpose: vb[t][256] -> vt[bg][d][s]
__global__ __launch_bounds__(256) void vt_kernel(
    const bf16* __restrict__ vb, bf16* __restrict__ vt) {
  __shared__ __align__(16) bf16 tile[64 * 72];
  int t0 = blockIdx.x * 64, bg = blockIdx.y;
  int b = bg >> 2, g = bg & 3;
  int tid = threadIdx.x;
  for (int c = tid; c < 512; c += 256) {
    int r = c >> 3, d8 = (c & 7) * 8;
    *(short8*)(tile + r * 72 + d8) =
        *(const short8*)(vb + (size_t)(b * SEQ + t0 + r) * 256 + g * 64 + d8);
  }
  __syncthreads();
  for (int c = tid; c < 512; c += 256) {
    int d = c >> 3, s8 = (c & 7) * 8;
    bf16 tmp[8];
#pragma unroll
    for (int x = 0; x < 8; ++x) tmp[x] = tile[(s8 + x) * 72 + d];
    *(short8*)(vt + ((size_t)bg * 64 + d) * SEQ + t0 + s8) = *(short8*)tmp;
  }
}

// ---------------------------------------------------------------- flash attention
// One q-tile per block, grid (32, NH, 2) = 1024 blocks = 4/CU (was 2/CU with
// paired tiles). q0 = (31-bx)*64: longest blocks dispatch first (LPT packing).
__global__ __launch_bounds__(256) void attn_kernel(
    const bf16* __restrict__ Q, const bf16* __restrict__ Kc, const bf16* __restrict__ Vt,
    bf16* __restrict__ AO) {
  __shared__ __align__(16) bf16 Qs[64 * 64];
  __shared__ __align__(16) bf16 Ks[64 * 64];
  __shared__ __align__(16) bf16 Vs[64 * 64];
  __shared__ __align__(16) bf16 Ps[4][16 * 64];
  const int h = blockIdx.y, b = blockIdx.z;
  const int q0 = (31 - blockIdx.x) * 64;
  const int g = h >> 2;
  const int tid = threadIdx.x, lane = tid & 63, wave = tid >> 6;
  const int l15 = lane & 15, quad = lane >> 4;

  const bf16* kSrc[2]; const bf16* vSrc[2]; bf16* kDst[2]; bf16* vDst[2];
#pragma unroll
  for (int it = 0; it < 2; ++it) {
    int c = it * 256 + tid;
    int r = c >> 3, p = c & 7;
    int kq = p ^ (r & 7);
    kSrc[it] = Kc + (size_t)(b * SEQ + r) * 256 + g * 64 + kq * 8;
    vSrc[it] = Vt + ((size_t)(b * 4 + g) * 64 + r) * SEQ + kq * 8;
    kDst[it] = Ks + (size_t)(it * 256 + wave * 64) * 8;
    vDst[it] = Vs + (size_t)(it * 256 + wave * 64) * 8;
  }

  int qOff[2], kvOff[4][2], pOff[2];
#pragma unroll
  for (int hh = 0; hh < 2; ++hh) {
    int m = wave * 16 + l15;
    qOff[hh] = (m << 6) + (((hh * 4 + quad) ^ (m & 7)) << 3);
#pragma unroll
    for (int j = 0; j < 4; ++j) {
      int n = j * 16 + l15;
      kvOff[j][hh] = (n << 6) + (((hh * 4 + quad) ^ (n & 7)) << 3);
    }
    int cblk = (hh * 2 + (quad >> 1)) ^ (l15 >> 2);
    pOff[hh] = (l15 << 6) + (cblk << 4) + ((quad & 1) << 3);
  }
  bf16* pw = &Ps[wave][0];
  const int rowl = wave * 16 + quad * 4;

  short8 onesb;
#pragma unroll
  for (int e = 0; e < 8; ++e) onesb[e] = (short)0x3F80;

#pragma unroll
  for (int it = 0; it < 2; ++it) {
    int c = it * 256 + tid;
    int r = c >> 3, p = c & 7;
    int kq = p ^ (r & 7);
    gld16(Q + (size_t)(b * SEQ + q0 + r) * DM + h * 64 + kq * 8,
          Qs + (size_t)(it * 256 + wave * 64) * 8);
  }

  floatx4 oacc[4], sumacc;
#pragma unroll
  for (int r = 0; r < 4; ++r) { floatx4 z = {0.f, 0.f, 0.f, 0.f}; oacc[r] = z; }
  { floatx4 z = {0.f, 0.f, 0.f, 0.f}; sumacc = z; }

  const int nkt = (q0 >> 6) + 1;
  for (int kt = 0; kt < nkt; ++kt) {
    __syncthreads();
#pragma unroll
    for (int it = 0; it < 2; ++it) {
      gld16(kSrc[it] + (size_t)kt * 64 * 256, kDst[it]);
      gld16(vSrc[it] + kt * 64, vDst[it]);
    }
    __syncthreads();

    floatx4 sacc[4];
#pragma unroll
    for (int j = 0; j < 4; ++j) { floatx4 z = {0.f, 0.f, 0.f, 0.f}; sacc[j] = z; }
#pragma unroll
    for (int hh = 0; hh < 2; ++hh) {
      short8 aq = *(const short8*)(Qs + qOff[hh]);
#pragma unroll
      for (int j = 0; j < 4; ++j)
        sacc[j] = __builtin_amdgcn_mfma_f32_16x16x32_bf16(
            aq, *(const short8*)(Ks + kvOff[j][hh]), sacc[j], 0, 0, 0);
    }

    const bool lastTile = (kt == nkt - 1);
#pragma unroll
    for (int j = 0; j < 4; ++j) {
      int sw = ((j ^ quad) << 4) + l15;
      int colg = j * 16 + l15;
#pragma unroll
      for (int r = 0; r < 4; ++r) {
        float p = __expf(sacc[j][r]);
        if (lastTile && colg > rowl + r) p = 0.f;
        pw[(quad * 4 + r) * 64 + sw] = (bf16)p;
      }
    }
    asm volatile("s_waitcnt lgkmcnt(0)" ::: "memory");
#pragma unroll
    for (int hh = 0; hh < 2; ++hh) {
      short8 ap = *(const short8*)(pw + pOff[hh]);
#pragma unroll
      for (int j = 0; j < 4; ++j)
        oacc[j] = __builtin_amdgcn_mfma_f32_16x16x32_bf16(
            ap, *(const short8*)(Vs + kvOff[j][hh]), oacc[j], 0, 0, 0);
      sumacc = __builtin_amdgcn_mfma_f32_16x16x32_bf16(ap, onesb, sumacc, 0, 0, 0);
    }
  }

  float inv[4];
#pragma unroll
  for (int r = 0; r < 4; ++r) inv[r] = 1.f / sumacc[r];
#pragma unroll
  for (int j = 0; j < 4; ++j)
#pragma unroll
    for (int r = 0; r < 4; ++r) {
      int t = b * SEQ + q0 + rowl + r;
      AO[(size_t)t * DM + h * 64 + j * 16 + l15] = (bf16)(oacc[j][r] * inv[r]);
    }
}

// ------------------------------------------------- capacity assignment (9 blocks)
// blocks 0..7: per-expert compaction; block 8: identity fill for shared slots
__global__ __launch_bounds__(256) void assign_kernel(
    const int* __restrict__ tIdx, const float* __restrict__ tW,
    int* __restrict__ tokList, float* __restrict__ gateW,
    int* __restrict__ neCnt, int* __restrict__ cntFull) {
  int e = blockIdx.x;
  int tid = threadIdx.x, lane = tid & 63, wv = tid >> 6;
  if (e == 8) {
    for (int t = tid; t < TTOK; t += 256) {
      tokList[NSLOT + t] = t;
      gateW[NSLOT + t] = 1.0f;
    }
    if (tid == 0) neCnt[8] = TTOK;
    return;
  }
  __shared__ int waveTot[4];
  __shared__ int offs;
  if (tid == 0) offs = 0;
  __syncthreads();
  for (int base = 0; base < TTOK; base += 256) {
    int t = base + tid;
    int a = tIdx[t * 2], b2 = tIdx[t * 2 + 1];
    bool sel = (a == e) || (b2 == e);
    unsigned long long mask = __ballot(sel);
    int wrank = __popcll(mask & ((1ull << lane) - 1ull));
    if (lane == 0) waveTot[wv] = __popcll(mask);
    __syncthreads();
    int pre = offs;
    for (int w2 = 0; w2 < wv; ++w2) pre += waveTot[w2];
    int rank = pre + wrank;
    if (sel && rank < CAPT) {
      int slot = e * CAPT + rank;
      tokList[slot] = t;
      gateW[slot] = (a == e) ? tW[t * 2] : tW[t * 2 + 1];
    }
    __syncthreads();
    if (tid == 0) offs += waveTot[0] + waveTot[1] + waveTot[2] + waveTot[3];
    __syncthreads();
  }
  if (tid == 0) {
    cntFull[e] = offs;
    neCnt[e] = offs < CAPT ? offs : CAPT;
  }
}

// ---------------------------------------------------------------- aux loss / util
__global__ __launch_bounds__(256) void aux_kernel(
    const float* __restrict__ probs, const int* __restrict__ cntFull,
    float* __restrict__ outAux) {
  __shared__ float psum[8];
  if (threadIdx.x < 8) psum[threadIdx.x] = 0.f;
  __syncthreads();
  float lp[8] = {0, 0, 0, 0, 0, 0, 0, 0};
  for (int t = threadIdx.x; t < TTOK; t += 256) {
#pragma unroll
    for (int e = 0; e < 8; ++e) lp[e] += probs[t * 8 + e];
  }
#pragma unroll
  for (int e = 0; e < 8; ++e)
#pragma unroll
    for (int off = 1; off < 64; off <<= 1) lp[e] += __shfl_xor(lp[e], off);
  if ((threadIdx.x & 63) == 0)
#pragma unroll
    for (int e = 0; e < 8; ++e) atomicAdd(&psum[e], lp[e]);
  __syncthreads();
  if (threadIdx.x == 0) {
    float aux = 0.f; int used = 0;
    for (int e = 0; e < 8; ++e) {
      aux += (psum[e] / (float)TTOK) * ((float)cntFull[e] / (float)TTOK);
      if (cntFull[e] > 0) used++;
    }
    outAux[0] = 8.f * aux;
    outAux[1] = 100.f * (float)used / 8.f;
  }
}

// ---------------------------------------------------------------- launch
extern "C" void kernel_launch(void* const* d_in, const int* in_sizes, int n_in,
                              void* d_out, int out_size, void* d_ws, size_t ws_size,
                              hipStream_t stream) {
  (void)in_sizes; (void)n_in; (void)out_size; (void)ws_size;
  const float* x     = (const float*)d_in[0];
  const float* cosb  = (const float*)d_in[1];
  const float* sinb  = (const float*)d_in[2];
  const float* attnw = (const float*)d_in[4];
  const float* moew  = (const float*)d_in[5];
  const float* wq  = (const float*)d_in[6];
  const float* wk  = (const float*)d_in[7];
  const float* wv  = (const float*)d_in[8];
  const float* wo  = (const float*)d_in[9];
  const float* rw  = (const float*)d_in[10];
  const float* ew1 = (const float*)d_in[11];
  const float* ew2 = (const float*)d_in[12];
  const float* ew3 = (const float*)d_in[13];
  const float* sw1 = (const float*)d_in[14];
  const float* sw2 = (const float*)d_in[15];
  const float* sw3 = (const float*)d_in[16];

  float* outp = (float*)d_out;
  float* auxp = outp + 4194304;
  float* newk = outp + 4194306;
  float* newv = newk + 1048576;

  char* wsp = (char*)d_ws;
  size_t off = 0;
  auto alloc = [&](size_t bytes) -> void* {
    void* p = wsp + off; off += (bytes + 255) & ~(size_t)255; return p;
  };
  bf16* wqkvT = (bf16*)alloc((size_t)1536 * 1024 * 2);
  bf16* woT   = (bf16*)alloc((size_t)1024 * 1024 * 2);
  bf16* ew1T  = (bf16*)alloc((size_t)9 * HIDDEN * 1024 * 2);   // slice 8 = sw1
  bf16* ew3T  = (bf16*)alloc((size_t)9 * HIDDEN * 1024 * 2);   // slice 8 = sw3
  bf16* ew2T  = (bf16*)alloc((size_t)9 * 1024 * HIDP * 2);     // slice 8 = sw2
  bf16* xn    = (bf16*)alloc((size_t)TTOK * DM * 2);
  bf16* qb    = (bf16*)alloc((size_t)TTOK * DM * 2);
  bf16* kb    = (bf16*)alloc((size_t)TTOK * 256 * 2);
  bf16* vb    = (bf16*)alloc((size_t)TTOK * 256 * 2);
  bf16* vt    = (bf16*)alloc((size_t)TTOK * 256 * 2);
  bf16* ao    = (bf16*)alloc((size_t)TTOK * DM * 2);
  float* hbuf = (float*)alloc((size_t)TTOK * DM * 4);
  bf16* hn    = (bf16*)alloc((size_t)TTOK * DM * 2);
  float* probs = (float*)alloc((size_t)TTOK * 8 * 4);
  int*   tIdx  = (int*)alloc((size_t)TTOK * 2 * 4);
  float* tW    = (float*)alloc((size_t)TTOK * 2 * 4);
  int*   tokList = (int*)alloc((size_t)TSLOT * 4);
  float* gateW   = (float*)alloc((size_t)TSLOT * 4);
  int*   neCnt   = (int*)alloc(64);
  int*   cntFull = (int*)alloc(64);
  bf16*  mact = (bf16*)alloc((size_t)TSLOT * HIDP * 2);

  EpiAux nil{};
  EpiAux ropeAux{cosb, sinb, qb, kb, vb, newk, newv};

  // ---- weight convert + transpose (r0 grids)
  transpose_cvt<<<dim3(16, 16, 1), 256, 0, stream>>>(wq, wqkvT, 1024, 1024, 1024, 0, 0);
  transpose_cvt<<<dim3(4, 16, 1), 256, 0, stream>>>(wk, wqkvT + (size_t)1024 * 1024, 1024, 256, 1024, 0, 0);
  transpose_cvt<<<dim3(4, 16, 1), 256, 0, stream>>>(wv, wqkvT + (size_t)1280 * 1024, 1024, 256, 1024, 0, 0);
  transpose_cvt<<<dim3(16, 16, 1), 256, 0, stream>>>(wo, woT, 1024, 1024, 1024, 0, 0);
  transpose_cvt<<<dim3(22, 16, NEXP), 256, 0, stream>>>(ew1, ew1T, 1024, HIDDEN, 1024,
      (long)1024 * HIDDEN, (long)HIDDEN * 1024);
  transpose_cvt<<<dim3(22, 16, NEXP), 256, 0, stream>>>(ew3, ew3T, 1024, HIDDEN, 1024,
      (long)1024 * HIDDEN, (long)HIDDEN * 1024);
  transpose_cvt<<<dim3(16, 22, NEXP), 256, 0, stream>>>(ew2, ew2T, HIDDEN, 1024, HIDP,
      (long)HIDDEN * 1024, (long)1024 * HIDP);
  transpose_cvt<<<dim3(22, 16, 1), 256, 0, stream>>>(sw1, ew1T + (size_t)8 * HIDDEN * 1024,
      1024, HIDDEN, 1024, 0, 0);
  transpose_cvt<<<dim3(22, 16, 1), 256, 0, stream>>>(sw3, ew3T + (size_t)8 * HIDDEN * 1024,
      1024, HIDDEN, 1024, 0, 0);
  transpose_cvt<<<dim3(16, 22, 1), 256, 0, stream>>>(sw2, ew2T + (size_t)8 * 1024 * HIDP,
      HIDDEN, 1024, HIDP, 0, 0);

  // ---- attention path (64-row M-tiles: xPerXcd = 4096/64/8 = 8)
  rmsnorm_kernel<<<TTOK, 256, 0, stream>>>(x, attnw, xn);
  gemm_bt<4><<<8 * 8 * 12, 256, 0, stream>>>(
      xn, wqkvT, TTOK, 1536, 1024, 1024, 1024, 8, nullptr, 0, nullptr, nullptr, ropeAux);
  vt_kernel<<<dim3(32, 8), 256, 0, stream>>>(vb, vt);
  attn_kernel<<<dim3(32, NHEAD, 2), 256, 0, stream>>>(qb, kb, vt, ao);
  gemm_bt<2><<<8 * 8 * 8, 256, 0, stream>>>(
      ao, woT, TTOK, 1024, 1024, 1024, 1024, 8, hbuf, 1024, x, outp, nil);

  // ---- MoE routing
  rmsnorm_router_kernel<<<TTOK, 256, 0, stream>>>(hbuf, moew, rw, hn, probs, tIdx, tW);
  assign_kernel<<<9, 256, 0, stream>>>(tIdx, tW, tokList, gateW, neCnt, cntFull);
  aux_kernel<<<1, 256, 0, stream>>>(probs, cntFull, auxp);

  // ---- experts (8 routed + shared as expert 8); down9 accumulates into outp
  gemm_dual9<<<8 * XBT * 11, 256, 0, stream>>>(hn, ew1T, ew3T, mact, tokList, neCnt);
  gemm_down9<<<8 * XBT * 16, 256, 0, stream>>>(mact, ew2T, outp, gateW, tokList, neCnt);
}

// Round 8
// 578.940 us; speedup vs baseline: 1.0257x; 1.0257x over previous
//
#include <hip/hip_runtime.h>
#include <hip/hip_bf16.h>
#include <math.h>

typedef __hip_bfloat16 bf16;
typedef __attribute__((ext_vector_type(8))) short short8;
typedef __attribute__((ext_vector_type(4))) float floatx4;

#define SEQ    2048
#define TTOK   4096
#define DM     1024
#define NHEAD  16
#define NKVH   4
#define HD     64
#define NEXP   8
#define HIDDEN 1365
#define HIDP   1408
#define CAPT   1280
#define NSLOT  (NEXP*CAPT)      /* 10240 routed slots */
#define TSLOT  (NSLOT+TTOK)     /* 14336: + shared-expert identity slots */
#define XPE    (CAPT/128)       /* 10 routed 128-row M-blocks per expert */
#define XBT    14               /* per-XCD 128-row M-blocks: 10 routed + 4 shared */

// ---------------------------------------------------------------- utilities
__device__ __forceinline__ void gld16(const void* g, void* l) {
  __builtin_amdgcn_global_load_lds((const __attribute__((address_space(1))) void*)g,
                                   (__attribute__((address_space(3))) void*)l,
                                   16, 0, 0);
}

struct __align__(8) bf4 { bf16 x, y, z, w; };

struct EpiAux {
  const float* cosb; const float* sinb;
  bf16* qb; bf16* kb; bf16* vb; float* newk; float* newv;
};

// ---------------------------------------------------- weight convert+transpose
// src: (K,N) f32 row-major -> dst: (N,Kp) bf16 row-major, zero-fill k in [K,Kp)
__global__ __launch_bounds__(256) void transpose_cvt(
    const float* __restrict__ src, bf16* __restrict__ dst,
    int K, int N, int Kp, long srcZ, long dstZ) {
  src += (size_t)blockIdx.z * srcZ;
  dst += (size_t)blockIdx.z * dstZ;
  __shared__ float tile[64][65];
  const int tid = threadIdx.x;
  const int k0 = blockIdx.y * 64, n0 = blockIdx.x * 64;
  const int lr = tid >> 4, lc = (tid & 15) * 4;
#pragma unroll
  for (int i = 0; i < 4; ++i) {
    int k = k0 + lr + i * 16;
    int n = n0 + lc;
    float4 v = {0.f, 0.f, 0.f, 0.f};
    if (k < K) {
      if (n + 3 < N) v = *(const float4*)(src + (size_t)k * N + n);
      else {
        float* vp = (float*)&v;
        for (int e = 0; e < 4; ++e) if (n + e < N) vp[e] = src[(size_t)k * N + n + e];
      }
    }
    tile[lr + i * 16][lc] = v.x; tile[lr + i * 16][lc + 1] = v.y;
    tile[lr + i * 16][lc + 2] = v.z; tile[lr + i * 16][lc + 3] = v.w;
  }
  __syncthreads();
  const int n = tid >> 2, kk0 = (tid & 3) * 16;
  if (n0 + n < N) {
    bf16 buf[16];
#pragma unroll
    for (int e = 0; e < 16; ++e) buf[e] = (bf16)tile[kk0 + e][n];
    bf16* dp = dst + (size_t)(n0 + n) * Kp + k0 + kk0;
    *(short8*)dp = *(short8*)buf;
    *(short8*)(dp + 8) = *(short8*)(buf + 8);
  }
}

// ---------------------------------------------------------------- rmsnorm
__global__ __launch_bounds__(256) void rmsnorm_kernel(
    const float* __restrict__ x, const float* __restrict__ w, bf16* __restrict__ out) {
  int t = blockIdx.x;
  const float* xr = x + (size_t)t * DM;
  float4 xv = *(const float4*)(xr + threadIdx.x * 4);
  float ss = xv.x * xv.x + xv.y * xv.y + xv.z * xv.z + xv.w * xv.w;
#pragma unroll
  for (int off = 1; off < 64; off <<= 1) ss += __shfl_xor(ss, off);
  __shared__ float sred[4];
  if ((threadIdx.x & 63) == 0) sred[threadIdx.x >> 6] = ss;
  __syncthreads();
  float scale = rsqrtf((sred[0] + sred[1] + sred[2] + sred[3]) * (1.f / DM) + 1e-6f);
  float4 wv = *(const float4*)(w + threadIdx.x * 4);
  bf4 o;
  o.x = (bf16)(xv.x * scale * wv.x); o.y = (bf16)(xv.y * scale * wv.y);
  o.z = (bf16)(xv.z * scale * wv.z); o.w = (bf16)(xv.w * scale * wv.w);
  ((bf4*)(out + (size_t)t * DM))[threadIdx.x] = o;
}

// -------------------------------------------- rmsnorm + router (moe path)
__global__ __launch_bounds__(256) void rmsnorm_router_kernel(
    const float* __restrict__ x, const float* __restrict__ w, const float* __restrict__ rw,
    bf16* __restrict__ out, float* __restrict__ probs,
    int* __restrict__ tIdx, float* __restrict__ tW) {
  int t = blockIdx.x;
  int tid = threadIdx.x, lane = tid & 63, wv = tid >> 6;
  const float* xr = x + (size_t)t * DM;
  float4 xv = *(const float4*)(xr + tid * 4);
  float ss = xv.x * xv.x + xv.y * xv.y + xv.z * xv.z + xv.w * xv.w;
#pragma unroll
  for (int off = 1; off < 64; off <<= 1) ss += __shfl_xor(ss, off);
  __shared__ float sred[4];
  __shared__ float red[4][8];
  if (lane == 0) sred[wv] = ss;
  __syncthreads();
  float scale = rsqrtf((sred[0] + sred[1] + sred[2] + sred[3]) * (1.f / DM) + 1e-6f);
  float4 wvv = *(const float4*)(w + tid * 4);
  float y[4] = {xv.x * scale * wvv.x, xv.y * scale * wvv.y,
                xv.z * scale * wvv.z, xv.w * scale * wvv.w};
  bf4 o; o.x = (bf16)y[0]; o.y = (bf16)y[1]; o.z = (bf16)y[2]; o.w = (bf16)y[3];
  ((bf4*)(out + (size_t)t * DM))[tid] = o;
  float acc[8] = {0, 0, 0, 0, 0, 0, 0, 0};
#pragma unroll
  for (int dd = 0; dd < 4; ++dd) {
    const float* rwr = rw + (size_t)(tid * 4 + dd) * 8;
#pragma unroll
    for (int e = 0; e < 8; ++e) acc[e] += y[dd] * rwr[e];
  }
#pragma unroll
  for (int e = 0; e < 8; ++e)
#pragma unroll
    for (int off = 1; off < 64; off <<= 1) acc[e] += __shfl_xor(acc[e], off);
  if (lane == 0)
#pragma unroll
    for (int e = 0; e < 8; ++e) red[wv][e] = acc[e];
  __syncthreads();
  if (tid == 0) {
    float lg[8];
#pragma unroll
    for (int e = 0; e < 8; ++e) lg[e] = red[0][e] + red[1][e] + red[2][e] + red[3][e];
    float mx = lg[0];
#pragma unroll
    for (int e = 1; e < 8; ++e) mx = fmaxf(mx, lg[e]);
    float p[8], se = 0.f;
#pragma unroll
    for (int e = 0; e < 8; ++e) { p[e] = __expf(lg[e] - mx); se += p[e]; }
#pragma unroll
    for (int e = 0; e < 8; ++e) { p[e] /= se; probs[t * 8 + e] = p[e]; }
    int i1 = 0;
#pragma unroll
    for (int e = 1; e < 8; ++e) if (p[e] > p[i1]) i1 = e;
    int i2 = (i1 == 0) ? 1 : 0;
#pragma unroll
    for (int e = 0; e < 8; ++e) if (e != i1 && p[e] > p[i2]) i2 = e;
    float s = p[i1] + p[i2];
    tIdx[t * 2] = i1; tIdx[t * 2 + 1] = i2;
    tW[t * 2] = p[i1] / s; tW[t * 2 + 1] = p[i2] / s;
  }
}

// ---------------------------------------------------------------- dense GEMM
// 64x128 tile. EPI: 2 = Cf = resid + acc ; 4 = QKV+rope
template <int EPI>
__global__ __launch_bounds__(256) void gemm_bt(
    const bf16* __restrict__ A, const bf16* __restrict__ Bt,
    int M, int N, int K, int lda, int ldb, int xPerXcd,
    float* __restrict__ Cf, int ldc,
    const float* __restrict__ resid, EpiAux aux) {
  __shared__ __align__(16) bf16 As[64 * 64];
  __shared__ __align__(16) bf16 Bs[128 * 64];
  const int tid = threadIdx.x, lane = tid & 63, wave = tid >> 6;
  const int f = blockIdx.x, lo = f >> 3;
  int xb = (f & 7) * xPerXcd + lo % xPerXcd;
  int n0 = (lo / xPerXcd) * 128;
  int m0 = xb * 64;

  const bf16* aSrc[2]; const bf16* bSrc[4];
  bf16* aDst[2]; bf16* bDst[4];
#pragma unroll
  for (int it = 0; it < 2; ++it) {
    int c = it * 256 + tid;
    int r = c >> 3, q = c & 7;
    int kq = q ^ (r & 7);
    aSrc[it] = A + (long)(m0 + r) * lda + kq * 8;
    aDst[it] = As + (size_t)(it * 256 + wave * 64) * 8;
  }
#pragma unroll
  for (int it = 0; it < 4; ++it) {
    int c = it * 256 + tid;
    int r = c >> 3, q = c & 7;
    int kq = q ^ (r & 7);
    bSrc[it] = Bt + (long)(n0 + r) * ldb + kq * 8;
    bDst[it] = Bs + (size_t)(it * 256 + wave * 64) * 8;
  }

  floatx4 acc[2][4];
#pragma unroll
  for (int i = 0; i < 2; ++i)
#pragma unroll
    for (int j = 0; j < 4; ++j) { floatx4 z = {0.f, 0.f, 0.f, 0.f}; acc[i][j] = z; }

  const int wm = (wave & 1) * 32, wn = (wave >> 1) * 64;
  const int l15 = lane & 15, quad = lane >> 4;
  int aOff[2][2], bOff[4][2];
#pragma unroll
  for (int h = 0; h < 2; ++h) {
#pragma unroll
    for (int i = 0; i < 2; ++i) {
      int m = wm + i * 16 + l15;
      aOff[i][h] = (((m << 3) | ((h * 4 + quad) ^ (m & 7))) << 3);
    }
#pragma unroll
    for (int j = 0; j < 4; ++j) {
      int n = wn + j * 16 + l15;
      bOff[j][h] = (((n << 3) | ((h * 4 + quad) ^ (n & 7))) << 3);
    }
  }

  const int kIters = K >> 6;
  for (int kt = 0; kt < kIters; ++kt) {
    __syncthreads();
#pragma unroll
    for (int it = 0; it < 2; ++it) { gld16(aSrc[it], aDst[it]); aSrc[it] += 64; }
#pragma unroll
    for (int it = 0; it < 4; ++it) { gld16(bSrc[it], bDst[it]); bSrc[it] += 64; }
    __syncthreads();
#pragma unroll
    for (int h = 0; h < 2; ++h) {
      short8 af[2], bfr[4];
#pragma unroll
      for (int i = 0; i < 2; ++i) af[i] = *(const short8*)(As + aOff[i][h]);
#pragma unroll
      for (int j = 0; j < 4; ++j) bfr[j] = *(const short8*)(Bs + bOff[j][h]);
#pragma unroll
      for (int i = 0; i < 2; ++i)
#pragma unroll
        for (int j = 0; j < 4; ++j)
          acc[i][j] = __builtin_amdgcn_mfma_f32_16x16x32_bf16(af[i], bfr[j], acc[i][j], 0, 0, 0);
    }
  }

  if constexpr (EPI == 4) {
#pragma unroll
    for (int i = 0; i < 2; ++i) {
#pragma unroll
      for (int r = 0; r < 4; ++r) {
        int row = wm + i * 16 + quad * 4 + r;
        int t = m0 + row;
        int s = t & (SEQ - 1);
        if (n0 < 1024) {
#pragma unroll
          for (int j = 0; j < 2; ++j) {
            int col = n0 + wn + j * 16 + l15;
            int dlo = col & 63;
            float x1 = acc[i][j][r], x2 = acc[i][j + 2][r];
            float ch = aux.cosb[s * 64 + dlo], sh = aux.sinb[s * 64 + dlo];
            aux.qb[(size_t)t * DM + col]      = (bf16)((x1 * ch - x2 * sh) * 0.125f);
            aux.qb[(size_t)t * DM + col + 32] = (bf16)((x1 * sh + x2 * ch) * 0.125f);
          }
        } else if (n0 < 1280) {
#pragma unroll
          for (int j = 0; j < 2; ++j) {
            int ck = n0 + wn + j * 16 + l15 - 1024;
            int dlo = ck & 63;
            float x1 = acc[i][j][r], x2 = acc[i][j + 2][r];
            float ch = aux.cosb[s * 64 + dlo], sh = aux.sinb[s * 64 + dlo];
            float o1 = x1 * ch - x2 * sh, o2 = x1 * sh + x2 * ch;
            aux.kb[(size_t)t * 256 + ck]        = (bf16)o1;
            aux.kb[(size_t)t * 256 + ck + 32]   = (bf16)o2;
            aux.newk[(size_t)t * 256 + ck]      = o1;
            aux.newk[(size_t)t * 256 + ck + 32] = o2;
          }
        } else {
#pragma unroll
          for (int j = 0; j < 4; ++j) {
            int cv = n0 + wn + j * 16 + l15 - 1280;
            float v = acc[i][j][r];
            aux.vb[(size_t)t * 256 + cv]   = (bf16)v;
            aux.newv[(size_t)t * 256 + cv] = v;
          }
        }
      }
    }
    return;
  }
#pragma unroll
  for (int i = 0; i < 2; ++i) {
#pragma unroll
    for (int j = 0; j < 4; ++j) {
      int col = n0 + wn + j * 16 + l15;
#pragma unroll
      for (int r = 0; r < 4; ++r) {
        int row = wm + i * 16 + quad * 4 + r;
        size_t o = (size_t)(m0 + row) * ldc + col;
        Cf[o] = resid[o] + acc[i][j][r];
      }
    }
  }
}

// --------------------------------------------------- slot-block decode helper
__device__ __forceinline__ bool slot_block(
    int f, int NY, const int* neCnt, int& expert, int& m0, int& mLimit, int& n0) {
  int xcd = f & 7, lo = f >> 3;
  int xb = lo / NY, y = lo % NY;
  n0 = y * 64;
  if (xb < XPE) {
    expert = xcd;
    int ne = neCnt[xcd];
    if (xb * 128 >= ne) return false;
    m0 = xcd * CAPT + xb * 128;
    mLimit = ne - xb * 128;
    if (mLimit > 128) mLimit = 128;
  } else {
    expert = 8;
    int sb = xcd * 4 + (xb - XPE);
    m0 = NSLOT + sb * 128;
    mLimit = 128;
  }
  return true;
}

// ------------------------------------------------------ MoE dual GEMM + swiglu
// 128x128 tile, dual-B: 48 KB LDS, 256 thr / 4 waves, m97-style 2-barrier
// schedule. ~800 TF measured (r3) — near structural ceiling.
__global__ __launch_bounds__(256, 2) void gemm_dual9(
    const bf16* __restrict__ A, const bf16* __restrict__ B1t, const bf16* __restrict__ B3t,
    bf16* __restrict__ mact,
    const int* __restrict__ tokList, const int* __restrict__ neCnt) {
  __shared__ __align__(16) bf16 As[128 * 64];
  __shared__ __align__(16) bf16 B1s[128 * 64];
  __shared__ __align__(16) bf16 B3s[128 * 64];
  const int tid = threadIdx.x, lane = tid & 63, wave = tid >> 6;
  int expert, m0, mLimit, n0;
  if (!slot_block(blockIdx.x, 11, neCnt, expert, m0, mLimit, n0)) return;
  n0 <<= 1;  // 128-wide N-tiles
  const bf16* B1e = B1t + (long)expert * (HIDDEN * 1024);
  const bf16* B3e = B3t + (long)expert * (HIDDEN * 1024);

  const bf16* aSrc[4]; const bf16* b1Src[4]; const bf16* b3Src[4];
  bf16* aDst[4]; bf16* b1Dst[4]; bf16* b3Dst[4];
#pragma unroll
  for (int it = 0; it < 4; ++it) {
    int c = it * 256 + tid;
    int r = c >> 3, q = c & 7;
    int kq = q ^ (r & 7);
    int rr = r < mLimit ? r : (mLimit - 1);
    aSrc[it] = A + (long)tokList[m0 + rr] * 1024 + kq * 8;
    aDst[it] = As + (size_t)(it * 256 + wave * 64) * 8;
    int nn = n0 + r; if (nn > HIDDEN - 1) nn = HIDDEN - 1;
    b1Src[it] = B1e + (long)nn * 1024 + kq * 8;
    b3Src[it] = B3e + (long)nn * 1024 + kq * 8;
    b1Dst[it] = B1s + (size_t)(it * 256 + wave * 64) * 8;
    b3Dst[it] = B3s + (size_t)(it * 256 + wave * 64) * 8;
  }

  floatx4 acc1[4][4], acc3[4][4];
#pragma unroll
  for (int i = 0; i < 4; ++i)
#pragma unroll
    for (int j = 0; j < 4; ++j) {
      floatx4 z = {0.f, 0.f, 0.f, 0.f};
      acc1[i][j] = z; acc3[i][j] = z;
    }

  const int wm = (wave & 1) * 64, wn = (wave >> 1) * 64;
  const int l15 = lane & 15, quad = lane >> 4;
  int aOff[4][2], bOff[4][2];
#pragma unroll
  for (int h = 0; h < 2; ++h) {
#pragma unroll
    for (int i = 0; i < 4; ++i) {
      int m = wm + i * 16 + l15;
      aOff[i][h] = (((m << 3) | ((h * 4 + quad) ^ (m & 7))) << 3);
    }
#pragma unroll
    for (int j = 0; j < 4; ++j) {
      int n = wn + j * 16 + l15;
      bOff[j][h] = (((n << 3) | ((h * 4 + quad) ^ (n & 7))) << 3);
    }
  }

  for (int kt = 0; kt < 16; ++kt) {
    __syncthreads();
#pragma unroll
    for (int it = 0; it < 4; ++it) { gld16(aSrc[it], aDst[it]); aSrc[it] += 64; }
#pragma unroll
    for (int it = 0; it < 4; ++it) {
      gld16(b1Src[it], b1Dst[it]); b1Src[it] += 64;
      gld16(b3Src[it], b3Dst[it]); b3Src[it] += 64;
    }
    __syncthreads();
#pragma unroll
    for (int h = 0; h < 2; ++h) {
      short8 af[4];
#pragma unroll
      for (int i = 0; i < 4; ++i) af[i] = *(const short8*)(As + aOff[i][h]);
#pragma unroll
      for (int j = 0; j < 4; ++j) {
        short8 b1f = *(const short8*)(B1s + bOff[j][h]);
        short8 b3f = *(const short8*)(B3s + bOff[j][h]);
#pragma unroll
        for (int i = 0; i < 4; ++i) {
          acc1[i][j] = __builtin_amdgcn_mfma_f32_16x16x32_bf16(af[i], b1f, acc1[i][j], 0, 0, 0);
          acc3[i][j] = __builtin_amdgcn_mfma_f32_16x16x32_bf16(af[i], b3f, acc3[i][j], 0, 0, 0);
        }
      }
    }
  }

#pragma unroll
  for (int i = 0; i < 4; ++i) {
#pragma unroll
    for (int j = 0; j < 4; ++j) {
      int col = n0 + wn + j * 16 + l15;
#pragma unroll
      for (int r = 0; r < 4; ++r) {
        int row = wm + i * 16 + quad * 4 + r;
        if (row >= mLimit) continue;
        float a1 = acc1[i][j][r], a3 = acc3[i][j][r];
        float sl = a1 / (1.f + __expf(-a1));
        mact[(size_t)(m0 + row) * HIDP + col] = (col < HIDDEN) ? (bf16)(sl * a3) : (bf16)0.f;
      }
    }
  }
}

// ------------------------------------------------------ MoE down GEMM (gated)
// 128x64 tile (r0 version — best measured); A = mact slots (no gather);
// eo[slot] = gateW[slot] * (A@ew2^T)
__global__ __launch_bounds__(256) void gemm_down9(
    const bf16* __restrict__ A, const bf16* __restrict__ B2t,
    bf16* __restrict__ eo,
    const float* __restrict__ gateW, const int* __restrict__ neCnt) {
  __shared__ __align__(16) bf16 As[128 * 64];
  __shared__ __align__(16) bf16 Bs[64 * 64];
  const int tid = threadIdx.x, lane = tid & 63, wave = tid >> 6;
  int expert, m0, mLimit, n0;
  if (!slot_block(blockIdx.x, 16, neCnt, expert, m0, mLimit, n0)) return;
  const bf16* Be = B2t + (long)expert * (1024 * HIDP);

  const bf16* aSrc[4]; const bf16* bSrc[2];
  bf16* aDst[4]; bf16* bDst[2];
#pragma unroll
  for (int it = 0; it < 4; ++it) {
    int c = it * 256 + tid;
    int r = c >> 3, q = c & 7;
    int kq = q ^ (r & 7);
    int rr = r < mLimit ? r : (mLimit - 1);
    aSrc[it] = A + (long)(m0 + rr) * HIDP + kq * 8;
    aDst[it] = As + (size_t)(it * 256 + wave * 64) * 8;
  }
#pragma unroll
  for (int it = 0; it < 2; ++it) {
    int c = it * 256 + tid;
    int r = c >> 3, q = c & 7;
    int kq = q ^ (r & 7);
    bSrc[it] = Be + (long)(n0 + r) * HIDP + kq * 8;
    bDst[it] = Bs + (size_t)(it * 256 + wave * 64) * 8;
  }

  floatx4 acc[4][2];
#pragma unroll
  for (int i = 0; i < 4; ++i)
#pragma unroll
    for (int j = 0; j < 2; ++j) { floatx4 z = {0.f, 0.f, 0.f, 0.f}; acc[i][j] = z; }

  const int wm = (wave & 1) * 64, wn = (wave >> 1) * 32;
  const int l15 = lane & 15, quad = lane >> 4;
  int aOff[4][2], bOff[2][2];
#pragma unroll
  for (int h = 0; h < 2; ++h) {
#pragma unroll
    for (int i = 0; i < 4; ++i) {
      int m = wm + i * 16 + l15;
      aOff[i][h] = (((m << 3) | ((h * 4 + quad) ^ (m & 7))) << 3);
    }
#pragma unroll
    for (int j = 0; j < 2; ++j) {
      int n = wn + j * 16 + l15;
      bOff[j][h] = (((n << 3) | ((h * 4 + quad) ^ (n & 7))) << 3);
    }
  }

  for (int kt = 0; kt < 22; ++kt) {
    __syncthreads();
#pragma unroll
    for (int it = 0; it < 4; ++it) { gld16(aSrc[it], aDst[it]); aSrc[it] += 64; }
#pragma unroll
    for (int it = 0; it < 2; ++it) { gld16(bSrc[it], bDst[it]); bSrc[it] += 64; }
    __syncthreads();
#pragma unroll
    for (int h = 0; h < 2; ++h) {
      short8 af[4];
#pragma unroll
      for (int i = 0; i < 4; ++i) af[i] = *(const short8*)(As + aOff[i][h]);
#pragma unroll
      for (int j = 0; j < 2; ++j) {
        short8 bf = *(const short8*)(Bs + bOff[j][h]);
#pragma unroll
        for (int i = 0; i < 4; ++i)
          acc[i][j] = __builtin_amdgcn_mfma_f32_16x16x32_bf16(af[i], bf, acc[i][j], 0, 0, 0);
      }
    }
  }

#pragma unroll
  for (int i = 0; i < 4; ++i) {
#pragma unroll
    for (int j = 0; j < 2; ++j) {
      int col = n0 + wn + j * 16 + l15;
#pragma unroll
      for (int r = 0; r < 4; ++r) {
        int row = wm + i * 16 + quad * 4 + r;
        if (row >= mLimit) continue;
        eo[(size_t)(m0 + row) * 1024 + col] = (bf16)(gateW[m0 + row] * acc[i][j][r]);
      }
    }
  }
}

// ------------------------------------------- V transpose: vb[t][256] -> vt[bg][d][s]
__global__ __launch_bounds__(256) void vt_kernel(
    const bf16* __restrict__ vb, bf16* __restrict__ vt) {
  __shared__ __align__(16) bf16 tile[64 * 72];
  int t0 = blockIdx.x * 64, bg = blockIdx.y;
  int b = bg >> 2, g = bg & 3;
  int tid = threadIdx.x;
  for (int c = tid; c < 512; c += 256) {
    int r = c >> 3, d8 = (c & 7) * 8;
    *(short8*)(tile + r * 72 + d8) =
        *(const short8*)(vb + (size_t)(b * SEQ + t0 + r) * 256 + g * 64 + d8);
  }
  __syncthreads();
  for (int c = tid; c < 512; c += 256) {
    int d = c >> 3, s8 = (c & 7) * 8;
    bf16 tmp[8];
#pragma unroll
    for (int x = 0; x < 8; ++x) tmp[x] = tile[(s8 + x) * 72 + d];
    *(short8*)(vt + ((size_t)bg * 64 + d) * SEQ + t0 + s8) = *(short8*)tmp;
  }
}

// ---------------------------------------------------------------- flash attention
// One q-tile per block, grid (32, NH, 2) = 1024 blocks = 4/CU (was 2/CU with
// paired tiles). q0 = (31-bx)*64: longest blocks dispatch first (LPT packing).
__global__ __launch_bounds__(256) void attn_kernel(
    const bf16* __restrict__ Q, const bf16* __restrict__ Kc, const bf16* __restrict__ Vt,
    bf16* __restrict__ AO) {
  __shared__ __align__(16) bf16 Qs[64 * 64];
  __shared__ __align__(16) bf16 Ks[64 * 64];
  __shared__ __align__(16) bf16 Vs[64 * 64];
  __shared__ __align__(16) bf16 Ps[4][16 * 64];
  const int h = blockIdx.y, b = blockIdx.z;
  const int q0 = (31 - blockIdx.x) * 64;
  const int g = h >> 2;
  const int tid = threadIdx.x, lane = tid & 63, wave = tid >> 6;
  const int l15 = lane & 15, quad = lane >> 4;

  const bf16* kSrc[2]; const bf16* vSrc[2]; bf16* kDst[2]; bf16* vDst[2];
#pragma unroll
  for (int it = 0; it < 2; ++it) {
    int c = it * 256 + tid;
    int r = c >> 3, p = c & 7;
    int kq = p ^ (r & 7);
    kSrc[it] = Kc + (size_t)(b * SEQ + r) * 256 + g * 64 + kq * 8;
    vSrc[it] = Vt + ((size_t)(b * 4 + g) * 64 + r) * SEQ + kq * 8;
    kDst[it] = Ks + (size_t)(it * 256 + wave * 64) * 8;
    vDst[it] = Vs + (size_t)(it * 256 + wave * 64) * 8;
  }

  int qOff[2], kvOff[4][2], pOff[2];
#pragma unroll
  for (int hh = 0; hh < 2; ++hh) {
    int m = wave * 16 + l15;
    qOff[hh] = (m << 6) + (((hh * 4 + quad) ^ (m & 7)) << 3);
#pragma unroll
    for (int j = 0; j < 4; ++j) {
      int n = j * 16 + l15;
      kvOff[j][hh] = (n << 6) + (((hh * 4 + quad) ^ (n & 7)) << 3);
    }
    int cblk = (hh * 2 + (quad >> 1)) ^ (l15 >> 2);
    pOff[hh] = (l15 << 6) + (cblk << 4) + ((quad & 1) << 3);
  }
  bf16* pw = &Ps[wave][0];
  const int rowl = wave * 16 + quad * 4;

  short8 onesb;
#pragma unroll
  for (int e = 0; e < 8; ++e) onesb[e] = (short)0x3F80;

#pragma unroll
  for (int it = 0; it < 2; ++it) {
    int c = it * 256 + tid;
    int r = c >> 3, p = c & 7;
    int kq = p ^ (r & 7);
    gld16(Q + (size_t)(b * SEQ + q0 + r) * DM + h * 64 + kq * 8,
          Qs + (size_t)(it * 256 + wave * 64) * 8);
  }

  floatx4 oacc[4], sumacc;
#pragma unroll
  for (int r = 0; r < 4; ++r) { floatx4 z = {0.f, 0.f, 0.f, 0.f}; oacc[r] = z; }
  { floatx4 z = {0.f, 0.f, 0.f, 0.f}; sumacc = z; }

  const int nkt = (q0 >> 6) + 1;
  for (int kt = 0; kt < nkt; ++kt) {
    __syncthreads();
#pragma unroll
    for (int it = 0; it < 2; ++it) {
      gld16(kSrc[it] + (size_t)kt * 64 * 256, kDst[it]);
      gld16(vSrc[it] + kt * 64, vDst[it]);
    }
    __syncthreads();

    floatx4 sacc[4];
#pragma unroll
    for (int j = 0; j < 4; ++j) { floatx4 z = {0.f, 0.f, 0.f, 0.f}; sacc[j] = z; }
#pragma unroll
    for (int hh = 0; hh < 2; ++hh) {
      short8 aq = *(const short8*)(Qs + qOff[hh]);
#pragma unroll
      for (int j = 0; j < 4; ++j)
        sacc[j] = __builtin_amdgcn_mfma_f32_16x16x32_bf16(
            aq, *(const short8*)(Ks + kvOff[j][hh]), sacc[j], 0, 0, 0);
    }

    const bool lastTile = (kt == nkt - 1);
#pragma unroll
    for (int j = 0; j < 4; ++j) {
      int sw = ((j ^ quad) << 4) + l15;
      int colg = j * 16 + l15;
#pragma unroll
      for (int r = 0; r < 4; ++r) {
        float p = __expf(sacc[j][r]);
        if (lastTile && colg > rowl + r) p = 0.f;
        pw[(quad * 4 + r) * 64 + sw] = (bf16)p;
      }
    }
    asm volatile("s_waitcnt lgkmcnt(0)" ::: "memory");
#pragma unroll
    for (int hh = 0; hh < 2; ++hh) {
      short8 ap = *(const short8*)(pw + pOff[hh]);
#pragma unroll
      for (int j = 0; j < 4; ++j)
        oacc[j] = __builtin_amdgcn_mfma_f32_16x16x32_bf16(
            ap, *(const short8*)(Vs + kvOff[j][hh]), oacc[j], 0, 0, 0);
      sumacc = __builtin_amdgcn_mfma_f32_16x16x32_bf16(ap, onesb, sumacc, 0, 0, 0);
    }
  }

  float inv[4];
#pragma unroll
  for (int r = 0; r < 4; ++r) inv[r] = 1.f / sumacc[r];
#pragma unroll
  for (int j = 0; j < 4; ++j)
#pragma unroll
    for (int r = 0; r < 4; ++r) {
      int t = b * SEQ + q0 + rowl + r;
      AO[(size_t)t * DM + h * 64 + j * 16 + l15] = (bf16)(oacc[j][r] * inv[r]);
    }
}

// ------------------------------------------------- capacity assignment (9 blocks)
// blocks 0..7: per-expert compaction; block 8: identity fill for shared slots
__global__ __launch_bounds__(256) void assign_kernel(
    const int* __restrict__ tIdx, const float* __restrict__ tW,
    int* __restrict__ tokList, float* __restrict__ gateW,
    int* __restrict__ neCnt, int* __restrict__ cntFull, int* __restrict__ slotOf) {
  int e = blockIdx.x;
  int tid = threadIdx.x, lane = tid & 63, wv = tid >> 6;
  if (e == 8) {
    for (int t = tid; t < TTOK; t += 256) {
      tokList[NSLOT + t] = t;
      gateW[NSLOT + t] = 1.0f;
    }
    if (tid == 0) neCnt[8] = TTOK;
    return;
  }
  __shared__ int waveTot[4];
  __shared__ int offs;
  if (tid == 0) offs = 0;
  __syncthreads();
  for (int base = 0; base < TTOK; base += 256) {
    int t = base + tid;
    int a = tIdx[t * 2], b2 = tIdx[t * 2 + 1];
    bool sel = (a == e) || (b2 == e);
    unsigned long long mask = __ballot(sel);
    int wrank = __popcll(mask & ((1ull << lane) - 1ull));
    if (lane == 0) waveTot[wv] = __popcll(mask);
    __syncthreads();
    int pre = offs;
    for (int w2 = 0; w2 < wv; ++w2) pre += waveTot[w2];
    int rank = pre + wrank;
    if (sel && rank < CAPT) {
      int slot = e * CAPT + rank;
      tokList[slot] = t;
      gateW[slot] = (a == e) ? tW[t * 2] : tW[t * 2 + 1];
      slotOf[t * 2 + ((a == e) ? 0 : 1)] = slot;
    }
    __syncthreads();
    if (tid == 0) offs += waveTot[0] + waveTot[1] + waveTot[2] + waveTot[3];
    __syncthreads();
  }
  if (tid == 0) {
    cntFull[e] = offs;
    neCnt[e] = offs < CAPT ? offs : CAPT;
  }
}

// ---------------------------------------------------------------- aux loss / util
__global__ __launch_bounds__(256) void aux_kernel(
    const float* __restrict__ probs, const int* __restrict__ cntFull,
    float* __restrict__ outAux) {
  __shared__ float psum[8];
  if (threadIdx.x < 8) psum[threadIdx.x] = 0.f;
  __syncthreads();
  float lp[8] = {0, 0, 0, 0, 0, 0, 0, 0};
  for (int t = threadIdx.x; t < TTOK; t += 256) {
#pragma unroll
    for (int e = 0; e < 8; ++e) lp[e] += probs[t * 8 + e];
  }
#pragma unroll
  for (int e = 0; e < 8; ++e)
#pragma unroll
    for (int off = 1; off < 64; off <<= 1) lp[e] += __shfl_xor(lp[e], off);
  if ((threadIdx.x & 63) == 0)
#pragma unroll
    for (int e = 0; e < 8; ++e) atomicAdd(&psum[e], lp[e]);
  __syncthreads();
  if (threadIdx.x == 0) {
    float aux = 0.f; int used = 0;
    for (int e = 0; e < 8; ++e) {
      aux += (psum[e] / (float)TTOK) * ((float)cntFull[e] / (float)TTOK);
      if (cntFull[e] > 0) used++;
    }
    outAux[0] = 8.f * aux;
    outAux[1] = 100.f * (float)used / 8.f;
  }
}

// ------------------------- combine: out = hbuf + shared eo + <=2 gated eo rows
__global__ __launch_bounds__(256) void combine_kernel(
    float* __restrict__ outp, const float* __restrict__ hbuf,
    const bf16* __restrict__ eo, const int* __restrict__ slotOf) {
  int t = blockIdx.x, tid = threadIdx.x;
  float4 v = ((const float4*)(hbuf + (size_t)t * DM))[tid];
  bf4 sh = ((const bf4*)(eo + (size_t)(NSLOT + t) * DM))[tid];
  v.x += (float)sh.x; v.y += (float)sh.y; v.z += (float)sh.z; v.w += (float)sh.w;
  int s0 = slotOf[t * 2], s1 = slotOf[t * 2 + 1];
  if (s0 >= 0) {
    bf4 e = ((const bf4*)(eo + (size_t)s0 * DM))[tid];
    v.x += (float)e.x; v.y += (float)e.y; v.z += (float)e.z; v.w += (float)e.w;
  }
  if (s1 >= 0) {
    bf4 e = ((const bf4*)(eo + (size_t)s1 * DM))[tid];
    v.x += (float)e.x; v.y += (float)e.y; v.z += (float)e.z; v.w += (float)e.w;
  }
  ((float4*)(outp + (size_t)t * DM))[tid] = v;
}

// ---------------------------------------------------------------- launch
extern "C" void kernel_launch(void* const* d_in, const int* in_sizes, int n_in,
                              void* d_out, int out_size, void* d_ws, size_t ws_size,
                              hipStream_t stream) {
  (void)in_sizes; (void)n_in; (void)out_size; (void)ws_size;
  const float* x     = (const float*)d_in[0];
  const float* cosb  = (const float*)d_in[1];
  const float* sinb  = (const float*)d_in[2];
  const float* attnw = (const float*)d_in[4];
  const float* moew  = (const float*)d_in[5];
  const float* wq  = (const float*)d_in[6];
  const float* wk  = (const float*)d_in[7];
  const float* wv  = (const float*)d_in[8];
  const float* wo  = (const float*)d_in[9];
  const float* rw  = (const float*)d_in[10];
  const float* ew1 = (const float*)d_in[11];
  const float* ew2 = (const float*)d_in[12];
  const float* ew3 = (const float*)d_in[13];
  const float* sw1 = (const float*)d_in[14];
  const float* sw2 = (const float*)d_in[15];
  const float* sw3 = (const float*)d_in[16];

  float* outp = (float*)d_out;
  float* auxp = outp + 4194304;
  float* newk = outp + 4194306;
  float* newv = newk + 1048576;

  char* wsp = (char*)d_ws;
  size_t off = 0;
  auto alloc = [&](size_t bytes) -> void* {
    void* p = wsp + off; off += (bytes + 255) & ~(size_t)255; return p;
  };
  bf16* wqkvT = (bf16*)alloc((size_t)1536 * 1024 * 2);
  bf16* woT   = (bf16*)alloc((size_t)1024 * 1024 * 2);
  bf16* ew1T  = (bf16*)alloc((size_t)9 * HIDDEN * 1024 * 2);   // slice 8 = sw1
  bf16* ew3T  = (bf16*)alloc((size_t)9 * HIDDEN * 1024 * 2);   // slice 8 = sw3
  bf16* ew2T  = (bf16*)alloc((size_t)9 * 1024 * HIDP * 2);     // slice 8 = sw2
  bf16* xn    = (bf16*)alloc((size_t)TTOK * DM * 2);
  bf16* qb    = (bf16*)alloc((size_t)TTOK * DM * 2);
  bf16* kb    = (bf16*)alloc((size_t)TTOK * 256 * 2);
  bf16* vb    = (bf16*)alloc((size_t)TTOK * 256 * 2);
  bf16* vt    = (bf16*)alloc((size_t)TTOK * 256 * 2);
  bf16* ao    = (bf16*)alloc((size_t)TTOK * DM * 2);
  float* hbuf = (float*)alloc((size_t)TTOK * DM * 4);
  bf16* hn    = (bf16*)alloc((size_t)TTOK * DM * 2);
  float* probs = (float*)alloc((size_t)TTOK * 8 * 4);
  int*   tIdx  = (int*)alloc((size_t)TTOK * 2 * 4);
  float* tW    = (float*)alloc((size_t)TTOK * 2 * 4);
  int*   tokList = (int*)alloc((size_t)TSLOT * 4);
  float* gateW   = (float*)alloc((size_t)TSLOT * 4);
  int*   neCnt   = (int*)alloc(64);
  int*   cntFull = (int*)alloc(64);
  int*   slotOf  = (int*)alloc((size_t)TTOK * 2 * 4);
  bf16*  mact = (bf16*)alloc((size_t)TSLOT * HIDP * 2);
  bf16*  eo   = (bf16*)alloc((size_t)TSLOT * DM * 2);

  EpiAux nil{};
  EpiAux ropeAux{cosb, sinb, qb, kb, vb, newk, newv};

  // ---- weight convert + transpose (r0 grids)
  transpose_cvt<<<dim3(16, 16, 1), 256, 0, stream>>>(wq, wqkvT, 1024, 1024, 1024, 0, 0);
  transpose_cvt<<<dim3(4, 16, 1), 256, 0, stream>>>(wk, wqkvT + (size_t)1024 * 1024, 1024, 256, 1024, 0, 0);
  transpose_cvt<<<dim3(4, 16, 1), 256, 0, stream>>>(wv, wqkvT + (size_t)1280 * 1024, 1024, 256, 1024, 0, 0);
  transpose_cvt<<<dim3(16, 16, 1), 256, 0, stream>>>(wo, woT, 1024, 1024, 1024, 0, 0);
  transpose_cvt<<<dim3(22, 16, NEXP), 256, 0, stream>>>(ew1, ew1T, 1024, HIDDEN, 1024,
      (long)1024 * HIDDEN, (long)HIDDEN * 1024);
  transpose_cvt<<<dim3(22, 16, NEXP), 256, 0, stream>>>(ew3, ew3T, 1024, HIDDEN, 1024,
      (long)1024 * HIDDEN, (long)HIDDEN * 1024);
  transpose_cvt<<<dim3(16, 22, NEXP), 256, 0, stream>>>(ew2, ew2T, HIDDEN, 1024, HIDP,
      (long)HIDDEN * 1024, (long)1024 * HIDP);
  transpose_cvt<<<dim3(22, 16, 1), 256, 0, stream>>>(sw1, ew1T + (size_t)8 * HIDDEN * 1024,
      1024, HIDDEN, 1024, 0, 0);
  transpose_cvt<<<dim3(22, 16, 1), 256, 0, stream>>>(sw3, ew3T + (size_t)8 * HIDDEN * 1024,
      1024, HIDDEN, 1024, 0, 0);
  transpose_cvt<<<dim3(16, 22, 1), 256, 0, stream>>>(sw2, ew2T + (size_t)8 * 1024 * HIDP,
      HIDDEN, 1024, HIDP, 0, 0);

  // ---- attention path (64-row M-tiles: xPerXcd = 4096/64/8 = 8)
  rmsnorm_kernel<<<TTOK, 256, 0, stream>>>(x, attnw, xn);
  gemm_bt<4><<<8 * 8 * 12, 256, 0, stream>>>(
      xn, wqkvT, TTOK, 1536, 1024, 1024, 1024, 8, nullptr, 0, nullptr, ropeAux);
  vt_kernel<<<dim3(32, 8), 256, 0, stream>>>(vb, vt);
  attn_kernel<<<dim3(32, NHEAD, 2), 256, 0, stream>>>(qb, kb, vt, ao);
  gemm_bt<2><<<8 * 8 * 8, 256, 0, stream>>>(
      ao, woT, TTOK, 1024, 1024, 1024, 1024, 8, hbuf, 1024, x, nil);

  // ---- MoE routing
  rmsnorm_router_kernel<<<TTOK, 256, 0, stream>>>(hbuf, moew, rw, hn, probs, tIdx, tW);
  hipMemsetAsync(slotOf, 0xFF, (size_t)TTOK * 2 * 4, stream);
  assign_kernel<<<9, 256, 0, stream>>>(tIdx, tW, tokList, gateW, neCnt, cntFull, slotOf);
  aux_kernel<<<1, 256, 0, stream>>>(probs, cntFull, auxp);

  // ---- experts (8 routed + shared as expert 8)
  gemm_dual9<<<8 * XBT * 11, 256, 0, stream>>>(hn, ew1T, ew3T, mact, tokList, neCnt);
  gemm_down9<<<8 * XBT * 16, 256, 0, stream>>>(mact, ew2T, eo, gateW, neCnt);
  combine_kernel<<<TTOK, 256, 0, stream>>>(outp, hbuf, eo, slotOf);
}

// Round 9
// 562.070 us; speedup vs baseline: 1.0565x; 1.0300x over previous
//
#include <hip/hip_runtime.h>
#include <hip/hip_bf16.h>
#include <math.h>

typedef __hip_bfloat16 bf16;
typedef __attribute__((ext_vector_type(8))) short short8;
typedef __attribute__((ext_vector_type(4))) float floatx4;

#define SEQ    2048
#define TTOK   4096
#define DM     1024
#define NHEAD  16
#define NKVH   4
#define HD     64
#define NEXP   8
#define HIDDEN 1365
#define HIDP   1408
#define CAPT   1280
#define NSLOT  (NEXP*CAPT)      /* 10240 routed slots */
#define TSLOT  (NSLOT+TTOK)     /* 14336: + shared-expert identity slots */
#define XPE    (CAPT/128)       /* 10 routed 128-row M-blocks per expert */
#define XBT    14               /* per-XCD 128-row M-blocks: 10 routed + 4 shared */

// ---------------------------------------------------------------- utilities
__device__ __forceinline__ void gld16(const void* g, void* l) {
  __builtin_amdgcn_global_load_lds((const __attribute__((address_space(1))) void*)g,
                                   (__attribute__((address_space(3))) void*)l,
                                   16, 0, 0);
}

struct __align__(8) bf4 { bf16 x, y, z, w; };

struct EpiAux {
  const float* cosb; const float* sinb;
  bf16* qb; bf16* kb; bf16* vb; float* newk; float* newv;
};

// ---------------------------------------------------- weight convert+transpose
// src: (K,N) f32 row-major -> dst: (N,Kp) bf16 row-major, zero-fill k in [K,Kp)
__global__ __launch_bounds__(256) void transpose_cvt(
    const float* __restrict__ src, bf16* __restrict__ dst,
    int K, int N, int Kp, long srcZ, long dstZ) {
  src += (size_t)blockIdx.z * srcZ;
  dst += (size_t)blockIdx.z * dstZ;
  __shared__ float tile[64][65];
  const int tid = threadIdx.x;
  const int k0 = blockIdx.y * 64, n0 = blockIdx.x * 64;
  const int lr = tid >> 4, lc = (tid & 15) * 4;
#pragma unroll
  for (int i = 0; i < 4; ++i) {
    int k = k0 + lr + i * 16;
    int n = n0 + lc;
    float4 v = {0.f, 0.f, 0.f, 0.f};
    if (k < K) {
      if (n + 3 < N) v = *(const float4*)(src + (size_t)k * N + n);
      else {
        float* vp = (float*)&v;
        for (int e = 0; e < 4; ++e) if (n + e < N) vp[e] = src[(size_t)k * N + n + e];
      }
    }
    tile[lr + i * 16][lc] = v.x; tile[lr + i * 16][lc + 1] = v.y;
    tile[lr + i * 16][lc + 2] = v.z; tile[lr + i * 16][lc + 3] = v.w;
  }
  __syncthreads();
  const int n = tid >> 2, kk0 = (tid & 3) * 16;
  if (n0 + n < N) {
    bf16 buf[16];
#pragma unroll
    for (int e = 0; e < 16; ++e) buf[e] = (bf16)tile[kk0 + e][n];
    bf16* dp = dst + (size_t)(n0 + n) * Kp + k0 + kk0;
    *(short8*)dp = *(short8*)buf;
    *(short8*)(dp + 8) = *(short8*)(buf + 8);
  }
}

// ---------------------------------------------------------------- rmsnorm
__global__ __launch_bounds__(256) void rmsnorm_kernel(
    const float* __restrict__ x, const float* __restrict__ w, bf16* __restrict__ out) {
  int t = blockIdx.x;
  const float* xr = x + (size_t)t * DM;
  float4 xv = *(const float4*)(xr + threadIdx.x * 4);
  float ss = xv.x * xv.x + xv.y * xv.y + xv.z * xv.z + xv.w * xv.w;
#pragma unroll
  for (int off = 1; off < 64; off <<= 1) ss += __shfl_xor(ss, off);
  __shared__ float sred[4];
  if ((threadIdx.x & 63) == 0) sred[threadIdx.x >> 6] = ss;
  __syncthreads();
  float scale = rsqrtf((sred[0] + sred[1] + sred[2] + sred[3]) * (1.f / DM) + 1e-6f);
  float4 wv = *(const float4*)(w + threadIdx.x * 4);
  bf4 o;
  o.x = (bf16)(xv.x * scale * wv.x); o.y = (bf16)(xv.y * scale * wv.y);
  o.z = (bf16)(xv.z * scale * wv.z); o.w = (bf16)(xv.w * scale * wv.w);
  ((bf4*)(out + (size_t)t * DM))[threadIdx.x] = o;
}

// -------------------------------------------- rmsnorm + router (moe path)
__global__ __launch_bounds__(256) void rmsnorm_router_kernel(
    const float* __restrict__ x, const float* __restrict__ w, const float* __restrict__ rw,
    bf16* __restrict__ out, float* __restrict__ probs,
    int* __restrict__ tIdx, float* __restrict__ tW) {
  int t = blockIdx.x;
  int tid = threadIdx.x, lane = tid & 63, wv = tid >> 6;
  const float* xr = x + (size_t)t * DM;
  float4 xv = *(const float4*)(xr + tid * 4);
  float ss = xv.x * xv.x + xv.y * xv.y + xv.z * xv.z + xv.w * xv.w;
#pragma unroll
  for (int off = 1; off < 64; off <<= 1) ss += __shfl_xor(ss, off);
  __shared__ float sred[4];
  __shared__ float red[4][8];
  if (lane == 0) sred[wv] = ss;
  __syncthreads();
  float scale = rsqrtf((sred[0] + sred[1] + sred[2] + sred[3]) * (1.f / DM) + 1e-6f);
  float4 wvv = *(const float4*)(w + tid * 4);
  float y[4] = {xv.x * scale * wvv.x, xv.y * scale * wvv.y,
                xv.z * scale * wvv.z, xv.w * scale * wvv.w};
  bf4 o; o.x = (bf16)y[0]; o.y = (bf16)y[1]; o.z = (bf16)y[2]; o.w = (bf16)y[3];
  ((bf4*)(out + (size_t)t * DM))[tid] = o;
  float acc[8] = {0, 0, 0, 0, 0, 0, 0, 0};
#pragma unroll
  for (int dd = 0; dd < 4; ++dd) {
    const float* rwr = rw + (size_t)(tid * 4 + dd) * 8;
#pragma unroll
    for (int e = 0; e < 8; ++e) acc[e] += y[dd] * rwr[e];
  }
#pragma unroll
  for (int e = 0; e < 8; ++e)
#pragma unroll
    for (int off = 1; off < 64; off <<= 1) acc[e] += __shfl_xor(acc[e], off);
  if (lane == 0)
#pragma unroll
    for (int e = 0; e < 8; ++e) red[wv][e] = acc[e];
  __syncthreads();
  if (tid == 0) {
    float lg[8];
#pragma unroll
    for (int e = 0; e < 8; ++e) lg[e] = red[0][e] + red[1][e] + red[2][e] + red[3][e];
    float mx = lg[0];
#pragma unroll
    for (int e = 1; e < 8; ++e) mx = fmaxf(mx, lg[e]);
    float p[8], se = 0.f;
#pragma unroll
    for (int e = 0; e < 8; ++e) { p[e] = __expf(lg[e] - mx); se += p[e]; }
#pragma unroll
    for (int e = 0; e < 8; ++e) { p[e] /= se; probs[t * 8 + e] = p[e]; }
    int i1 = 0;
#pragma unroll
    for (int e = 1; e < 8; ++e) if (p[e] > p[i1]) i1 = e;
    int i2 = (i1 == 0) ? 1 : 0;
#pragma unroll
    for (int e = 0; e < 8; ++e) if (e != i1 && p[e] > p[i2]) i2 = e;
    float s = p[i1] + p[i2];
    tIdx[t * 2] = i1; tIdx[t * 2 + 1] = i2;
    tW[t * 2] = p[i1] / s; tW[t * 2 + 1] = p[i2] / s;
  }
}

// ---------------------------------------------------------------- dense GEMM
// 64x128 tile (2 M-frags/wave): doubles grid vs 128x128 so QKV gets 3 blocks/CU
// and WO 2 blocks/CU (was 1.5 / 1.0 — latency-bound). Same inner loop/layout.
// EPI: 2 = Cf = resid + acc ; 4 = QKV+rope.
template <int EPI>
__global__ __launch_bounds__(256) void gemm_bt(
    const bf16* __restrict__ A, const bf16* __restrict__ Bt,
    int M, int N, int K, int lda, int ldb, int xPerXcd,
    float* __restrict__ Cf, int ldc,
    const float* __restrict__ resid, EpiAux aux) {
  __shared__ __align__(16) bf16 As[64 * 64];
  __shared__ __align__(16) bf16 Bs[128 * 64];
  const int tid = threadIdx.x, lane = tid & 63, wave = tid >> 6;
  const int f = blockIdx.x, lo = f >> 3;
  int xb = (f & 7) * xPerXcd + lo % xPerXcd;
  int n0 = (lo / xPerXcd) * 128;
  int m0 = xb * 64;

  const bf16* aSrc[2]; const bf16* bSrc[4];
  bf16* aDst[2]; bf16* bDst[4];
#pragma unroll
  for (int it = 0; it < 2; ++it) {
    int c = it * 256 + tid;
    int r = c >> 3, q = c & 7;
    int kq = q ^ (r & 7);
    aSrc[it] = A + (long)(m0 + r) * lda + kq * 8;
    aDst[it] = As + (size_t)(it * 256 + wave * 64) * 8;
  }
#pragma unroll
  for (int it = 0; it < 4; ++it) {
    int c = it * 256 + tid;
    int r = c >> 3, q = c & 7;
    int kq = q ^ (r & 7);
    bSrc[it] = Bt + (long)(n0 + r) * ldb + kq * 8;
    bDst[it] = Bs + (size_t)(it * 256 + wave * 64) * 8;
  }

  floatx4 acc[2][4];
#pragma unroll
  for (int i = 0; i < 2; ++i)
#pragma unroll
    for (int j = 0; j < 4; ++j) { floatx4 z = {0.f, 0.f, 0.f, 0.f}; acc[i][j] = z; }

  const int wm = (wave & 1) * 32, wn = (wave >> 1) * 64;
  const int l15 = lane & 15, quad = lane >> 4;
  int aOff[2][2], bOff[4][2];
#pragma unroll
  for (int h = 0; h < 2; ++h) {
#pragma unroll
    for (int i = 0; i < 2; ++i) {
      int m = wm + i * 16 + l15;
      aOff[i][h] = (((m << 3) | ((h * 4 + quad) ^ (m & 7))) << 3);
    }
#pragma unroll
    for (int j = 0; j < 4; ++j) {
      int n = wn + j * 16 + l15;
      bOff[j][h] = (((n << 3) | ((h * 4 + quad) ^ (n & 7))) << 3);
    }
  }

  const int kIters = K >> 6;
  for (int kt = 0; kt < kIters; ++kt) {
    __syncthreads();
#pragma unroll
    for (int it = 0; it < 2; ++it) { gld16(aSrc[it], aDst[it]); aSrc[it] += 64; }
#pragma unroll
    for (int it = 0; it < 4; ++it) { gld16(bSrc[it], bDst[it]); bSrc[it] += 64; }
    __syncthreads();
#pragma unroll
    for (int h = 0; h < 2; ++h) {
      short8 af[2], bfr[4];
#pragma unroll
      for (int i = 0; i < 2; ++i) af[i] = *(const short8*)(As + aOff[i][h]);
#pragma unroll
      for (int j = 0; j < 4; ++j) bfr[j] = *(const short8*)(Bs + bOff[j][h]);
#pragma unroll
      for (int i = 0; i < 2; ++i)
#pragma unroll
        for (int j = 0; j < 4; ++j)
          acc[i][j] = __builtin_amdgcn_mfma_f32_16x16x32_bf16(af[i], bfr[j], acc[i][j], 0, 0, 0);
    }
  }

  if constexpr (EPI == 4) {
#pragma unroll
    for (int i = 0; i < 2; ++i) {
#pragma unroll
      for (int r = 0; r < 4; ++r) {
        int row = wm + i * 16 + quad * 4 + r;
        int t = m0 + row;
        int s = t & (SEQ - 1);
        if (n0 < 1024) {
#pragma unroll
          for (int j = 0; j < 2; ++j) {
            int col = n0 + wn + j * 16 + l15;
            int dlo = col & 63;
            float x1 = acc[i][j][r], x2 = acc[i][j + 2][r];
            float ch = aux.cosb[s * 64 + dlo], sh = aux.sinb[s * 64 + dlo];
            aux.qb[(size_t)t * DM + col]      = (bf16)((x1 * ch - x2 * sh) * 0.125f);
            aux.qb[(size_t)t * DM + col + 32] = (bf16)((x1 * sh + x2 * ch) * 0.125f);
          }
        } else if (n0 < 1280) {
#pragma unroll
          for (int j = 0; j < 2; ++j) {
            int ck = n0 + wn + j * 16 + l15 - 1024;
            int dlo = ck & 63;
            float x1 = acc[i][j][r], x2 = acc[i][j + 2][r];
            float ch = aux.cosb[s * 64 + dlo], sh = aux.sinb[s * 64 + dlo];
            float o1 = x1 * ch - x2 * sh, o2 = x1 * sh + x2 * ch;
            aux.kb[(size_t)t * 256 + ck]        = (bf16)o1;
            aux.kb[(size_t)t * 256 + ck + 32]   = (bf16)o2;
            aux.newk[(size_t)t * 256 + ck]      = o1;
            aux.newk[(size_t)t * 256 + ck + 32] = o2;
          }
        } else {
#pragma unroll
          for (int j = 0; j < 4; ++j) {
            int cv = n0 + wn + j * 16 + l15 - 1280;
            float v = acc[i][j][r];
            aux.vb[(size_t)t * 256 + cv]   = (bf16)v;
            aux.newv[(size_t)t * 256 + cv] = v;
          }
        }
      }
    }
    return;
  }
#pragma unroll
  for (int i = 0; i < 2; ++i) {
#pragma unroll
    for (int j = 0; j < 4; ++j) {
      int col = n0 + wn + j * 16 + l15;
#pragma unroll
      for (int r = 0; r < 4; ++r) {
        int row = wm + i * 16 + quad * 4 + r;
        size_t o = (size_t)(m0 + row) * ldc + col;
        Cf[o] = resid[o] + acc[i][j][r];
      }
    }
  }
}

// --------------------------------------------------- slot-block decode helper
// f&7 = xcd; lo = f>>3 = xb_local*NY + y ; xb_local<XPE -> routed expert=xcd,
// else shared block (expert 8). Returns false if block has no work.
// n0 is returned in units of 64 cols (y*64); caller scales for wider N-tiles.
__device__ __forceinline__ bool slot_block(
    int f, int NY, const int* neCnt, int& expert, int& m0, int& mLimit, int& n0) {
  int xcd = f & 7, lo = f >> 3;
  int xb = lo / NY, y = lo % NY;
  n0 = y * 64;
  if (xb < XPE) {
    expert = xcd;
    int ne = neCnt[xcd];
    if (xb * 128 >= ne) return false;
    m0 = xcd * CAPT + xb * 128;
    mLimit = ne - xb * 128;
    if (mLimit > 128) mLimit = 128;
  } else {
    expert = 8;
    int sb = xcd * 4 + (xb - XPE);
    m0 = NSLOT + sb * 128;
    mLimit = 128;
  }
  return true;
}

// ------------------------------------------------------ MoE dual GEMM + swiglu
// 128x128 tile, dual-B (B1,B3 share the staged A): 48 KB LDS, 256 thr / 4 waves,
// m97-style 2-barrier schedule. ~800 TF measured (r3) — near structural ceiling.
__global__ __launch_bounds__(256, 2) void gemm_dual9(
    const bf16* __restrict__ A, const bf16* __restrict__ B1t, const bf16* __restrict__ B3t,
    bf16* __restrict__ mact,
    const int* __restrict__ tokList, const int* __restrict__ neCnt) {
  __shared__ __align__(16) bf16 As[128 * 64];
  __shared__ __align__(16) bf16 B1s[128 * 64];
  __shared__ __align__(16) bf16 B3s[128 * 64];
  const int tid = threadIdx.x, lane = tid & 63, wave = tid >> 6;
  int expert, m0, mLimit, n0;
  if (!slot_block(blockIdx.x, 11, neCnt, expert, m0, mLimit, n0)) return;
  n0 <<= 1;  // 128-wide N-tiles
  const bf16* B1e = B1t + (long)expert * (HIDDEN * 1024);
  const bf16* B3e = B3t + (long)expert * (HIDDEN * 1024);

  const bf16* aSrc[4]; const bf16* b1Src[4]; const bf16* b3Src[4];
  bf16* aDst[4]; bf16* b1Dst[4]; bf16* b3Dst[4];
#pragma unroll
  for (int it = 0; it < 4; ++it) {
    int c = it * 256 + tid;
    int r = c >> 3, q = c & 7;
    int kq = q ^ (r & 7);
    int rr = r < mLimit ? r : (mLimit - 1);
    aSrc[it] = A + (long)tokList[m0 + rr] * 1024 + kq * 8;
    aDst[it] = As + (size_t)(it * 256 + wave * 64) * 8;
    int nn = n0 + r; if (nn > HIDDEN - 1) nn = HIDDEN - 1;
    b1Src[it] = B1e + (long)nn * 1024 + kq * 8;
    b3Src[it] = B3e + (long)nn * 1024 + kq * 8;
    b1Dst[it] = B1s + (size_t)(it * 256 + wave * 64) * 8;
    b3Dst[it] = B3s + (size_t)(it * 256 + wave * 64) * 8;
  }

  floatx4 acc1[4][4], acc3[4][4];
#pragma unroll
  for (int i = 0; i < 4; ++i)
#pragma unroll
    for (int j = 0; j < 4; ++j) {
      floatx4 z = {0.f, 0.f, 0.f, 0.f};
      acc1[i][j] = z; acc3[i][j] = z;
    }

  const int wm = (wave & 1) * 64, wn = (wave >> 1) * 64;
  const int l15 = lane & 15, quad = lane >> 4;
  int aOff[4][2], bOff[4][2];
#pragma unroll
  for (int h = 0; h < 2; ++h) {
#pragma unroll
    for (int i = 0; i < 4; ++i) {
      int m = wm + i * 16 + l15;
      aOff[i][h] = (((m << 3) | ((h * 4 + quad) ^ (m & 7))) << 3);
    }
#pragma unroll
    for (int j = 0; j < 4; ++j) {
      int n = wn + j * 16 + l15;
      bOff[j][h] = (((n << 3) | ((h * 4 + quad) ^ (n & 7))) << 3);
    }
  }

  for (int kt = 0; kt < 16; ++kt) {
    __syncthreads();
#pragma unroll
    for (int it = 0; it < 4; ++it) { gld16(aSrc[it], aDst[it]); aSrc[it] += 64; }
#pragma unroll
    for (int it = 0; it < 4; ++it) {
      gld16(b1Src[it], b1Dst[it]); b1Src[it] += 64;
      gld16(b3Src[it], b3Dst[it]); b3Src[it] += 64;
    }
    __syncthreads();
#pragma unroll
    for (int h = 0; h < 2; ++h) {
      short8 af[4];
#pragma unroll
      for (int i = 0; i < 4; ++i) af[i] = *(const short8*)(As + aOff[i][h]);
#pragma unroll
      for (int j = 0; j < 4; ++j) {
        short8 b1f = *(const short8*)(B1s + bOff[j][h]);
        short8 b3f = *(const short8*)(B3s + bOff[j][h]);
#pragma unroll
        for (int i = 0; i < 4; ++i) {
          acc1[i][j] = __builtin_amdgcn_mfma_f32_16x16x32_bf16(af[i], b1f, acc1[i][j], 0, 0, 0);
          acc3[i][j] = __builtin_amdgcn_mfma_f32_16x16x32_bf16(af[i], b3f, acc3[i][j], 0, 0, 0);
        }
      }
    }
  }

#pragma unroll
  for (int i = 0; i < 4; ++i) {
#pragma unroll
    for (int j = 0; j < 4; ++j) {
      int col = n0 + wn + j * 16 + l15;
#pragma unroll
      for (int r = 0; r < 4; ++r) {
        int row = wm + i * 16 + quad * 4 + r;
        if (row >= mLimit) continue;
        float a1 = acc1[i][j][r], a3 = acc3[i][j][r];
        float sl = a1 / (1.f + __expf(-a1));
        mact[(size_t)(m0 + row) * HIDP + col] = (col < HIDDEN) ? (bf16)(sl * a3) : (bf16)0.f;
      }
    }
  }
}

// ------------------------------------------------------ MoE down GEMM (gated)
// 128x64 tile (r0 version — best measured); A = mact slots (no gather);
// eo[slot] = gateW[slot] * (A@ew2^T)
__global__ __launch_bounds__(256) void gemm_down9(
    const bf16* __restrict__ A, const bf16* __restrict__ B2t,
    bf16* __restrict__ eo,
    const float* __restrict__ gateW, const int* __restrict__ neCnt) {
  __shared__ __align__(16) bf16 As[128 * 64];
  __shared__ __align__(16) bf16 Bs[64 * 64];
  const int tid = threadIdx.x, lane = tid & 63, wave = tid >> 6;
  int expert, m0, mLimit, n0;
  if (!slot_block(blockIdx.x, 16, neCnt, expert, m0, mLimit, n0)) return;
  const bf16* Be = B2t + (long)expert * (1024 * HIDP);

  const bf16* aSrc[4]; const bf16* bSrc[2];
  bf16* aDst[4]; bf16* bDst[2];
#pragma unroll
  for (int it = 0; it < 4; ++it) {
    int c = it * 256 + tid;
    int r = c >> 3, q = c & 7;
    int kq = q ^ (r & 7);
    int rr = r < mLimit ? r : (mLimit - 1);
    aSrc[it] = A + (long)(m0 + rr) * HIDP + kq * 8;
    aDst[it] = As + (size_t)(it * 256 + wave * 64) * 8;
  }
#pragma unroll
  for (int it = 0; it < 2; ++it) {
    int c = it * 256 + tid;
    int r = c >> 3, q = c & 7;
    int kq = q ^ (r & 7);
    bSrc[it] = Be + (long)(n0 + r) * HIDP + kq * 8;
    bDst[it] = Bs + (size_t)(it * 256 + wave * 64) * 8;
  }

  floatx4 acc[4][2];
#pragma unroll
  for (int i = 0; i < 4; ++i)
#pragma unroll
    for (int j = 0; j < 2; ++j) { floatx4 z = {0.f, 0.f, 0.f, 0.f}; acc[i][j] = z; }

  const int wm = (wave & 1) * 64, wn = (wave >> 1) * 32;
  const int l15 = lane & 15, quad = lane >> 4;
  int aOff[4][2], bOff[2][2];
#pragma unroll
  for (int h = 0; h < 2; ++h) {
#pragma unroll
    for (int i = 0; i < 4; ++i) {
      int m = wm + i * 16 + l15;
      aOff[i][h] = (((m << 3) | ((h * 4 + quad) ^ (m & 7))) << 3);
    }
#pragma unroll
    for (int j = 0; j < 2; ++j) {
      int n = wn + j * 16 + l15;
      bOff[j][h] = (((n << 3) | ((h * 4 + quad) ^ (n & 7))) << 3);
    }
  }

  for (int kt = 0; kt < 22; ++kt) {
    __syncthreads();
#pragma unroll
    for (int it = 0; it < 4; ++it) { gld16(aSrc[it], aDst[it]); aSrc[it] += 64; }
#pragma unroll
    for (int it = 0; it < 2; ++it) { gld16(bSrc[it], bDst[it]); bSrc[it] += 64; }
    __syncthreads();
#pragma unroll
    for (int h = 0; h < 2; ++h) {
      short8 af[4];
#pragma unroll
      for (int i = 0; i < 4; ++i) af[i] = *(const short8*)(As + aOff[i][h]);
#pragma unroll
      for (int j = 0; j < 2; ++j) {
        short8 bf = *(const short8*)(Bs + bOff[j][h]);
#pragma unroll
        for (int i = 0; i < 4; ++i)
          acc[i][j] = __builtin_amdgcn_mfma_f32_16x16x32_bf16(af[i], bf, acc[i][j], 0, 0, 0);
      }
    }
  }

#pragma unroll
  for (int i = 0; i < 4; ++i) {
#pragma unroll
    for (int j = 0; j < 2; ++j) {
      int col = n0 + wn + j * 16 + l15;
#pragma unroll
      for (int r = 0; r < 4; ++r) {
        int row = wm + i * 16 + quad * 4 + r;
        if (row >= mLimit) continue;
        eo[(size_t)(m0 + row) * 1024 + col] = (bf16)(gateW[m0 + row] * acc[i][j][r]);
      }
    }
  }
}

// ------------------------------------------- V transpose: vb[t][256] -> vt[bg][d][s]
__global__ __launch_bounds__(256) void vt_kernel(
    const bf16* __restrict__ vb, bf16* __restrict__ vt) {
  __shared__ __align__(16) bf16 tile[64 * 72];
  int t0 = blockIdx.x * 64, bg = blockIdx.y;
  int b = bg >> 2, g = bg & 3;
  int tid = threadIdx.x;
  for (int c = tid; c < 512; c += 256) {
    int r = c >> 3, d8 = (c & 7) * 8;
    *(short8*)(tile + r * 72 + d8) =
        *(const short8*)(vb + (size_t)(b * SEQ + t0 + r) * 256 + g * 64 + d8);
  }
  __syncthreads();
  for (int c = tid; c < 512; c += 256) {
    int d = c >> 3, s8 = (c & 7) * 8;
    bf16 tmp[8];
#pragma unroll
    for (int x = 0; x < 8; ++x) tmp[x] = tile[(s8 + x) * 72 + d];
    *(short8*)(vt + ((size_t)bg * 64 + d) * SEQ + t0 + s8) = *(short8*)tmp;
  }
}

// ---------------------------------------------------------------- flash attention
// (r0 version — best measured; single-buffered K/V, paired q-tiles for perfect
// per-block load balance: pairI + (31-pairI) = 33 key-tiles per block)
__global__ __launch_bounds__(256) void attn_kernel(
    const bf16* __restrict__ Q, const bf16* __restrict__ Kc, const bf16* __restrict__ Vt,
    bf16* __restrict__ AO) {
  __shared__ __align__(16) bf16 Qs[64 * 64];
  __shared__ __align__(16) bf16 Ks[64 * 64];
  __shared__ __align__(16) bf16 Vs[64 * 64];
  __shared__ __align__(16) bf16 Ps[4][16 * 64];
  const int pairI = blockIdx.x, h = blockIdx.y, b = blockIdx.z;
  const int g = h >> 2;
  const int tid = threadIdx.x, lane = tid & 63, wave = tid >> 6;
  const int l15 = lane & 15, quad = lane >> 4;

  const bf16* kSrc[2]; const bf16* vSrc[2]; bf16* kDst[2]; bf16* vDst[2];
#pragma unroll
  for (int it = 0; it < 2; ++it) {
    int c = it * 256 + tid;
    int r = c >> 3, p = c & 7;
    int kq = p ^ (r & 7);
    kSrc[it] = Kc + (size_t)(b * SEQ + r) * 256 + g * 64 + kq * 8;
    vSrc[it] = Vt + ((size_t)(b * 4 + g) * 64 + r) * SEQ + kq * 8;
    kDst[it] = Ks + (size_t)(it * 256 + wave * 64) * 8;
    vDst[it] = Vs + (size_t)(it * 256 + wave * 64) * 8;
  }

  int qOff[2], kvOff[4][2], pOff[2];
#pragma unroll
  for (int hh = 0; hh < 2; ++hh) {
    int m = wave * 16 + l15;
    qOff[hh] = (m << 6) + (((hh * 4 + quad) ^ (m & 7)) << 3);
#pragma unroll
    for (int j = 0; j < 4; ++j) {
      int n = j * 16 + l15;
      kvOff[j][hh] = (n << 6) + (((hh * 4 + quad) ^ (n & 7)) << 3);
    }
    int cblk = (hh * 2 + (quad >> 1)) ^ (l15 >> 2);
    pOff[hh] = (l15 << 6) + (cblk << 4) + ((quad & 1) << 3);
  }
  bf16* pw = &Ps[wave][0];
  const int rowl = wave * 16 + quad * 4;

  short8 onesb;
#pragma unroll
  for (int e = 0; e < 8; ++e) onesb[e] = (short)0x3F80;

  for (int ph = 0; ph < 2; ++ph) {
    const int q0 = (ph == 0 ? pairI : 31 - pairI) * 64;
    __syncthreads();
#pragma unroll
    for (int it = 0; it < 2; ++it) {
      int c = it * 256 + tid;
      int r = c >> 3, p = c & 7;
      int kq = p ^ (r & 7);
      gld16(Q + (size_t)(b * SEQ + q0 + r) * DM + h * 64 + kq * 8,
            Qs + (size_t)(it * 256 + wave * 64) * 8);
    }

    floatx4 oacc[4], sumacc;
#pragma unroll
    for (int r = 0; r < 4; ++r) { floatx4 z = {0.f, 0.f, 0.f, 0.f}; oacc[r] = z; }
    { floatx4 z = {0.f, 0.f, 0.f, 0.f}; sumacc = z; }

    const int nkt = (q0 >> 6) + 1;
    for (int kt = 0; kt < nkt; ++kt) {
      __syncthreads();
#pragma unroll
      for (int it = 0; it < 2; ++it) {
        gld16(kSrc[it] + (size_t)kt * 64 * 256, kDst[it]);
        gld16(vSrc[it] + kt * 64, vDst[it]);
      }
      __syncthreads();

      floatx4 sacc[4];
#pragma unroll
      for (int j = 0; j < 4; ++j) { floatx4 z = {0.f, 0.f, 0.f, 0.f}; sacc[j] = z; }
#pragma unroll
      for (int hh = 0; hh < 2; ++hh) {
        short8 aq = *(const short8*)(Qs + qOff[hh]);
#pragma unroll
        for (int j = 0; j < 4; ++j)
          sacc[j] = __builtin_amdgcn_mfma_f32_16x16x32_bf16(
              aq, *(const short8*)(Ks + kvOff[j][hh]), sacc[j], 0, 0, 0);
      }

      const bool lastTile = (kt == nkt - 1);
#pragma unroll
      for (int j = 0; j < 4; ++j) {
        int sw = ((j ^ quad) << 4) + l15;
        int colg = j * 16 + l15;
#pragma unroll
        for (int r = 0; r < 4; ++r) {
          float p = __expf(sacc[j][r]);
          if (lastTile && colg > rowl + r) p = 0.f;
          pw[(quad * 4 + r) * 64 + sw] = (bf16)p;
        }
      }
      asm volatile("s_waitcnt lgkmcnt(0)" ::: "memory");
#pragma unroll
      for (int hh = 0; hh < 2; ++hh) {
        short8 ap = *(const short8*)(pw + pOff[hh]);
#pragma unroll
        for (int j = 0; j < 4; ++j)
          oacc[j] = __builtin_amdgcn_mfma_f32_16x16x32_bf16(
              ap, *(const short8*)(Vs + kvOff[j][hh]), oacc[j], 0, 0, 0);
        sumacc = __builtin_amdgcn_mfma_f32_16x16x32_bf16(ap, onesb, sumacc, 0, 0, 0);
      }
    }

    float inv[4];
#pragma unroll
    for (int r = 0; r < 4; ++r) inv[r] = 1.f / sumacc[r];
#pragma unroll
    for (int j = 0; j < 4; ++j)
#pragma unroll
      for (int r = 0; r < 4; ++r) {
        int t = b * SEQ + q0 + rowl + r;
        AO[(size_t)t * DM + h * 64 + j * 16 + l15] = (bf16)(oacc[j][r] * inv[r]);
      }
  }
}

// ------------------------------------------------- capacity assignment (9 blocks)
// blocks 0..7: per-expert compaction; block 8: identity fill for shared slots
__global__ __launch_bounds__(256) void assign_kernel(
    const int* __restrict__ tIdx, const float* __restrict__ tW,
    int* __restrict__ tokList, float* __restrict__ gateW,
    int* __restrict__ neCnt, int* __restrict__ cntFull, int* __restrict__ slotOf) {
  int e = blockIdx.x;
  int tid = threadIdx.x, lane = tid & 63, wv = tid >> 6;
  if (e == 8) {
    for (int t = tid; t < TTOK; t += 256) {
      tokList[NSLOT + t] = t;
      gateW[NSLOT + t] = 1.0f;
    }
    if (tid == 0) neCnt[8] = TTOK;
    return;
  }
  __shared__ int waveTot[4];
  __shared__ int offs;
  if (tid == 0) offs = 0;
  __syncthreads();
  for (int base = 0; base < TTOK; base += 256) {
    int t = base + tid;
    int a = tIdx[t * 2], b2 = tIdx[t * 2 + 1];
    bool sel = (a == e) || (b2 == e);
    unsigned long long mask = __ballot(sel);
    int wrank = __popcll(mask & ((1ull << lane) - 1ull));
    if (lane == 0) waveTot[wv] = __popcll(mask);
    __syncthreads();
    int pre = offs;
    for (int w2 = 0; w2 < wv; ++w2) pre += waveTot[w2];
    int rank = pre + wrank;
    if (sel && rank < CAPT) {
      int slot = e * CAPT + rank;
      tokList[slot] = t;
      gateW[slot] = (a == e) ? tW[t * 2] : tW[t * 2 + 1];
      slotOf[t * 2 + ((a == e) ? 0 : 1)] = slot;
    }
    __syncthreads();
    if (tid == 0) offs += waveTot[0] + waveTot[1] + waveTot[2] + waveTot[3];
    __syncthreads();
  }
  if (tid == 0) {
    cntFull[e] = offs;
    neCnt[e] = offs < CAPT ? offs : CAPT;
  }
}

// ---------------------------------------------------------------- aux loss / util
__global__ __launch_bounds__(256) void aux_kernel(
    const float* __restrict__ probs, const int* __restrict__ cntFull,
    float* __restrict__ outAux) {
  __shared__ float psum[8];
  if (threadIdx.x < 8) psum[threadIdx.x] = 0.f;
  __syncthreads();
  float lp[8] = {0, 0, 0, 0, 0, 0, 0, 0};
  for (int t = threadIdx.x; t < TTOK; t += 256) {
#pragma unroll
    for (int e = 0; e < 8; ++e) lp[e] += probs[t * 8 + e];
  }
#pragma unroll
  for (int e = 0; e < 8; ++e)
#pragma unroll
    for (int off = 1; off < 64; off <<= 1) lp[e] += __shfl_xor(lp[e], off);
  if ((threadIdx.x & 63) == 0)
#pragma unroll
    for (int e = 0; e < 8; ++e) atomicAdd(&psum[e], lp[e]);
  __syncthreads();
  if (threadIdx.x == 0) {
    float aux = 0.f; int used = 0;
    for (int e = 0; e < 8; ++e) {
      aux += (psum[e] / (float)TTOK) * ((float)cntFull[e] / (float)TTOK);
      if (cntFull[e] > 0) used++;
    }
    outAux[0] = 8.f * aux;
    outAux[1] = 100.f * (float)used / 8.f;
  }
}

// ------------------------- combine: out = hbuf + shared eo + <=2 gated eo rows
__global__ __launch_bounds__(256) void combine_kernel(
    float* __restrict__ outp, const float* __restrict__ hbuf,
    const bf16* __restrict__ eo, const int* __restrict__ slotOf) {
  int t = blockIdx.x, tid = threadIdx.x;
  float4 v = ((const float4*)(hbuf + (size_t)t * DM))[tid];
  bf4 sh = ((const bf4*)(eo + (size_t)(NSLOT + t) * DM))[tid];
  v.x += (float)sh.x; v.y += (float)sh.y; v.z += (float)sh.z; v.w += (float)sh.w;
  int s0 = slotOf[t * 2], s1 = slotOf[t * 2 + 1];
  if (s0 >= 0) {
    bf4 e = ((const bf4*)(eo + (size_t)s0 * DM))[tid];
    v.x += (float)e.x; v.y += (float)e.y; v.z += (float)e.z; v.w += (float)e.w;
  }
  if (s1 >= 0) {
    bf4 e = ((const bf4*)(eo + (size_t)s1 * DM))[tid];
    v.x += (float)e.x; v.y += (float)e.y; v.z += (float)e.z; v.w += (float)e.w;
  }
  ((float4*)(outp + (size_t)t * DM))[tid] = v;
}

// ---------------------------------------------------------------- launch
extern "C" void kernel_launch(void* const* d_in, const int* in_sizes, int n_in,
                              void* d_out, int out_size, void* d_ws, size_t ws_size,
                              hipStream_t stream) {
  (void)in_sizes; (void)n_in; (void)out_size; (void)ws_size;
  const float* x     = (const float*)d_in[0];
  const float* cosb  = (const float*)d_in[1];
  const float* sinb  = (const float*)d_in[2];
  const float* attnw = (const float*)d_in[4];
  const float* moew  = (const float*)d_in[5];
  const float* wq  = (const float*)d_in[6];
  const float* wk  = (const float*)d_in[7];
  const float* wv  = (const float*)d_in[8];
  const float* wo  = (const float*)d_in[9];
  const float* rw  = (const float*)d_in[10];
  const float* ew1 = (const float*)d_in[11];
  const float* ew2 = (const float*)d_in[12];
  const float* ew3 = (const float*)d_in[13];
  const float* sw1 = (const float*)d_in[14];
  const float* sw2 = (const float*)d_in[15];
  const float* sw3 = (const float*)d_in[16];

  float* outp = (float*)d_out;
  float* auxp = outp + 4194304;
  float* newk = outp + 4194306;
  float* newv = newk + 1048576;

  char* wsp = (char*)d_ws;
  size_t off = 0;
  auto alloc = [&](size_t bytes) -> void* {
    void* p = wsp + off; off += (bytes + 255) & ~(size_t)255; return p;
  };
  bf16* wqkvT = (bf16*)alloc((size_t)1536 * 1024 * 2);
  bf16* woT   = (bf16*)alloc((size_t)1024 * 1024 * 2);
  bf16* ew1T  = (bf16*)alloc((size_t)9 * HIDDEN * 1024 * 2);   // slice 8 = sw1
  bf16* ew3T  = (bf16*)alloc((size_t)9 * HIDDEN * 1024 * 2);   // slice 8 = sw3
  bf16* ew2T  = (bf16*)alloc((size_t)9 * 1024 * HIDP * 2);     // slice 8 = sw2
  bf16* xn    = (bf16*)alloc((size_t)TTOK * DM * 2);
  bf16* qb    = (bf16*)alloc((size_t)TTOK * DM * 2);
  bf16* kb    = (bf16*)alloc((size_t)TTOK * 256 * 2);
  bf16* vb    = (bf16*)alloc((size_t)TTOK * 256 * 2);
  bf16* vt    = (bf16*)alloc((size_t)TTOK * 256 * 2);
  bf16* ao    = (bf16*)alloc((size_t)TTOK * DM * 2);
  float* hbuf = (float*)alloc((size_t)TTOK * DM * 4);
  bf16* hn    = (bf16*)alloc((size_t)TTOK * DM * 2);
  float* probs = (float*)alloc((size_t)TTOK * 8 * 4);
  int*   tIdx  = (int*)alloc((size_t)TTOK * 2 * 4);
  float* tW    = (float*)alloc((size_t)TTOK * 2 * 4);
  int*   tokList = (int*)alloc((size_t)TSLOT * 4);
  float* gateW   = (float*)alloc((size_t)TSLOT * 4);
  int*   neCnt   = (int*)alloc(64);
  int*   cntFull = (int*)alloc(64);
  int*   slotOf  = (int*)alloc((size_t)TTOK * 2 * 4);
  bf16*  mact = (bf16*)alloc((size_t)TSLOT * HIDP * 2);
  bf16*  eo   = (bf16*)alloc((size_t)TSLOT * DM * 2);

  EpiAux nil{};
  EpiAux ropeAux{cosb, sinb, qb, kb, vb, newk, newv};

  // ---- weight convert + transpose (r0 grids)
  transpose_cvt<<<dim3(16, 16, 1), 256, 0, stream>>>(wq, wqkvT, 1024, 1024, 1024, 0, 0);
  transpose_cvt<<<dim3(4, 16, 1), 256, 0, stream>>>(wk, wqkvT + (size_t)1024 * 1024, 1024, 256, 1024, 0, 0);
  transpose_cvt<<<dim3(4, 16, 1), 256, 0, stream>>>(wv, wqkvT + (size_t)1280 * 1024, 1024, 256, 1024, 0, 0);
  transpose_cvt<<<dim3(16, 16, 1), 256, 0, stream>>>(wo, woT, 1024, 1024, 1024, 0, 0);
  transpose_cvt<<<dim3(22, 16, NEXP), 256, 0, stream>>>(ew1, ew1T, 1024, HIDDEN, 1024,
      (long)1024 * HIDDEN, (long)HIDDEN * 1024);
  transpose_cvt<<<dim3(22, 16, NEXP), 256, 0, stream>>>(ew3, ew3T, 1024, HIDDEN, 1024,
      (long)1024 * HIDDEN, (long)HIDDEN * 1024);
  transpose_cvt<<<dim3(16, 22, NEXP), 256, 0, stream>>>(ew2, ew2T, HIDDEN, 1024, HIDP,
      (long)HIDDEN * 1024, (long)1024 * HIDP);
  transpose_cvt<<<dim3(22, 16, 1), 256, 0, stream>>>(sw1, ew1T + (size_t)8 * HIDDEN * 1024,
      1024, HIDDEN, 1024, 0, 0);
  transpose_cvt<<<dim3(22, 16, 1), 256, 0, stream>>>(sw3, ew3T + (size_t)8 * HIDDEN * 1024,
      1024, HIDDEN, 1024, 0, 0);
  transpose_cvt<<<dim3(16, 22, 1), 256, 0, stream>>>(sw2, ew2T + (size_t)8 * 1024 * HIDP,
      HIDDEN, 1024, HIDP, 0, 0);

  // ---- attention path (64-row M-tiles: xPerXcd = 4096/64/8 = 8)
  rmsnorm_kernel<<<TTOK, 256, 0, stream>>>(x, attnw, xn);
  gemm_bt<4><<<8 * 8 * 12, 256, 0, stream>>>(
      xn, wqkvT, TTOK, 1536, 1024, 1024, 1024, 8, nullptr, 0, nullptr, ropeAux);
  vt_kernel<<<dim3(32, 8), 256, 0, stream>>>(vb, vt);
  attn_kernel<<<dim3(16, NHEAD, 2), 256, 0, stream>>>(qb, kb, vt, ao);
  gemm_bt<2><<<8 * 8 * 8, 256, 0, stream>>>(
      ao, woT, TTOK, 1024, 1024, 1024, 1024, 8, hbuf, 1024, x, nil);

  // ---- MoE routing
  rmsnorm_router_kernel<<<TTOK, 256, 0, stream>>>(hbuf, moew, rw, hn, probs, tIdx, tW);
  hipMemsetAsync(slotOf, 0xFF, (size_t)TTOK * 2 * 4, stream);
  assign_kernel<<<9, 256, 0, stream>>>(tIdx, tW, tokList, gateW, neCnt, cntFull, slotOf);
  aux_kernel<<<1, 256, 0, stream>>>(probs, cntFull, auxp);

  // ---- experts (8 routed + shared as expert 8)
  gemm_dual9<<<8 * XBT * 11, 256, 0, stream>>>(hn, ew1T, ew3T, mact, tokList, neCnt);
  gemm_down9<<<8 * XBT * 16, 256, 0, stream>>>(mact, ew2T, eo, gateW, neCnt);
  combine_kernel<<<TTOK, 256, 0, stream>>>(outp, hbuf, eo, slotOf);
}

// Round 10
// 538.084 us; speedup vs baseline: 1.1035x; 1.0446x over previous
//
#include <hip/hip_runtime.h>
#include <hip/hip_bf16.h>
#include <math.h>

typedef __hip_bfloat16 bf16;
typedef __attribute__((ext_vector_type(8))) short short8;
typedef __attribute__((ext_vector_type(4))) float floatx4;

#define SEQ    2048
#define TTOK   4096
#define DM     1024
#define NHEAD  16
#define NKVH   4
#define HD     64
#define NEXP   8
#define HIDDEN 1365
#define HIDP   1408
#define CAPT   1280
#define NSLOT  (NEXP*CAPT)      /* 10240 routed slots */
#define TSLOT  (NSLOT+TTOK)     /* 14336: + shared-expert identity slots */
#define XPE    (CAPT/128)       /* 10 routed 128-row M-blocks per expert */
#define XBT    14               /* per-XCD 128-row M-blocks: 10 routed + 4 shared */

// ---------------------------------------------------------------- utilities
__device__ __forceinline__ void gld16(const void* g, void* l) {
  __builtin_amdgcn_global_load_lds((const __attribute__((address_space(1))) void*)g,
                                   (__attribute__((address_space(3))) void*)l,
                                   16, 0, 0);
}

struct __align__(8) bf4 { bf16 x, y, z, w; };

struct EpiAux {
  const float* cosb; const float* sinb;
  bf16* qb; bf16* kb; bf16* vb; float* newk; float* newv;
};

// ---------------------------------------------------- weight convert+transpose
// Shared body: (K,N) f32 row-major -> (N,Kp) bf16 row-major for one 64x64 tile.
__device__ __forceinline__ void tcvt_body(
    const float* __restrict__ src, bf16* __restrict__ dst,
    int K, int N, int Kp, int k0, int n0, float (*tile)[65]) {
  const int tid = threadIdx.x;
  const int lr = tid >> 4, lc = (tid & 15) * 4;
#pragma unroll
  for (int i = 0; i < 4; ++i) {
    int k = k0 + lr + i * 16;
    int n = n0 + lc;
    float4 v = {0.f, 0.f, 0.f, 0.f};
    if (k < K) {
      if (n + 3 < N) v = *(const float4*)(src + (size_t)k * N + n);
      else {
        float* vp = (float*)&v;
        for (int e = 0; e < 4; ++e) if (n + e < N) vp[e] = src[(size_t)k * N + n + e];
      }
    }
    tile[lr + i * 16][lc] = v.x; tile[lr + i * 16][lc + 1] = v.y;
    tile[lr + i * 16][lc + 2] = v.z; tile[lr + i * 16][lc + 3] = v.w;
  }
  __syncthreads();
  const int n = tid >> 2, kk0 = (tid & 3) * 16;
  if (n0 + n < N) {
    bf16 buf[16];
#pragma unroll
    for (int e = 0; e < 16; ++e) buf[e] = (bf16)tile[kk0 + e][n];
    bf16* dp = dst + (size_t)(n0 + n) * Kp + k0 + kk0;
    *(short8*)dp = *(short8*)buf;
    *(short8*)(dp + 8) = *(short8*)(buf + 8);
  }
}

// Generic single-source variant (ew2 / sw2)
__global__ __launch_bounds__(256) void transpose_cvt(
    const float* __restrict__ src, bf16* __restrict__ dst,
    int K, int N, int Kp, long srcZ, long dstZ) {
  __shared__ float tile[64][65];
  tcvt_body(src + (size_t)blockIdx.z * srcZ, dst + (size_t)blockIdx.z * dstZ,
            K, N, Kp, blockIdx.y * 64, blockIdx.x * 64, tile);
}

// Dual-source variant: z<splitZ -> (src0,dst0) slice z; else (src1,dst1) slice z-splitZ.
__global__ __launch_bounds__(256) void transpose_cvt_pair(
    const float* __restrict__ src0, const float* __restrict__ src1,
    bf16* __restrict__ dst0, bf16* __restrict__ dst1,
    int K, int N, int Kp, long srcZ, long dstZ, int splitZ) {
  __shared__ float tile[64][65];
  const float* src; bf16* dst;
  int z = blockIdx.z;
  if (z < splitZ) { src = src0 + (size_t)z * srcZ; dst = dst0 + (size_t)z * dstZ; }
  else { int zz = z - splitZ; src = src1 + (size_t)zz * srcZ; dst = dst1 + (size_t)zz * dstZ; }
  tcvt_body(src, dst, K, N, Kp, blockIdx.y * 64, blockIdx.x * 64, tile);
}

// All four dense weights (wq/wk/wv/wo) in one launch: grid (40,16).
__global__ __launch_bounds__(256) void transpose_cvt_qkvo(
    const float* __restrict__ wq, const float* __restrict__ wk,
    const float* __restrict__ wv, const float* __restrict__ wo,
    bf16* __restrict__ wqkvT, bf16* __restrict__ woT) {
  __shared__ float tile[64][65];
  const float* src; bf16* dst; int N, n0;
  int bx = blockIdx.x;
  if (bx < 16)      { src = wq; dst = wqkvT;                       N = 1024; n0 = bx * 64; }
  else if (bx < 20) { src = wk; dst = wqkvT + (size_t)1024 * 1024; N = 256;  n0 = (bx - 16) * 64; }
  else if (bx < 24) { src = wv; dst = wqkvT + (size_t)1280 * 1024; N = 256;  n0 = (bx - 20) * 64; }
  else              { src = wo; dst = woT;                         N = 1024; n0 = (bx - 24) * 64; }
  tcvt_body(src, dst, 1024, N, 1024, blockIdx.y * 64, n0, tile);
}

// ---------------------------------------------------------------- rmsnorm
__global__ __launch_bounds__(256) void rmsnorm_kernel(
    const float* __restrict__ x, const float* __restrict__ w, bf16* __restrict__ out) {
  int t = blockIdx.x;
  const float* xr = x + (size_t)t * DM;
  float4 xv = *(const float4*)(xr + threadIdx.x * 4);
  float ss = xv.x * xv.x + xv.y * xv.y + xv.z * xv.z + xv.w * xv.w;
#pragma unroll
  for (int off = 1; off < 64; off <<= 1) ss += __shfl_xor(ss, off);
  __shared__ float sred[4];
  if ((threadIdx.x & 63) == 0) sred[threadIdx.x >> 6] = ss;
  __syncthreads();
  float scale = rsqrtf((sred[0] + sred[1] + sred[2] + sred[3]) * (1.f / DM) + 1e-6f);
  float4 wv = *(const float4*)(w + threadIdx.x * 4);
  bf4 o;
  o.x = (bf16)(xv.x * scale * wv.x); o.y = (bf16)(xv.y * scale * wv.y);
  o.z = (bf16)(xv.z * scale * wv.z); o.w = (bf16)(xv.w * scale * wv.w);
  ((bf4*)(out + (size_t)t * DM))[threadIdx.x] = o;
}

// -------------------------------------------- rmsnorm + router (moe path)
__global__ __launch_bounds__(256) void rmsnorm_router_kernel(
    const float* __restrict__ x, const float* __restrict__ w, const float* __restrict__ rw,
    bf16* __restrict__ out, float* __restrict__ probs,
    int* __restrict__ tIdx, float* __restrict__ tW) {
  int t = blockIdx.x;
  int tid = threadIdx.x, lane = tid & 63, wv = tid >> 6;
  const float* xr = x + (size_t)t * DM;
  float4 xv = *(const float4*)(xr + tid * 4);
  float ss = xv.x * xv.x + xv.y * xv.y + xv.z * xv.z + xv.w * xv.w;
#pragma unroll
  for (int off = 1; off < 64; off <<= 1) ss += __shfl_xor(ss, off);
  __shared__ float sred[4];
  __shared__ float red[4][8];
  if (lane == 0) sred[wv] = ss;
  __syncthreads();
  float scale = rsqrtf((sred[0] + sred[1] + sred[2] + sred[3]) * (1.f / DM) + 1e-6f);
  float4 wvv = *(const float4*)(w + tid * 4);
  float y[4] = {xv.x * scale * wvv.x, xv.y * scale * wvv.y,
                xv.z * scale * wvv.z, xv.w * scale * wvv.w};
  bf4 o; o.x = (bf16)y[0]; o.y = (bf16)y[1]; o.z = (bf16)y[2]; o.w = (bf16)y[3];
  ((bf4*)(out + (size_t)t * DM))[tid] = o;
  float acc[8] = {0, 0, 0, 0, 0, 0, 0, 0};
#pragma unroll
  for (int dd = 0; dd < 4; ++dd) {
    const float* rwr = rw + (size_t)(tid * 4 + dd) * 8;
#pragma unroll
    for (int e = 0; e < 8; ++e) acc[e] += y[dd] * rwr[e];
  }
#pragma unroll
  for (int e = 0; e < 8; ++e)
#pragma unroll
    for (int off = 1; off < 64; off <<= 1) acc[e] += __shfl_xor(acc[e], off);
  if (lane == 0)
#pragma unroll
    for (int e = 0; e < 8; ++e) red[wv][e] = acc[e];
  __syncthreads();
  if (tid == 0) {
    float lg[8];
#pragma unroll
    for (int e = 0; e < 8; ++e) lg[e] = red[0][e] + red[1][e] + red[2][e] + red[3][e];
    float mx = lg[0];
#pragma unroll
    for (int e = 1; e < 8; ++e) mx = fmaxf(mx, lg[e]);
    float p[8], se = 0.f;
#pragma unroll
    for (int e = 0; e < 8; ++e) { p[e] = __expf(lg[e] - mx); se += p[e]; }
#pragma unroll
    for (int e = 0; e < 8; ++e) { p[e] /= se; probs[t * 8 + e] = p[e]; }
    int i1 = 0;
#pragma unroll
    for (int e = 1; e < 8; ++e) if (p[e] > p[i1]) i1 = e;
    int i2 = (i1 == 0) ? 1 : 0;
#pragma unroll
    for (int e = 0; e < 8; ++e) if (e != i1 && p[e] > p[i2]) i2 = e;
    float s = p[i1] + p[i2];
    tIdx[t * 2] = i1; tIdx[t * 2 + 1] = i2;
    tW[t * 2] = p[i1] / s; tW[t * 2 + 1] = p[i2] / s;
  }
}

// ---------------------------------------------------------------- dense GEMM
// 64x128 tile (2 M-frags/wave): doubles grid vs 128x128 so QKV gets 3 blocks/CU
// and WO 2 blocks/CU. EPI: 2 = Cf = resid + acc ; 4 = QKV+rope.
template <int EPI>
__global__ __launch_bounds__(256) void gemm_bt(
    const bf16* __restrict__ A, const bf16* __restrict__ Bt,
    int M, int N, int K, int lda, int ldb, int xPerXcd,
    float* __restrict__ Cf, int ldc,
    const float* __restrict__ resid, EpiAux aux) {
  __shared__ __align__(16) bf16 As[64 * 64];
  __shared__ __align__(16) bf16 Bs[128 * 64];
  const int tid = threadIdx.x, lane = tid & 63, wave = tid >> 6;
  const int f = blockIdx.x, lo = f >> 3;
  int xb = (f & 7) * xPerXcd + lo % xPerXcd;
  int n0 = (lo / xPerXcd) * 128;
  int m0 = xb * 64;

  const bf16* aSrc[2]; const bf16* bSrc[4];
  bf16* aDst[2]; bf16* bDst[4];
#pragma unroll
  for (int it = 0; it < 2; ++it) {
    int c = it * 256 + tid;
    int r = c >> 3, q = c & 7;
    int kq = q ^ (r & 7);
    aSrc[it] = A + (long)(m0 + r) * lda + kq * 8;
    aDst[it] = As + (size_t)(it * 256 + wave * 64) * 8;
  }
#pragma unroll
  for (int it = 0; it < 4; ++it) {
    int c = it * 256 + tid;
    int r = c >> 3, q = c & 7;
    int kq = q ^ (r & 7);
    bSrc[it] = Bt + (long)(n0 + r) * ldb + kq * 8;
    bDst[it] = Bs + (size_t)(it * 256 + wave * 64) * 8;
  }

  floatx4 acc[2][4];
#pragma unroll
  for (int i = 0; i < 2; ++i)
#pragma unroll
    for (int j = 0; j < 4; ++j) { floatx4 z = {0.f, 0.f, 0.f, 0.f}; acc[i][j] = z; }

  const int wm = (wave & 1) * 32, wn = (wave >> 1) * 64;
  const int l15 = lane & 15, quad = lane >> 4;
  int aOff[2][2], bOff[4][2];
#pragma unroll
  for (int h = 0; h < 2; ++h) {
#pragma unroll
    for (int i = 0; i < 2; ++i) {
      int m = wm + i * 16 + l15;
      aOff[i][h] = (((m << 3) | ((h * 4 + quad) ^ (m & 7))) << 3);
    }
#pragma unroll
    for (int j = 0; j < 4; ++j) {
      int n = wn + j * 16 + l15;
      bOff[j][h] = (((n << 3) | ((h * 4 + quad) ^ (n & 7))) << 3);
    }
  }

  const int kIters = K >> 6;
  for (int kt = 0; kt < kIters; ++kt) {
    __syncthreads();
#pragma unroll
    for (int it = 0; it < 2; ++it) { gld16(aSrc[it], aDst[it]); aSrc[it] += 64; }
#pragma unroll
    for (int it = 0; it < 4; ++it) { gld16(bSrc[it], bDst[it]); bSrc[it] += 64; }
    __syncthreads();
#pragma unroll
    for (int h = 0; h < 2; ++h) {
      short8 af[2], bfr[4];
#pragma unroll
      for (int i = 0; i < 2; ++i) af[i] = *(const short8*)(As + aOff[i][h]);
#pragma unroll
      for (int j = 0; j < 4; ++j) bfr[j] = *(const short8*)(Bs + bOff[j][h]);
#pragma unroll
      for (int i = 0; i < 2; ++i)
#pragma unroll
        for (int j = 0; j < 4; ++j)
          acc[i][j] = __builtin_amdgcn_mfma_f32_16x16x32_bf16(af[i], bfr[j], acc[i][j], 0, 0, 0);
    }
  }

  if constexpr (EPI == 4) {
#pragma unroll
    for (int i = 0; i < 2; ++i) {
#pragma unroll
      for (int r = 0; r < 4; ++r) {
        int row = wm + i * 16 + quad * 4 + r;
        int t = m0 + row;
        int s = t & (SEQ - 1);
        if (n0 < 1024) {
#pragma unroll
          for (int j = 0; j < 2; ++j) {
            int col = n0 + wn + j * 16 + l15;
            int dlo = col & 63;
            float x1 = acc[i][j][r], x2 = acc[i][j + 2][r];
            float ch = aux.cosb[s * 64 + dlo], sh = aux.sinb[s * 64 + dlo];
            aux.qb[(size_t)t * DM + col]      = (bf16)((x1 * ch - x2 * sh) * 0.125f);
            aux.qb[(size_t)t * DM + col + 32] = (bf16)((x1 * sh + x2 * ch) * 0.125f);
          }
        } else if (n0 < 1280) {
#pragma unroll
          for (int j = 0; j < 2; ++j) {
            int ck = n0 + wn + j * 16 + l15 - 1024;
            int dlo = ck & 63;
            float x1 = acc[i][j][r], x2 = acc[i][j + 2][r];
            float ch = aux.cosb[s * 64 + dlo], sh = aux.sinb[s * 64 + dlo];
            float o1 = x1 * ch - x2 * sh, o2 = x1 * sh + x2 * ch;
            aux.kb[(size_t)t * 256 + ck]        = (bf16)o1;
            aux.kb[(size_t)t * 256 + ck + 32]   = (bf16)o2;
            aux.newk[(size_t)t * 256 + ck]      = o1;
            aux.newk[(size_t)t * 256 + ck + 32] = o2;
          }
        } else {
#pragma unroll
          for (int j = 0; j < 4; ++j) {
            int cv = n0 + wn + j * 16 + l15 - 1280;
            float v = acc[i][j][r];
            aux.vb[(size_t)t * 256 + cv]   = (bf16)v;
            aux.newv[(size_t)t * 256 + cv] = v;
          }
        }
      }
    }
    return;
  }
#pragma unroll
  for (int i = 0; i < 2; ++i) {
#pragma unroll
    for (int j = 0; j < 4; ++j) {
      int col = n0 + wn + j * 16 + l15;
#pragma unroll
      for (int r = 0; r < 4; ++r) {
        int row = wm + i * 16 + quad * 4 + r;
        size_t o = (size_t)(m0 + row) * ldc + col;
        Cf[o] = resid[o] + acc[i][j][r];
      }
    }
  }
}

// --------------------------------------------------- slot-block decode helper
__device__ __forceinline__ bool slot_block(
    int f, int NY, const int* neCnt, int& expert, int& m0, int& mLimit, int& n0) {
  int xcd = f & 7, lo = f >> 3;
  int xb = lo / NY, y = lo % NY;
  n0 = y * 64;
  if (xb < XPE) {
    expert = xcd;
    int ne = neCnt[xcd];
    if (xb * 128 >= ne) return false;
    m0 = xcd * CAPT + xb * 128;
    mLimit = ne - xb * 128;
    if (mLimit > 128) mLimit = 128;
  } else {
    expert = 8;
    int sb = xcd * 4 + (xb - XPE);
    m0 = NSLOT + sb * 128;
    mLimit = 128;
  }
  return true;
}

// ------------------------------------------------------ MoE dual GEMM + swiglu
// 128x128 tile, dual-B (B1,B3 share the staged A): 48 KB LDS, 256 thr / 4 waves,
// m97-style 2-barrier schedule. ~800 TF measured (r3) — near structural ceiling.
__global__ __launch_bounds__(256, 2) void gemm_dual9(
    const bf16* __restrict__ A, const bf16* __restrict__ B1t, const bf16* __restrict__ B3t,
    bf16* __restrict__ mact,
    const int* __restrict__ tokList, const int* __restrict__ neCnt) {
  __shared__ __align__(16) bf16 As[128 * 64];
  __shared__ __align__(16) bf16 B1s[128 * 64];
  __shared__ __align__(16) bf16 B3s[128 * 64];
  const int tid = threadIdx.x, lane = tid & 63, wave = tid >> 6;
  int expert, m0, mLimit, n0;
  if (!slot_block(blockIdx.x, 11, neCnt, expert, m0, mLimit, n0)) return;
  n0 <<= 1;  // 128-wide N-tiles
  const bf16* B1e = B1t + (long)expert * (HIDDEN * 1024);
  const bf16* B3e = B3t + (long)expert * (HIDDEN * 1024);

  const bf16* aSrc[4]; const bf16* b1Src[4]; const bf16* b3Src[4];
  bf16* aDst[4]; bf16* b1Dst[4]; bf16* b3Dst[4];
#pragma unroll
  for (int it = 0; it < 4; ++it) {
    int c = it * 256 + tid;
    int r = c >> 3, q = c & 7;
    int kq = q ^ (r & 7);
    int rr = r < mLimit ? r : (mLimit - 1);
    aSrc[it] = A + (long)tokList[m0 + rr] * 1024 + kq * 8;
    aDst[it] = As + (size_t)(it * 256 + wave * 64) * 8;
    int nn = n0 + r; if (nn > HIDDEN - 1) nn = HIDDEN - 1;
    b1Src[it] = B1e + (long)nn * 1024 + kq * 8;
    b3Src[it] = B3e + (long)nn * 1024 + kq * 8;
    b1Dst[it] = B1s + (size_t)(it * 256 + wave * 64) * 8;
    b3Dst[it] = B3s + (size_t)(it * 256 + wave * 64) * 8;
  }

  floatx4 acc1[4][4], acc3[4][4];
#pragma unroll
  for (int i = 0; i < 4; ++i)
#pragma unroll
    for (int j = 0; j < 4; ++j) {
      floatx4 z = {0.f, 0.f, 0.f, 0.f};
      acc1[i][j] = z; acc3[i][j] = z;
    }

  const int wm = (wave & 1) * 64, wn = (wave >> 1) * 64;
  const int l15 = lane & 15, quad = lane >> 4;
  int aOff[4][2], bOff[4][2];
#pragma unroll
  for (int h = 0; h < 2; ++h) {
#pragma unroll
    for (int i = 0; i < 4; ++i) {
      int m = wm + i * 16 + l15;
      aOff[i][h] = (((m << 3) | ((h * 4 + quad) ^ (m & 7))) << 3);
    }
#pragma unroll
    for (int j = 0; j < 4; ++j) {
      int n = wn + j * 16 + l15;
      bOff[j][h] = (((n << 3) | ((h * 4 + quad) ^ (n & 7))) << 3);
    }
  }

  for (int kt = 0; kt < 16; ++kt) {
    __syncthreads();
#pragma unroll
    for (int it = 0; it < 4; ++it) { gld16(aSrc[it], aDst[it]); aSrc[it] += 64; }
#pragma unroll
    for (int it = 0; it < 4; ++it) {
      gld16(b1Src[it], b1Dst[it]); b1Src[it] += 64;
      gld16(b3Src[it], b3Dst[it]); b3Src[it] += 64;
    }
    __syncthreads();
#pragma unroll
    for (int h = 0; h < 2; ++h) {
      short8 af[4];
#pragma unroll
      for (int i = 0; i < 4; ++i) af[i] = *(const short8*)(As + aOff[i][h]);
#pragma unroll
      for (int j = 0; j < 4; ++j) {
        short8 b1f = *(const short8*)(B1s + bOff[j][h]);
        short8 b3f = *(const short8*)(B3s + bOff[j][h]);
#pragma unroll
        for (int i = 0; i < 4; ++i) {
          acc1[i][j] = __builtin_amdgcn_mfma_f32_16x16x32_bf16(af[i], b1f, acc1[i][j], 0, 0, 0);
          acc3[i][j] = __builtin_amdgcn_mfma_f32_16x16x32_bf16(af[i], b3f, acc3[i][j], 0, 0, 0);
        }
      }
    }
  }

#pragma unroll
  for (int i = 0; i < 4; ++i) {
#pragma unroll
    for (int j = 0; j < 4; ++j) {
      int col = n0 + wn + j * 16 + l15;
#pragma unroll
      for (int r = 0; r < 4; ++r) {
        int row = wm + i * 16 + quad * 4 + r;
        if (row >= mLimit) continue;
        float a1 = acc1[i][j][r], a3 = acc3[i][j][r];
        float sl = a1 / (1.f + __expf(-a1));
        mact[(size_t)(m0 + row) * HIDP + col] = (col < HIDDEN) ? (bf16)(sl * a3) : (bf16)0.f;
      }
    }
  }
}

// ------------------------------------------------------ MoE down GEMM (gated)
// 128x64 tile (r0 version — best measured); A = mact slots (no gather);
// eo[slot] = gateW[slot] * (A@ew2^T)
__global__ __launch_bounds__(256) void gemm_down9(
    const bf16* __restrict__ A, const bf16* __restrict__ B2t,
    bf16* __restrict__ eo,
    const float* __restrict__ gateW, const int* __restrict__ neCnt) {
  __shared__ __align__(16) bf16 As[128 * 64];
  __shared__ __align__(16) bf16 Bs[64 * 64];
  const int tid = threadIdx.x, lane = tid & 63, wave = tid >> 6;
  int expert, m0, mLimit, n0;
  if (!slot_block(blockIdx.x, 16, neCnt, expert, m0, mLimit, n0)) return;
  const bf16* Be = B2t + (long)expert * (1024 * HIDP);

  const bf16* aSrc[4]; const bf16* bSrc[2];
  bf16* aDst[4]; bf16* bDst[2];
#pragma unroll
  for (int it = 0; it < 4; ++it) {
    int c = it * 256 + tid;
    int r = c >> 3, q = c & 7;
    int kq = q ^ (r & 7);
    int rr = r < mLimit ? r : (mLimit - 1);
    aSrc[it] = A + (long)(m0 + rr) * HIDP + kq * 8;
    aDst[it] = As + (size_t)(it * 256 + wave * 64) * 8;
  }
#pragma unroll
  for (int it = 0; it < 2; ++it) {
    int c = it * 256 + tid;
    int r = c >> 3, q = c & 7;
    int kq = q ^ (r & 7);
    bSrc[it] = Be + (long)(n0 + r) * HIDP + kq * 8;
    bDst[it] = Bs + (size_t)(it * 256 + wave * 64) * 8;
  }

  floatx4 acc[4][2];
#pragma unroll
  for (int i = 0; i < 4; ++i)
#pragma unroll
    for (int j = 0; j < 2; ++j) { floatx4 z = {0.f, 0.f, 0.f, 0.f}; acc[i][j] = z; }

  const int wm = (wave & 1) * 64, wn = (wave >> 1) * 32;
  const int l15 = lane & 15, quad = lane >> 4;
  int aOff[4][2], bOff[2][2];
#pragma unroll
  for (int h = 0; h < 2; ++h) {
#pragma unroll
    for (int i = 0; i < 4; ++i) {
      int m = wm + i * 16 + l15;
      aOff[i][h] = (((m << 3) | ((h * 4 + quad) ^ (m & 7))) << 3);
    }
#pragma unroll
    for (int j = 0; j < 2; ++j) {
      int n = wn + j * 16 + l15;
      bOff[j][h] = (((n << 3) | ((h * 4 + quad) ^ (n & 7))) << 3);
    }
  }

  for (int kt = 0; kt < 22; ++kt) {
    __syncthreads();
#pragma unroll
    for (int it = 0; it < 4; ++it) { gld16(aSrc[it], aDst[it]); aSrc[it] += 64; }
#pragma unroll
    for (int it = 0; it < 2; ++it) { gld16(bSrc[it], bDst[it]); bSrc[it] += 64; }
    __syncthreads();
#pragma unroll
    for (int h = 0; h < 2; ++h) {
      short8 af[4];
#pragma unroll
      for (int i = 0; i < 4; ++i) af[i] = *(const short8*)(As + aOff[i][h]);
#pragma unroll
      for (int j = 0; j < 2; ++j) {
        short8 bf = *(const short8*)(Bs + bOff[j][h]);
#pragma unroll
        for (int i = 0; i < 4; ++i)
          acc[i][j] = __builtin_amdgcn_mfma_f32_16x16x32_bf16(af[i], bf, acc[i][j], 0, 0, 0);
      }
    }
  }

#pragma unroll
  for (int i = 0; i < 4; ++i) {
#pragma unroll
    for (int j = 0; j < 2; ++j) {
      int col = n0 + wn + j * 16 + l15;
#pragma unroll
      for (int r = 0; r < 4; ++r) {
        int row = wm + i * 16 + quad * 4 + r;
        if (row >= mLimit) continue;
        eo[(size_t)(m0 + row) * 1024 + col] = (bf16)(gateW[m0 + row] * acc[i][j][r]);
      }
    }
  }
}

// ------------------------------------------- V transpose: vb[t][256] -> vt[bg][d][s]
__global__ __launch_bounds__(256) void vt_kernel(
    const bf16* __restrict__ vb, bf16* __restrict__ vt) {
  __shared__ __align__(16) bf16 tile[64 * 72];
  int t0 = blockIdx.x * 64, bg = blockIdx.y;
  int b = bg >> 2, g = bg & 3;
  int tid = threadIdx.x;
  for (int c = tid; c < 512; c += 256) {
    int r = c >> 3, d8 = (c & 7) * 8;
    *(short8*)(tile + r * 72 + d8) =
        *(const short8*)(vb + (size_t)(b * SEQ + t0 + r) * 256 + g * 64 + d8);
  }
  __syncthreads();
  for (int c = tid; c < 512; c += 256) {
    int d = c >> 3, s8 = (c & 7) * 8;
    bf16 tmp[8];
#pragma unroll
    for (int x = 0; x < 8; ++x) tmp[x] = tile[(s8 + x) * 72 + d];
    *(short8*)(vt + ((size_t)bg * 64 + d) * SEQ + t0 + s8) = *(short8*)tmp;
  }
}

// ---------------------------------------------------------------- flash attention
// (r0 version — best measured; single-buffered K/V, paired q-tiles for perfect
// per-block load balance: pairI + (31-pairI) = 33 key-tiles per block)
__global__ __launch_bounds__(256) void attn_kernel(
    const bf16* __restrict__ Q, const bf16* __restrict__ Kc, const bf16* __restrict__ Vt,
    bf16* __restrict__ AO) {
  __shared__ __align__(16) bf16 Qs[64 * 64];
  __shared__ __align__(16) bf16 Ks[64 * 64];
  __shared__ __align__(16) bf16 Vs[64 * 64];
  __shared__ __align__(16) bf16 Ps[4][16 * 64];
  const int pairI = blockIdx.x, h = blockIdx.y, b = blockIdx.z;
  const int g = h >> 2;
  const int tid = threadIdx.x, lane = tid & 63, wave = tid >> 6;
  const int l15 = lane & 15, quad = lane >> 4;

  const bf16* kSrc[2]; const bf16* vSrc[2]; bf16* kDst[2]; bf16* vDst[2];
#pragma unroll
  for (int it = 0; it < 2; ++it) {
    int c = it * 256 + tid;
    int r = c >> 3, p = c & 7;
    int kq = p ^ (r & 7);
    kSrc[it] = Kc + (size_t)(b * SEQ + r) * 256 + g * 64 + kq * 8;
    vSrc[it] = Vt + ((size_t)(b * 4 + g) * 64 + r) * SEQ + kq * 8;
    kDst[it] = Ks + (size_t)(it * 256 + wave * 64) * 8;
    vDst[it] = Vs + (size_t)(it * 256 + wave * 64) * 8;
  }

  int qOff[2], kvOff[4][2], pOff[2];
#pragma unroll
  for (int hh = 0; hh < 2; ++hh) {
    int m = wave * 16 + l15;
    qOff[hh] = (m << 6) + (((hh * 4 + quad) ^ (m & 7)) << 3);
#pragma unroll
    for (int j = 0; j < 4; ++j) {
      int n = j * 16 + l15;
      kvOff[j][hh] = (n << 6) + (((hh * 4 + quad) ^ (n & 7)) << 3);
    }
    int cblk = (hh * 2 + (quad >> 1)) ^ (l15 >> 2);
    pOff[hh] = (l15 << 6) + (cblk << 4) + ((quad & 1) << 3);
  }
  bf16* pw = &Ps[wave][0];
  const int rowl = wave * 16 + quad * 4;

  short8 onesb;
#pragma unroll
  for (int e = 0; e < 8; ++e) onesb[e] = (short)0x3F80;

  for (int ph = 0; ph < 2; ++ph) {
    const int q0 = (ph == 0 ? pairI : 31 - pairI) * 64;
    __syncthreads();
#pragma unroll
    for (int it = 0; it < 2; ++it) {
      int c = it * 256 + tid;
      int r = c >> 3, p = c & 7;
      int kq = p ^ (r & 7);
      gld16(Q + (size_t)(b * SEQ + q0 + r) * DM + h * 64 + kq * 8,
            Qs + (size_t)(it * 256 + wave * 64) * 8);
    }

    floatx4 oacc[4], sumacc;
#pragma unroll
    for (int r = 0; r < 4; ++r) { floatx4 z = {0.f, 0.f, 0.f, 0.f}; oacc[r] = z; }
    { floatx4 z = {0.f, 0.f, 0.f, 0.f}; sumacc = z; }

    const int nkt = (q0 >> 6) + 1;
    for (int kt = 0; kt < nkt; ++kt) {
      __syncthreads();
#pragma unroll
      for (int it = 0; it < 2; ++it) {
        gld16(kSrc[it] + (size_t)kt * 64 * 256, kDst[it]);
        gld16(vSrc[it] + kt * 64, vDst[it]);
      }
      __syncthreads();

      floatx4 sacc[4];
#pragma unroll
      for (int j = 0; j < 4; ++j) { floatx4 z = {0.f, 0.f, 0.f, 0.f}; sacc[j] = z; }
#pragma unroll
      for (int hh = 0; hh < 2; ++hh) {
        short8 aq = *(const short8*)(Qs + qOff[hh]);
#pragma unroll
        for (int j = 0; j < 4; ++j)
          sacc[j] = __builtin_amdgcn_mfma_f32_16x16x32_bf16(
              aq, *(const short8*)(Ks + kvOff[j][hh]), sacc[j], 0, 0, 0);
      }

      const bool lastTile = (kt == nkt - 1);
#pragma unroll
      for (int j = 0; j < 4; ++j) {
        int sw = ((j ^ quad) << 4) + l15;
        int colg = j * 16 + l15;
#pragma unroll
        for (int r = 0; r < 4; ++r) {
          float p = __expf(sacc[j][r]);
          if (lastTile && colg > rowl + r) p = 0.f;
          pw[(quad * 4 + r) * 64 + sw] = (bf16)p;
        }
      }
      asm volatile("s_waitcnt lgkmcnt(0)" ::: "memory");
#pragma unroll
      for (int hh = 0; hh < 2; ++hh) {
        short8 ap = *(const short8*)(pw + pOff[hh]);
#pragma unroll
        for (int j = 0; j < 4; ++j)
          oacc[j] = __builtin_amdgcn_mfma_f32_16x16x32_bf16(
              ap, *(const short8*)(Vs + kvOff[j][hh]), oacc[j], 0, 0, 0);
        sumacc = __builtin_amdgcn_mfma_f32_16x16x32_bf16(ap, onesb, sumacc, 0, 0, 0);
      }
    }

    float inv[4];
#pragma unroll
    for (int r = 0; r < 4; ++r) inv[r] = 1.f / sumacc[r];
#pragma unroll
    for (int j = 0; j < 4; ++j)
#pragma unroll
      for (int r = 0; r < 4; ++r) {
        int t = b * SEQ + q0 + rowl + r;
        AO[(size_t)t * DM + h * 64 + j * 16 + l15] = (bf16)(oacc[j][r] * inv[r]);
      }
  }
}

// ------------------------------------------------- capacity assignment (9 blocks)
// blocks 0..7: per-expert compaction; block 8: identity fill for shared slots
__global__ __launch_bounds__(256) void assign_kernel(
    const int* __restrict__ tIdx, const float* __restrict__ tW,
    int* __restrict__ tokList, float* __restrict__ gateW,
    int* __restrict__ neCnt, int* __restrict__ cntFull, int* __restrict__ slotOf) {
  int e = blockIdx.x;
  int tid = threadIdx.x, lane = tid & 63, wv = tid >> 6;
  if (e == 8) {
    for (int t = tid; t < TTOK; t += 256) {
      tokList[NSLOT + t] = t;
      gateW[NSLOT + t] = 1.0f;
    }
    if (tid == 0) neCnt[8] = TTOK;
    return;
  }
  __shared__ int waveTot[4];
  __shared__ int offs;
  if (tid == 0) offs = 0;
  __syncthreads();
  for (int base = 0; base < TTOK; base += 256) {
    int t = base + tid;
    int a = tIdx[t * 2], b2 = tIdx[t * 2 + 1];
    bool sel = (a == e) || (b2 == e);
    unsigned long long mask = __ballot(sel);
    int wrank = __popcll(mask & ((1ull << lane) - 1ull));
    if (lane == 0) waveTot[wv] = __popcll(mask);
    __syncthreads();
    int pre = offs;
    for (int w2 = 0; w2 < wv; ++w2) pre += waveTot[w2];
    int rank = pre + wrank;
    if (sel && rank < CAPT) {
      int slot = e * CAPT + rank;
      tokList[slot] = t;
      gateW[slot] = (a == e) ? tW[t * 2] : tW[t * 2 + 1];
      slotOf[t * 2 + ((a == e) ? 0 : 1)] = slot;
    }
    __syncthreads();
    if (tid == 0) offs += waveTot[0] + waveTot[1] + waveTot[2] + waveTot[3];
    __syncthreads();
  }
  if (tid == 0) {
    cntFull[e] = offs;
    neCnt[e] = offs < CAPT ? offs : CAPT;
  }
}

// ---------------------------------------------------------------- aux loss / util
__global__ __launch_bounds__(256) void aux_kernel(
    const float* __restrict__ probs, const int* __restrict__ cntFull,
    float* __restrict__ outAux) {
  __shared__ float psum[8];
  if (threadIdx.x < 8) psum[threadIdx.x] = 0.f;
  __syncthreads();
  float lp[8] = {0, 0, 0, 0, 0, 0, 0, 0};
  for (int t = threadIdx.x; t < TTOK; t += 256) {
#pragma unroll
    for (int e = 0; e < 8; ++e) lp[e] += probs[t * 8 + e];
  }
#pragma unroll
  for (int e = 0; e < 8; ++e)
#pragma unroll
    for (int off = 1; off < 64; off <<= 1) lp[e] += __shfl_xor(lp[e], off);
  if ((threadIdx.x & 63) == 0)
#pragma unroll
    for (int e = 0; e < 8; ++e) atomicAdd(&psum[e], lp[e]);
  __syncthreads();
  if (threadIdx.x == 0) {
    float aux = 0.f; int used = 0;
    for (int e = 0; e < 8; ++e) {
      aux += (psum[e] / (float)TTOK) * ((float)cntFull[e] / (float)TTOK);
      if (cntFull[e] > 0) used++;
    }
    outAux[0] = 8.f * aux;
    outAux[1] = 100.f * (float)used / 8.f;
  }
}

// ------------------------- combine: out = hbuf + shared eo + <=2 gated eo rows
__global__ __launch_bounds__(256) void combine_kernel(
    float* __restrict__ outp, const float* __restrict__ hbuf,
    const bf16* __restrict__ eo, const int* __restrict__ slotOf) {
  int t = blockIdx.x, tid = threadIdx.x;
  float4 v = ((const float4*)(hbuf + (size_t)t * DM))[tid];
  bf4 sh = ((const bf4*)(eo + (size_t)(NSLOT + t) * DM))[tid];
  v.x += (float)sh.x; v.y += (float)sh.y; v.z += (float)sh.z; v.w += (float)sh.w;
  int s0 = slotOf[t * 2], s1 = slotOf[t * 2 + 1];
  if (s0 >= 0) {
    bf4 e = ((const bf4*)(eo + (size_t)s0 * DM))[tid];
    v.x += (float)e.x; v.y += (float)e.y; v.z += (float)e.z; v.w += (float)e.w;
  }
  if (s1 >= 0) {
    bf4 e = ((const bf4*)(eo + (size_t)s1 * DM))[tid];
    v.x += (float)e.x; v.y += (float)e.y; v.z += (float)e.z; v.w += (float)e.w;
  }
  ((float4*)(outp + (size_t)t * DM))[tid] = v;
}

// ---------------------------------------------------------------- launch
extern "C" void kernel_launch(void* const* d_in, const int* in_sizes, int n_in,
                              void* d_out, int out_size, void* d_ws, size_t ws_size,
                              hipStream_t stream) {
  (void)in_sizes; (void)n_in; (void)out_size; (void)ws_size;
  const float* x     = (const float*)d_in[0];
  const float* cosb  = (const float*)d_in[1];
  const float* sinb  = (const float*)d_in[2];
  const float* attnw = (const float*)d_in[4];
  const float* moew  = (const float*)d_in[5];
  const float* wq  = (const float*)d_in[6];
  const float* wk  = (const float*)d_in[7];
  const float* wv  = (const float*)d_in[8];
  const float* wo  = (const float*)d_in[9];
  const float* rw  = (const float*)d_in[10];
  const float* ew1 = (const float*)d_in[11];
  const float* ew2 = (const float*)d_in[12];
  const float* ew3 = (const float*)d_in[13];
  const float* sw1 = (const float*)d_in[14];
  const float* sw2 = (const float*)d_in[15];
  const float* sw3 = (const float*)d_in[16];

  float* outp = (float*)d_out;
  float* auxp = outp + 4194304;
  float* newk = outp + 4194306;
  float* newv = newk + 1048576;

  char* wsp = (char*)d_ws;
  size_t off = 0;
  auto alloc = [&](size_t bytes) -> void* {
    void* p = wsp + off; off += (bytes + 255) & ~(size_t)255; return p;
  };
  bf16* wqkvT = (bf16*)alloc((size_t)1536 * 1024 * 2);
  bf16* woT   = (bf16*)alloc((size_t)1024 * 1024 * 2);
  bf16* ew1T  = (bf16*)alloc((size_t)9 * HIDDEN * 1024 * 2);   // slice 8 = sw1
  bf16* ew3T  = (bf16*)alloc((size_t)9 * HIDDEN * 1024 * 2);   // slice 8 = sw3
  bf16* ew2T  = (bf16*)alloc((size_t)9 * 1024 * HIDP * 2);     // slice 8 = sw2
  bf16* xn    = (bf16*)alloc((size_t)TTOK * DM * 2);
  bf16* qb    = (bf16*)alloc((size_t)TTOK * DM * 2);
  bf16* kb    = (bf16*)alloc((size_t)TTOK * 256 * 2);
  bf16* vb    = (bf16*)alloc((size_t)TTOK * 256 * 2);
  bf16* vt    = (bf16*)alloc((size_t)TTOK * 256 * 2);
  bf16* ao    = (bf16*)alloc((size_t)TTOK * DM * 2);
  float* hbuf = (float*)alloc((size_t)TTOK * DM * 4);
  bf16* hn    = (bf16*)alloc((size_t)TTOK * DM * 2);
  float* probs = (float*)alloc((size_t)TTOK * 8 * 4);
  int*   tIdx  = (int*)alloc((size_t)TTOK * 2 * 4);
  float* tW    = (float*)alloc((size_t)TTOK * 2 * 4);
  int*   tokList = (int*)alloc((size_t)TSLOT * 4);
  float* gateW   = (float*)alloc((size_t)TSLOT * 4);
  int*   neCnt   = (int*)alloc(64);
  int*   cntFull = (int*)alloc(64);
  int*   slotOf  = (int*)alloc((size_t)TTOK * 2 * 4);
  bf16*  mact = (bf16*)alloc((size_t)TSLOT * HIDP * 2);
  bf16*  eo   = (bf16*)alloc((size_t)TSLOT * DM * 2);

  EpiAux nil{};
  EpiAux ropeAux{cosb, sinb, qb, kb, vb, newk, newv};

  // ---- weight convert + transpose (merged: 10 launches -> 5)
  transpose_cvt_qkvo<<<dim3(40, 16), 256, 0, stream>>>(wq, wk, wv, wo, wqkvT, woT);
  transpose_cvt_pair<<<dim3(22, 16, 16), 256, 0, stream>>>(
      ew1, ew3, ew1T, ew3T, 1024, HIDDEN, 1024,
      (long)1024 * HIDDEN, (long)HIDDEN * 1024, 8);
  transpose_cvt_pair<<<dim3(22, 16, 2), 256, 0, stream>>>(
      sw1, sw3, ew1T + (size_t)8 * HIDDEN * 1024, ew3T + (size_t)8 * HIDDEN * 1024,
      1024, HIDDEN, 1024, 0, 0, 1);
  transpose_cvt<<<dim3(16, 22, NEXP), 256, 0, stream>>>(ew2, ew2T, HIDDEN, 1024, HIDP,
      (long)HIDDEN * 1024, (long)1024 * HIDP);
  transpose_cvt<<<dim3(16, 22, 1), 256, 0, stream>>>(sw2, ew2T + (size_t)8 * 1024 * HIDP,
      HIDDEN, 1024, HIDP, 0, 0);

  // ---- attention path (64-row M-tiles: xPerXcd = 4096/64/8 = 8)
  rmsnorm_kernel<<<TTOK, 256, 0, stream>>>(x, attnw, xn);
  gemm_bt<4><<<8 * 8 * 12, 256, 0, stream>>>(
      xn, wqkvT, TTOK, 1536, 1024, 1024, 1024, 8, nullptr, 0, nullptr, ropeAux);
  vt_kernel<<<dim3(32, 8), 256, 0, stream>>>(vb, vt);
  attn_kernel<<<dim3(16, NHEAD, 2), 256, 0, stream>>>(qb, kb, vt, ao);
  gemm_bt<2><<<8 * 8 * 8, 256, 0, stream>>>(
      ao, woT, TTOK, 1024, 1024, 1024, 1024, 8, hbuf, 1024, x, nil);

  // ---- MoE routing
  rmsnorm_router_kernel<<<TTOK, 256, 0, stream>>>(hbuf, moew, rw, hn, probs, tIdx, tW);
  hipMemsetAsync(slotOf, 0xFF, (size_t)TTOK * 2 * 4, stream);
  assign_kernel<<<9, 256, 0, stream>>>(tIdx, tW, tokList, gateW, neCnt, cntFull, slotOf);
  aux_kernel<<<1, 256, 0, stream>>>(probs, cntFull, auxp);

  // ---- experts (8 routed + shared as expert 8)
  gemm_dual9<<<8 * XBT * 11, 256, 0, stream>>>(hn, ew1T, ew3T, mact, tokList, neCnt);
  gemm_down9<<<8 * XBT * 16, 256, 0, stream>>>(mact, ew2T, eo, gateW, neCnt);
  combine_kernel<<<TTOK, 256, 0, stream>>>(outp, hbuf, eo, slotOf);
}

// Round 11
// 537.263 us; speedup vs baseline: 1.1052x; 1.0015x over previous
//
#include <hip/hip_runtime.h>
#include <hip/hip_bf16.h>
#include <math.h>

typedef __hip_bfloat16 bf16;
typedef __attribute__((ext_vector_type(8))) short short8;
typedef __attribute__((ext_vector_type(4))) float floatx4;

#define SEQ    2048
#define TTOK   4096
#define DM     1024
#define NHEAD  16
#define NKVH   4
#define HD     64
#define NEXP   8
#define HIDDEN 1365
#define HIDP   1408
#define CAPT   1280
#define NSLOT  (NEXP*CAPT)      /* 10240 routed slots */
#define TSLOT  (NSLOT+TTOK)     /* 14336: + shared-expert identity slots */
#define XPE    (CAPT/128)       /* 10 routed 128-row M-blocks per expert */
#define XBT    14               /* per-XCD 128-row M-blocks: 10 routed + 4 shared */

// ---------------------------------------------------------------- utilities
__device__ __forceinline__ void gld16(const void* g, void* l) {
  __builtin_amdgcn_global_load_lds((const __attribute__((address_space(1))) void*)g,
                                   (__attribute__((address_space(3))) void*)l,
                                   16, 0, 0);
}

struct __align__(8) bf4 { bf16 x, y, z, w; };

struct EpiAux {
  const float* cosb; const float* sinb;
  bf16* qb; bf16* kb; bf16* vb; float* newk; float* newv;
};

// ---------------------------------------------------- weight convert+transpose
// Shared body: (K,N) f32 row-major -> (N,Kp) bf16 row-major for one 64x64 tile.
__device__ __forceinline__ void tcvt_body(
    const float* __restrict__ src, bf16* __restrict__ dst,
    int K, int N, int Kp, int k0, int n0, float (*tile)[65]) {
  const int tid = threadIdx.x;
  const int lr = tid >> 4, lc = (tid & 15) * 4;
#pragma unroll
  for (int i = 0; i < 4; ++i) {
    int k = k0 + lr + i * 16;
    int n = n0 + lc;
    float4 v = {0.f, 0.f, 0.f, 0.f};
    if (k < K) {
      if (n + 3 < N) v = *(const float4*)(src + (size_t)k * N + n);
      else {
        float* vp = (float*)&v;
        for (int e = 0; e < 4; ++e) if (n + e < N) vp[e] = src[(size_t)k * N + n + e];
      }
    }
    tile[lr + i * 16][lc] = v.x; tile[lr + i * 16][lc + 1] = v.y;
    tile[lr + i * 16][lc + 2] = v.z; tile[lr + i * 16][lc + 3] = v.w;
  }
  __syncthreads();
  const int n = tid >> 2, kk0 = (tid & 3) * 16;
  if (n0 + n < N) {
    bf16 buf[16];
#pragma unroll
    for (int e = 0; e < 16; ++e) buf[e] = (bf16)tile[kk0 + e][n];
    bf16* dp = dst + (size_t)(n0 + n) * Kp + k0 + kk0;
    *(short8*)dp = *(short8*)buf;
    *(short8*)(dp + 8) = *(short8*)(buf + 8);
  }
}

// Dual-source variant: z<splitZ -> (src0,dst0) slice z; else (src1,dst1) slice z-splitZ.
__global__ __launch_bounds__(256) void transpose_cvt_pair(
    const float* __restrict__ src0, const float* __restrict__ src1,
    bf16* __restrict__ dst0, bf16* __restrict__ dst1,
    int K, int N, int Kp, long srcZ, long dstZ, int splitZ) {
  __shared__ float tile[64][65];
  const float* src; bf16* dst;
  int z = blockIdx.z;
  if (z < splitZ) { src = src0 + (size_t)z * srcZ; dst = dst0 + (size_t)z * dstZ; }
  else { int zz = z - splitZ; src = src1 + (size_t)zz * srcZ; dst = dst1 + (size_t)zz * dstZ; }
  tcvt_body(src, dst, K, N, Kp, blockIdx.y * 64, blockIdx.x * 64, tile);
}

// Quad-source variant: z<8 -> s0 slice z; z<16 -> s1 slice z-8; z==16 -> s2; z==17 -> s3.
__global__ __launch_bounds__(256) void transpose_cvt_quad(
    const float* __restrict__ s0, const float* __restrict__ s1,
    const float* __restrict__ s2, const float* __restrict__ s3,
    bf16* __restrict__ d0, bf16* __restrict__ d1,
    bf16* __restrict__ d2, bf16* __restrict__ d3,
    int K, int N, int Kp, long srcZ, long dstZ) {
  __shared__ float tile[64][65];
  const float* src; bf16* dst;
  int z = blockIdx.z;
  if (z < 8)        { src = s0 + (size_t)z * srcZ;       dst = d0 + (size_t)z * dstZ; }
  else if (z < 16)  { src = s1 + (size_t)(z - 8) * srcZ; dst = d1 + (size_t)(z - 8) * dstZ; }
  else if (z == 16) { src = s2; dst = d2; }
  else              { src = s3; dst = d3; }
  tcvt_body(src, dst, K, N, Kp, blockIdx.y * 64, blockIdx.x * 64, tile);
}

// All four dense weights (wq/wk/wv/wo) in one launch: grid (40,16).
__global__ __launch_bounds__(256) void transpose_cvt_qkvo(
    const float* __restrict__ wq, const float* __restrict__ wk,
    const float* __restrict__ wv, const float* __restrict__ wo,
    bf16* __restrict__ wqkvT, bf16* __restrict__ woT) {
  __shared__ float tile[64][65];
  const float* src; bf16* dst; int N, n0;
  int bx = blockIdx.x;
  if (bx < 16)      { src = wq; dst = wqkvT;                       N = 1024; n0 = bx * 64; }
  else if (bx < 20) { src = wk; dst = wqkvT + (size_t)1024 * 1024; N = 256;  n0 = (bx - 16) * 64; }
  else if (bx < 24) { src = wv; dst = wqkvT + (size_t)1280 * 1024; N = 256;  n0 = (bx - 20) * 64; }
  else              { src = wo; dst = woT;                         N = 1024; n0 = (bx - 24) * 64; }
  tcvt_body(src, dst, 1024, N, 1024, blockIdx.y * 64, n0, tile);
}

// ---------------------------------------------------------------- rmsnorm
__global__ __launch_bounds__(256) void rmsnorm_kernel(
    const float* __restrict__ x, const float* __restrict__ w, bf16* __restrict__ out) {
  int t = blockIdx.x;
  const float* xr = x + (size_t)t * DM;
  float4 xv = *(const float4*)(xr + threadIdx.x * 4);
  float ss = xv.x * xv.x + xv.y * xv.y + xv.z * xv.z + xv.w * xv.w;
#pragma unroll
  for (int off = 1; off < 64; off <<= 1) ss += __shfl_xor(ss, off);
  __shared__ float sred[4];
  if ((threadIdx.x & 63) == 0) sred[threadIdx.x >> 6] = ss;
  __syncthreads();
  float scale = rsqrtf((sred[0] + sred[1] + sred[2] + sred[3]) * (1.f / DM) + 1e-6f);
  float4 wv = *(const float4*)(w + threadIdx.x * 4);
  bf4 o;
  o.x = (bf16)(xv.x * scale * wv.x); o.y = (bf16)(xv.y * scale * wv.y);
  o.z = (bf16)(xv.z * scale * wv.z); o.w = (bf16)(xv.w * scale * wv.w);
  ((bf4*)(out + (size_t)t * DM))[threadIdx.x] = o;
}

// -------------------------------------------- rmsnorm + router (moe path)
// Also initializes slotOf[t*2..t*2+1] = -1 (replaces the hipMemsetAsync dispatch;
// runs before assign_kernel on the same stream).
__global__ __launch_bounds__(256) void rmsnorm_router_kernel(
    const float* __restrict__ x, const float* __restrict__ w, const float* __restrict__ rw,
    bf16* __restrict__ out, float* __restrict__ probs,
    int* __restrict__ tIdx, float* __restrict__ tW, int* __restrict__ slotOf) {
  int t = blockIdx.x;
  int tid = threadIdx.x, lane = tid & 63, wv = tid >> 6;
  const float* xr = x + (size_t)t * DM;
  float4 xv = *(const float4*)(xr + tid * 4);
  float ss = xv.x * xv.x + xv.y * xv.y + xv.z * xv.z + xv.w * xv.w;
#pragma unroll
  for (int off = 1; off < 64; off <<= 1) ss += __shfl_xor(ss, off);
  __shared__ float sred[4];
  __shared__ float red[4][8];
  if (lane == 0) sred[wv] = ss;
  __syncthreads();
  float scale = rsqrtf((sred[0] + sred[1] + sred[2] + sred[3]) * (1.f / DM) + 1e-6f);
  float4 wvv = *(const float4*)(w + tid * 4);
  float y[4] = {xv.x * scale * wvv.x, xv.y * scale * wvv.y,
                xv.z * scale * wvv.z, xv.w * scale * wvv.w};
  bf4 o; o.x = (bf16)y[0]; o.y = (bf16)y[1]; o.z = (bf16)y[2]; o.w = (bf16)y[3];
  ((bf4*)(out + (size_t)t * DM))[tid] = o;
  float acc[8] = {0, 0, 0, 0, 0, 0, 0, 0};
#pragma unroll
  for (int dd = 0; dd < 4; ++dd) {
    const float* rwr = rw + (size_t)(tid * 4 + dd) * 8;
#pragma unroll
    for (int e = 0; e < 8; ++e) acc[e] += y[dd] * rwr[e];
  }
#pragma unroll
  for (int e = 0; e < 8; ++e)
#pragma unroll
    for (int off = 1; off < 64; off <<= 1) acc[e] += __shfl_xor(acc[e], off);
  if (lane == 0)
#pragma unroll
    for (int e = 0; e < 8; ++e) red[wv][e] = acc[e];
  __syncthreads();
  if (tid == 0) {
    float lg[8];
#pragma unroll
    for (int e = 0; e < 8; ++e) lg[e] = red[0][e] + red[1][e] + red[2][e] + red[3][e];
    float mx = lg[0];
#pragma unroll
    for (int e = 1; e < 8; ++e) mx = fmaxf(mx, lg[e]);
    float p[8], se = 0.f;
#pragma unroll
    for (int e = 0; e < 8; ++e) { p[e] = __expf(lg[e] - mx); se += p[e]; }
#pragma unroll
    for (int e = 0; e < 8; ++e) { p[e] /= se; probs[t * 8 + e] = p[e]; }
    int i1 = 0;
#pragma unroll
    for (int e = 1; e < 8; ++e) if (p[e] > p[i1]) i1 = e;
    int i2 = (i1 == 0) ? 1 : 0;
#pragma unroll
    for (int e = 0; e < 8; ++e) if (e != i1 && p[e] > p[i2]) i2 = e;
    float s = p[i1] + p[i2];
    tIdx[t * 2] = i1; tIdx[t * 2 + 1] = i2;
    tW[t * 2] = p[i1] / s; tW[t * 2 + 1] = p[i2] / s;
    slotOf[t * 2] = -1; slotOf[t * 2 + 1] = -1;
  }
}

// ---------------------------------------------------------------- dense GEMM
// 64x128 tile (2 M-frags/wave): doubles grid vs 128x128 so QKV gets 3 blocks/CU
// and WO 2 blocks/CU. EPI: 2 = Cf = resid + acc ; 4 = QKV+rope.
template <int EPI>
__global__ __launch_bounds__(256) void gemm_bt(
    const bf16* __restrict__ A, const bf16* __restrict__ Bt,
    int M, int N, int K, int lda, int ldb, int xPerXcd,
    float* __restrict__ Cf, int ldc,
    const float* __restrict__ resid, EpiAux aux) {
  __shared__ __align__(16) bf16 As[64 * 64];
  __shared__ __align__(16) bf16 Bs[128 * 64];
  const int tid = threadIdx.x, lane = tid & 63, wave = tid >> 6;
  const int f = blockIdx.x, lo = f >> 3;
  int xb = (f & 7) * xPerXcd + lo % xPerXcd;
  int n0 = (lo / xPerXcd) * 128;
  int m0 = xb * 64;

  const bf16* aSrc[2]; const bf16* bSrc[4];
  bf16* aDst[2]; bf16* bDst[4];
#pragma unroll
  for (int it = 0; it < 2; ++it) {
    int c = it * 256 + tid;
    int r = c >> 3, q = c & 7;
    int kq = q ^ (r & 7);
    aSrc[it] = A + (long)(m0 + r) * lda + kq * 8;
    aDst[it] = As + (size_t)(it * 256 + wave * 64) * 8;
  }
#pragma unroll
  for (int it = 0; it < 4; ++it) {
    int c = it * 256 + tid;
    int r = c >> 3, q = c & 7;
    int kq = q ^ (r & 7);
    bSrc[it] = Bt + (long)(n0 + r) * ldb + kq * 8;
    bDst[it] = Bs + (size_t)(it * 256 + wave * 64) * 8;
  }

  floatx4 acc[2][4];
#pragma unroll
  for (int i = 0; i < 2; ++i)
#pragma unroll
    for (int j = 0; j < 4; ++j) { floatx4 z = {0.f, 0.f, 0.f, 0.f}; acc[i][j] = z; }

  const int wm = (wave & 1) * 32, wn = (wave >> 1) * 64;
  const int l15 = lane & 15, quad = lane >> 4;
  int aOff[2][2], bOff[4][2];
#pragma unroll
  for (int h = 0; h < 2; ++h) {
#pragma unroll
    for (int i = 0; i < 2; ++i) {
      int m = wm + i * 16 + l15;
      aOff[i][h] = (((m << 3) | ((h * 4 + quad) ^ (m & 7))) << 3);
    }
#pragma unroll
    for (int j = 0; j < 4; ++j) {
      int n = wn + j * 16 + l15;
      bOff[j][h] = (((n << 3) | ((h * 4 + quad) ^ (n & 7))) << 3);
    }
  }

  const int kIters = K >> 6;
  for (int kt = 0; kt < kIters; ++kt) {
    __syncthreads();
#pragma unroll
    for (int it = 0; it < 2; ++it) { gld16(aSrc[it], aDst[it]); aSrc[it] += 64; }
#pragma unroll
    for (int it = 0; it < 4; ++it) { gld16(bSrc[it], bDst[it]); bSrc[it] += 64; }
    __syncthreads();
#pragma unroll
    for (int h = 0; h < 2; ++h) {
      short8 af[2], bfr[4];
#pragma unroll
      for (int i = 0; i < 2; ++i) af[i] = *(const short8*)(As + aOff[i][h]);
#pragma unroll
      for (int j = 0; j < 4; ++j) bfr[j] = *(const short8*)(Bs + bOff[j][h]);
#pragma unroll
      for (int i = 0; i < 2; ++i)
#pragma unroll
        for (int j = 0; j < 4; ++j)
          acc[i][j] = __builtin_amdgcn_mfma_f32_16x16x32_bf16(af[i], bfr[j], acc[i][j], 0, 0, 0);
    }
  }

  if constexpr (EPI == 4) {
#pragma unroll
    for (int i = 0; i < 2; ++i) {
#pragma unroll
      for (int r = 0; r < 4; ++r) {
        int row = wm + i * 16 + quad * 4 + r;
        int t = m0 + row;
        int s = t & (SEQ - 1);
        if (n0 < 1024) {
#pragma unroll
          for (int j = 0; j < 2; ++j) {
            int col = n0 + wn + j * 16 + l15;
            int dlo = col & 63;
            float x1 = acc[i][j][r], x2 = acc[i][j + 2][r];
            float ch = aux.cosb[s * 64 + dlo], sh = aux.sinb[s * 64 + dlo];
            aux.qb[(size_t)t * DM + col]      = (bf16)((x1 * ch - x2 * sh) * 0.125f);
            aux.qb[(size_t)t * DM + col + 32] = (bf16)((x1 * sh + x2 * ch) * 0.125f);
          }
        } else if (n0 < 1280) {
#pragma unroll
          for (int j = 0; j < 2; ++j) {
            int ck = n0 + wn + j * 16 + l15 - 1024;
            int dlo = ck & 63;
            float x1 = acc[i][j][r], x2 = acc[i][j + 2][r];
            float ch = aux.cosb[s * 64 + dlo], sh = aux.sinb[s * 64 + dlo];
            float o1 = x1 * ch - x2 * sh, o2 = x1 * sh + x2 * ch;
            aux.kb[(size_t)t * 256 + ck]        = (bf16)o1;
            aux.kb[(size_t)t * 256 + ck + 32]   = (bf16)o2;
            aux.newk[(size_t)t * 256 + ck]      = o1;
            aux.newk[(size_t)t * 256 + ck + 32] = o2;
          }
        } else {
#pragma unroll
          for (int j = 0; j < 4; ++j) {
            int cv = n0 + wn + j * 16 + l15 - 1280;
            float v = acc[i][j][r];
            aux.vb[(size_t)t * 256 + cv]   = (bf16)v;
            aux.newv[(size_t)t * 256 + cv] = v;
          }
        }
      }
    }
    return;
  }
#pragma unroll
  for (int i = 0; i < 2; ++i) {
#pragma unroll
    for (int j = 0; j < 4; ++j) {
      int col = n0 + wn + j * 16 + l15;
#pragma unroll
      for (int r = 0; r < 4; ++r) {
        int row = wm + i * 16 + quad * 4 + r;
        size_t o = (size_t)(m0 + row) * ldc + col;
        Cf[o] = resid[o] + acc[i][j][r];
      }
    }
  }
}

// --------------------------------------------------- slot-block decode helper
__device__ __forceinline__ bool slot_block(
    int f, int NY, const int* neCnt, int& expert, int& m0, int& mLimit, int& n0) {
  int xcd = f & 7, lo = f >> 3;
  int xb = lo / NY, y = lo % NY;
  n0 = y * 64;
  if (xb < XPE) {
    expert = xcd;
    int ne = neCnt[xcd];
    if (xb * 128 >= ne) return false;
    m0 = xcd * CAPT + xb * 128;
    mLimit = ne - xb * 128;
    if (mLimit > 128) mLimit = 128;
  } else {
    expert = 8;
    int sb = xcd * 4 + (xb - XPE);
    m0 = NSLOT + sb * 128;
    mLimit = 128;
  }
  return true;
}

// ------------------------------------------------------ MoE dual GEMM + swiglu
// 128x128 tile, dual-B (B1,B3 share the staged A): 48 KB LDS, 256 thr / 4 waves,
// m97-style 2-barrier schedule. ~800 TF measured (r3) — near structural ceiling.
__global__ __launch_bounds__(256, 2) void gemm_dual9(
    const bf16* __restrict__ A, const bf16* __restrict__ B1t, const bf16* __restrict__ B3t,
    bf16* __restrict__ mact,
    const int* __restrict__ tokList, const int* __restrict__ neCnt) {
  __shared__ __align__(16) bf16 As[128 * 64];
  __shared__ __align__(16) bf16 B1s[128 * 64];
  __shared__ __align__(16) bf16 B3s[128 * 64];
  const int tid = threadIdx.x, lane = tid & 63, wave = tid >> 6;
  int expert, m0, mLimit, n0;
  if (!slot_block(blockIdx.x, 11, neCnt, expert, m0, mLimit, n0)) return;
  n0 <<= 1;  // 128-wide N-tiles
  const bf16* B1e = B1t + (long)expert * (HIDDEN * 1024);
  const bf16* B3e = B3t + (long)expert * (HIDDEN * 1024);

  const bf16* aSrc[4]; const bf16* b1Src[4]; const bf16* b3Src[4];
  bf16* aDst[4]; bf16* b1Dst[4]; bf16* b3Dst[4];
#pragma unroll
  for (int it = 0; it < 4; ++it) {
    int c = it * 256 + tid;
    int r = c >> 3, q = c & 7;
    int kq = q ^ (r & 7);
    int rr = r < mLimit ? r : (mLimit - 1);
    aSrc[it] = A + (long)tokList[m0 + rr] * 1024 + kq * 8;
    aDst[it] = As + (size_t)(it * 256 + wave * 64) * 8;
    int nn = n0 + r; if (nn > HIDDEN - 1) nn = HIDDEN - 1;
    b1Src[it] = B1e + (long)nn * 1024 + kq * 8;
    b3Src[it] = B3e + (long)nn * 1024 + kq * 8;
    b1Dst[it] = B1s + (size_t)(it * 256 + wave * 64) * 8;
    b3Dst[it] = B3s + (size_t)(it * 256 + wave * 64) * 8;
  }

  floatx4 acc1[4][4], acc3[4][4];
#pragma unroll
  for (int i = 0; i < 4; ++i)
#pragma unroll
    for (int j = 0; j < 4; ++j) {
      floatx4 z = {0.f, 0.f, 0.f, 0.f};
      acc1[i][j] = z; acc3[i][j] = z;
    }

  const int wm = (wave & 1) * 64, wn = (wave >> 1) * 64;
  const int l15 = lane & 15, quad = lane >> 4;
  int aOff[4][2], bOff[4][2];
#pragma unroll
  for (int h = 0; h < 2; ++h) {
#pragma unroll
    for (int i = 0; i < 4; ++i) {
      int m = wm + i * 16 + l15;
      aOff[i][h] = (((m << 3) | ((h * 4 + quad) ^ (m & 7))) << 3);
    }
#pragma unroll
    for (int j = 0; j < 4; ++j) {
      int n = wn + j * 16 + l15;
      bOff[j][h] = (((n << 3) | ((h * 4 + quad) ^ (n & 7))) << 3);
    }
  }

  for (int kt = 0; kt < 16; ++kt) {
    __syncthreads();
#pragma unroll
    for (int it = 0; it < 4; ++it) { gld16(aSrc[it], aDst[it]); aSrc[it] += 64; }
#pragma unroll
    for (int it = 0; it < 4; ++it) {
      gld16(b1Src[it], b1Dst[it]); b1Src[it] += 64;
      gld16(b3Src[it], b3Dst[it]); b3Src[it] += 64;
    }
    __syncthreads();
#pragma unroll
    for (int h = 0; h < 2; ++h) {
      short8 af[4];
#pragma unroll
      for (int i = 0; i < 4; ++i) af[i] = *(const short8*)(As + aOff[i][h]);
#pragma unroll
      for (int j = 0; j < 4; ++j) {
        short8 b1f = *(const short8*)(B1s + bOff[j][h]);
        short8 b3f = *(const short8*)(B3s + bOff[j][h]);
#pragma unroll
        for (int i = 0; i < 4; ++i) {
          acc1[i][j] = __builtin_amdgcn_mfma_f32_16x16x32_bf16(af[i], b1f, acc1[i][j], 0, 0, 0);
          acc3[i][j] = __builtin_amdgcn_mfma_f32_16x16x32_bf16(af[i], b3f, acc3[i][j], 0, 0, 0);
        }
      }
    }
  }

#pragma unroll
  for (int i = 0; i < 4; ++i) {
#pragma unroll
    for (int j = 0; j < 4; ++j) {
      int col = n0 + wn + j * 16 + l15;
#pragma unroll
      for (int r = 0; r < 4; ++r) {
        int row = wm + i * 16 + quad * 4 + r;
        if (row >= mLimit) continue;
        float a1 = acc1[i][j][r], a3 = acc3[i][j][r];
        float sl = a1 / (1.f + __expf(-a1));
        mact[(size_t)(m0 + row) * HIDP + col] = (col < HIDDEN) ? (bf16)(sl * a3) : (bf16)0.f;
      }
    }
  }
}

// ------------------------------------------------------ MoE down GEMM (gated)
// 128x64 tile (r0 version — best measured); A = mact slots (no gather);
// eo[slot] = gateW[slot] * (A@ew2^T)
__global__ __launch_bounds__(256) void gemm_down9(
    const bf16* __restrict__ A, const bf16* __restrict__ B2t,
    bf16* __restrict__ eo,
    const float* __restrict__ gateW, const int* __restrict__ neCnt) {
  __shared__ __align__(16) bf16 As[128 * 64];
  __shared__ __align__(16) bf16 Bs[64 * 64];
  const int tid = threadIdx.x, lane = tid & 63, wave = tid >> 6;
  int expert, m0, mLimit, n0;
  if (!slot_block(blockIdx.x, 16, neCnt, expert, m0, mLimit, n0)) return;
  const bf16* Be = B2t + (long)expert * (1024 * HIDP);

  const bf16* aSrc[4]; const bf16* bSrc[2];
  bf16* aDst[4]; bf16* bDst[2];
#pragma unroll
  for (int it = 0; it < 4; ++it) {
    int c = it * 256 + tid;
    int r = c >> 3, q = c & 7;
    int kq = q ^ (r & 7);
    int rr = r < mLimit ? r : (mLimit - 1);
    aSrc[it] = A + (long)(m0 + rr) * HIDP + kq * 8;
    aDst[it] = As + (size_t)(it * 256 + wave * 64) * 8;
  }
#pragma unroll
  for (int it = 0; it < 2; ++it) {
    int c = it * 256 + tid;
    int r = c >> 3, q = c & 7;
    int kq = q ^ (r & 7);
    bSrc[it] = Be + (long)(n0 + r) * HIDP + kq * 8;
    bDst[it] = Bs + (size_t)(it * 256 + wave * 64) * 8;
  }

  floatx4 acc[4][2];
#pragma unroll
  for (int i = 0; i < 4; ++i)
#pragma unroll
    for (int j = 0; j < 2; ++j) { floatx4 z = {0.f, 0.f, 0.f, 0.f}; acc[i][j] = z; }

  const int wm = (wave & 1) * 64, wn = (wave >> 1) * 32;
  const int l15 = lane & 15, quad = lane >> 4;
  int aOff[4][2], bOff[2][2];
#pragma unroll
  for (int h = 0; h < 2; ++h) {
#pragma unroll
    for (int i = 0; i < 4; ++i) {
      int m = wm + i * 16 + l15;
      aOff[i][h] = (((m << 3) | ((h * 4 + quad) ^ (m & 7))) << 3);
    }
#pragma unroll
    for (int j = 0; j < 2; ++j) {
      int n = wn + j * 16 + l15;
      bOff[j][h] = (((n << 3) | ((h * 4 + quad) ^ (n & 7))) << 3);
    }
  }

  for (int kt = 0; kt < 22; ++kt) {
    __syncthreads();
#pragma unroll
    for (int it = 0; it < 4; ++it) { gld16(aSrc[it], aDst[it]); aSrc[it] += 64; }
#pragma unroll
    for (int it = 0; it < 2; ++it) { gld16(bSrc[it], bDst[it]); bSrc[it] += 64; }
    __syncthreads();
#pragma unroll
    for (int h = 0; h < 2; ++h) {
      short8 af[4];
#pragma unroll
      for (int i = 0; i < 4; ++i) af[i] = *(const short8*)(As + aOff[i][h]);
#pragma unroll
      for (int j = 0; j < 2; ++j) {
        short8 bf = *(const short8*)(Bs + bOff[j][h]);
#pragma unroll
        for (int i = 0; i < 4; ++i)
          acc[i][j] = __builtin_amdgcn_mfma_f32_16x16x32_bf16(af[i], bf, acc[i][j], 0, 0, 0);
      }
    }
  }

#pragma unroll
  for (int i = 0; i < 4; ++i) {
#pragma unroll
    for (int j = 0; j < 2; ++j) {
      int col = n0 + wn + j * 16 + l15;
#pragma unroll
      for (int r = 0; r < 4; ++r) {
        int row = wm + i * 16 + quad * 4 + r;
        if (row >= mLimit) continue;
        eo[(size_t)(m0 + row) * 1024 + col] = (bf16)(gateW[m0 + row] * acc[i][j][r]);
      }
    }
  }
}

// ------------------------------------------- V transpose: vb[t][256] -> vt[bg][d][s]
__global__ __launch_bounds__(256) void vt_kernel(
    const bf16* __restrict__ vb, bf16* __restrict__ vt) {
  __shared__ __align__(16) bf16 tile[64 * 72];
  int t0 = blockIdx.x * 64, bg = blockIdx.y;
  int b = bg >> 2, g = bg & 3;
  int tid = threadIdx.x;
  for (int c = tid; c < 512; c += 256) {
    int r = c >> 3, d8 = (c & 7) * 8;
    *(short8*)(tile + r * 72 + d8) =
        *(const short8*)(vb + (size_t)(b * SEQ + t0 + r) * 256 + g * 64 + d8);
  }
  __syncthreads();
  for (int c = tid; c < 512; c += 256) {
    int d = c >> 3, s8 = (c & 7) * 8;
    bf16 tmp[8];
#pragma unroll
    for (int x = 0; x < 8; ++x) tmp[x] = tile[(s8 + x) * 72 + d];
    *(short8*)(vt + ((size_t)bg * 64 + d) * SEQ + t0 + s8) = *(short8*)tmp;
  }
}

// ---------------------------------------------------------------- flash attention
// (r0 version — best measured; single-buffered K/V, paired q-tiles for perfect
// per-block load balance: pairI + (31-pairI) = 33 key-tiles per block)
__global__ __launch_bounds__(256) void attn_kernel(
    const bf16* __restrict__ Q, const bf16* __restrict__ Kc, const bf16* __restrict__ Vt,
    bf16* __restrict__ AO) {
  __shared__ __align__(16) bf16 Qs[64 * 64];
  __shared__ __align__(16) bf16 Ks[64 * 64];
  __shared__ __align__(16) bf16 Vs[64 * 64];
  __shared__ __align__(16) bf16 Ps[4][16 * 64];
  const int pairI = blockIdx.x, h = blockIdx.y, b = blockIdx.z;
  const int g = h >> 2;
  const int tid = threadIdx.x, lane = tid & 63, wave = tid >> 6;
  const int l15 = lane & 15, quad = lane >> 4;

  const bf16* kSrc[2]; const bf16* vSrc[2]; bf16* kDst[2]; bf16* vDst[2];
#pragma unroll
  for (int it = 0; it < 2; ++it) {
    int c = it * 256 + tid;
    int r = c >> 3, p = c & 7;
    int kq = p ^ (r & 7);
    kSrc[it] = Kc + (size_t)(b * SEQ + r) * 256 + g * 64 + kq * 8;
    vSrc[it] = Vt + ((size_t)(b * 4 + g) * 64 + r) * SEQ + kq * 8;
    kDst[it] = Ks + (size_t)(it * 256 + wave * 64) * 8;
    vDst[it] = Vs + (size_t)(it * 256 + wave * 64) * 8;
  }

  int qOff[2], kvOff[4][2], pOff[2];
#pragma unroll
  for (int hh = 0; hh < 2; ++hh) {
    int m = wave * 16 + l15;
    qOff[hh] = (m << 6) + (((hh * 4 + quad) ^ (m & 7)) << 3);
#pragma unroll
    for (int j = 0; j < 4; ++j) {
      int n = j * 16 + l15;
      kvOff[j][hh] = (n << 6) + (((hh * 4 + quad) ^ (n & 7)) << 3);
    }
    int cblk = (hh * 2 + (quad >> 1)) ^ (l15 >> 2);
    pOff[hh] = (l15 << 6) + (cblk << 4) + ((quad & 1) << 3);
  }
  bf16* pw = &Ps[wave][0];
  const int rowl = wave * 16 + quad * 4;

  short8 onesb;
#pragma unroll
  for (int e = 0; e < 8; ++e) onesb[e] = (short)0x3F80;

  for (int ph = 0; ph < 2; ++ph) {
    const int q0 = (ph == 0 ? pairI : 31 - pairI) * 64;
    __syncthreads();
#pragma unroll
    for (int it = 0; it < 2; ++it) {
      int c = it * 256 + tid;
      int r = c >> 3, p = c & 7;
      int kq = p ^ (r & 7);
      gld16(Q + (size_t)(b * SEQ + q0 + r) * DM + h * 64 + kq * 8,
            Qs + (size_t)(it * 256 + wave * 64) * 8);
    }

    floatx4 oacc[4], sumacc;
#pragma unroll
    for (int r = 0; r < 4; ++r) { floatx4 z = {0.f, 0.f, 0.f, 0.f}; oacc[r] = z; }
    { floatx4 z = {0.f, 0.f, 0.f, 0.f}; sumacc = z; }

    const int nkt = (q0 >> 6) + 1;
    for (int kt = 0; kt < nkt; ++kt) {
      __syncthreads();
#pragma unroll
      for (int it = 0; it < 2; ++it) {
        gld16(kSrc[it] + (size_t)kt * 64 * 256, kDst[it]);
        gld16(vSrc[it] + kt * 64, vDst[it]);
      }
      __syncthreads();

      floatx4 sacc[4];
#pragma unroll
      for (int j = 0; j < 4; ++j) { floatx4 z = {0.f, 0.f, 0.f, 0.f}; sacc[j] = z; }
#pragma unroll
      for (int hh = 0; hh < 2; ++hh) {
        short8 aq = *(const short8*)(Qs + qOff[hh]);
#pragma unroll
        for (int j = 0; j < 4; ++j)
          sacc[j] = __builtin_amdgcn_mfma_f32_16x16x32_bf16(
              aq, *(const short8*)(Ks + kvOff[j][hh]), sacc[j], 0, 0, 0);
      }

      const bool lastTile = (kt == nkt - 1);
#pragma unroll
      for (int j = 0; j < 4; ++j) {
        int sw = ((j ^ quad) << 4) + l15;
        int colg = j * 16 + l15;
#pragma unroll
        for (int r = 0; r < 4; ++r) {
          float p = __expf(sacc[j][r]);
          if (lastTile && colg > rowl + r) p = 0.f;
          pw[(quad * 4 + r) * 64 + sw] = (bf16)p;
        }
      }
      asm volatile("s_waitcnt lgkmcnt(0)" ::: "memory");
#pragma unroll
      for (int hh = 0; hh < 2; ++hh) {
        short8 ap = *(const short8*)(pw + pOff[hh]);
#pragma unroll
        for (int j = 0; j < 4; ++j)
          oacc[j] = __builtin_amdgcn_mfma_f32_16x16x32_bf16(
              ap, *(const short8*)(Vs + kvOff[j][hh]), oacc[j], 0, 0, 0);
        sumacc = __builtin_amdgcn_mfma_f32_16x16x32_bf16(ap, onesb, sumacc, 0, 0, 0);
      }
    }

    float inv[4];
#pragma unroll
    for (int r = 0; r < 4; ++r) inv[r] = 1.f / sumacc[r];
#pragma unroll
    for (int j = 0; j < 4; ++j)
#pragma unroll
      for (int r = 0; r < 4; ++r) {
        int t = b * SEQ + q0 + rowl + r;
        AO[(size_t)t * DM + h * 64 + j * 16 + l15] = (bf16)(oacc[j][r] * inv[r]);
      }
  }
}

// ------------------------------------------------- capacity assignment (9 blocks)
// blocks 0..7: per-expert compaction; block 8: identity fill for shared slots
__global__ __launch_bounds__(256) void assign_kernel(
    const int* __restrict__ tIdx, const float* __restrict__ tW,
    int* __restrict__ tokList, float* __restrict__ gateW,
    int* __restrict__ neCnt, int* __restrict__ cntFull, int* __restrict__ slotOf) {
  int e = blockIdx.x;
  int tid = threadIdx.x, lane = tid & 63, wv = tid >> 6;
  if (e == 8) {
    for (int t = tid; t < TTOK; t += 256) {
      tokList[NSLOT + t] = t;
      gateW[NSLOT + t] = 1.0f;
    }
    if (tid == 0) neCnt[8] = TTOK;
    return;
  }
  __shared__ int waveTot[4];
  __shared__ int offs;
  if (tid == 0) offs = 0;
  __syncthreads();
  for (int base = 0; base < TTOK; base += 256) {
    int t = base + tid;
    int a = tIdx[t * 2], b2 = tIdx[t * 2 + 1];
    bool sel = (a == e) || (b2 == e);
    unsigned long long mask = __ballot(sel);
    int wrank = __popcll(mask & ((1ull << lane) - 1ull));
    if (lane == 0) waveTot[wv] = __popcll(mask);
    __syncthreads();
    int pre = offs;
    for (int w2 = 0; w2 < wv; ++w2) pre += waveTot[w2];
    int rank = pre + wrank;
    if (sel && rank < CAPT) {
      int slot = e * CAPT + rank;
      tokList[slot] = t;
      gateW[slot] = (a == e) ? tW[t * 2] : tW[t * 2 + 1];
      slotOf[t * 2 + ((a == e) ? 0 : 1)] = slot;
    }
    __syncthreads();
    if (tid == 0) offs += waveTot[0] + waveTot[1] + waveTot[2] + waveTot[3];
    __syncthreads();
  }
  if (tid == 0) {
    cntFull[e] = offs;
    neCnt[e] = offs < CAPT ? offs : CAPT;
  }
}

// ------------------------- combine: out = hbuf + shared eo + <=2 gated eo rows
// Block 0 additionally computes aux loss / util (fused former aux_kernel).
__global__ __launch_bounds__(256) void combine_kernel(
    float* __restrict__ outp, const float* __restrict__ hbuf,
    const bf16* __restrict__ eo, const int* __restrict__ slotOf,
    const float* __restrict__ probs, const int* __restrict__ cntFull,
    float* __restrict__ outAux) {
  int t = blockIdx.x, tid = threadIdx.x;
  float4 v = ((const float4*)(hbuf + (size_t)t * DM))[tid];
  bf4 sh = ((const bf4*)(eo + (size_t)(NSLOT + t) * DM))[tid];
  v.x += (float)sh.x; v.y += (float)sh.y; v.z += (float)sh.z; v.w += (float)sh.w;
  int s0 = slotOf[t * 2], s1 = slotOf[t * 2 + 1];
  if (s0 >= 0) {
    bf4 e = ((const bf4*)(eo + (size_t)s0 * DM))[tid];
    v.x += (float)e.x; v.y += (float)e.y; v.z += (float)e.z; v.w += (float)e.w;
  }
  if (s1 >= 0) {
    bf4 e = ((const bf4*)(eo + (size_t)s1 * DM))[tid];
    v.x += (float)e.x; v.y += (float)e.y; v.z += (float)e.z; v.w += (float)e.w;
  }
  ((float4*)(outp + (size_t)t * DM))[tid] = v;

  if (t == 0) {
    __shared__ float psum[8];
    if (tid < 8) psum[tid] = 0.f;
    __syncthreads();
    float lp[8] = {0, 0, 0, 0, 0, 0, 0, 0};
    for (int tt = tid; tt < TTOK; tt += 256) {
#pragma unroll
      for (int e = 0; e < 8; ++e) lp[e] += probs[tt * 8 + e];
    }
#pragma unroll
    for (int e = 0; e < 8; ++e)
#pragma unroll
      for (int off = 1; off < 64; off <<= 1) lp[e] += __shfl_xor(lp[e], off);
    if ((tid & 63) == 0)
#pragma unroll
      for (int e = 0; e < 8; ++e) atomicAdd(&psum[e], lp[e]);
    __syncthreads();
    if (tid == 0) {
      float aux = 0.f; int used = 0;
      for (int e = 0; e < 8; ++e) {
        aux += (psum[e] / (float)TTOK) * ((float)cntFull[e] / (float)TTOK);
        if (cntFull[e] > 0) used++;
      }
      outAux[0] = 8.f * aux;
      outAux[1] = 100.f * (float)used / 8.f;
    }
  }
}

// ---------------------------------------------------------------- launch
extern "C" void kernel_launch(void* const* d_in, const int* in_sizes, int n_in,
                              void* d_out, int out_size, void* d_ws, size_t ws_size,
                              hipStream_t stream) {
  (void)in_sizes; (void)n_in; (void)out_size; (void)ws_size;
  const float* x     = (const float*)d_in[0];
  const float* cosb  = (const float*)d_in[1];
  const float* sinb  = (const float*)d_in[2];
  const float* attnw = (const float*)d_in[4];
  const float* moew  = (const float*)d_in[5];
  const float* wq  = (const float*)d_in[6];
  const float* wk  = (const float*)d_in[7];
  const float* wv  = (const float*)d_in[8];
  const float* wo  = (const float*)d_in[9];
  const float* rw  = (const float*)d_in[10];
  const float* ew1 = (const float*)d_in[11];
  const float* ew2 = (const float*)d_in[12];
  const float* ew3 = (const float*)d_in[13];
  const float* sw1 = (const float*)d_in[14];
  const float* sw2 = (const float*)d_in[15];
  const float* sw3 = (const float*)d_in[16];

  float* outp = (float*)d_out;
  float* auxp = outp + 4194304;
  float* newk = outp + 4194306;
  float* newv = newk + 1048576;

  char* wsp = (char*)d_ws;
  size_t off = 0;
  auto alloc = [&](size_t bytes) -> void* {
    void* p = wsp + off; off += (bytes + 255) & ~(size_t)255; return p;
  };
  bf16* wqkvT = (bf16*)alloc((size_t)1536 * 1024 * 2);
  bf16* woT   = (bf16*)alloc((size_t)1024 * 1024 * 2);
  bf16* ew1T  = (bf16*)alloc((size_t)9 * HIDDEN * 1024 * 2);   // slice 8 = sw1
  bf16* ew3T  = (bf16*)alloc((size_t)9 * HIDDEN * 1024 * 2);   // slice 8 = sw3
  bf16* ew2T  = (bf16*)alloc((size_t)9 * 1024 * HIDP * 2);     // slice 8 = sw2
  bf16* xn    = (bf16*)alloc((size_t)TTOK * DM * 2);
  bf16* qb    = (bf16*)alloc((size_t)TTOK * DM * 2);
  bf16* kb    = (bf16*)alloc((size_t)TTOK * 256 * 2);
  bf16* vb    = (bf16*)alloc((size_t)TTOK * 256 * 2);
  bf16* vt    = (bf16*)alloc((size_t)TTOK * 256 * 2);
  bf16* ao    = (bf16*)alloc((size_t)TTOK * DM * 2);
  float* hbuf = (float*)alloc((size_t)TTOK * DM * 4);
  bf16* hn    = (bf16*)alloc((size_t)TTOK * DM * 2);
  float* probs = (float*)alloc((size_t)TTOK * 8 * 4);
  int*   tIdx  = (int*)alloc((size_t)TTOK * 2 * 4);
  float* tW    = (float*)alloc((size_t)TTOK * 2 * 4);
  int*   tokList = (int*)alloc((size_t)TSLOT * 4);
  float* gateW   = (float*)alloc((size_t)TSLOT * 4);
  int*   neCnt   = (int*)alloc(64);
  int*   cntFull = (int*)alloc(64);
  int*   slotOf  = (int*)alloc((size_t)TTOK * 2 * 4);
  bf16*  mact = (bf16*)alloc((size_t)TSLOT * HIDP * 2);
  bf16*  eo   = (bf16*)alloc((size_t)TSLOT * DM * 2);

  EpiAux nil{};
  EpiAux ropeAux{cosb, sinb, qb, kb, vb, newk, newv};

  // ---- weight convert + transpose (merged: 3 launches)
  transpose_cvt_qkvo<<<dim3(40, 16), 256, 0, stream>>>(wq, wk, wv, wo, wqkvT, woT);
  transpose_cvt_quad<<<dim3(22, 16, 18), 256, 0, stream>>>(
      ew1, ew3, sw1, sw3,
      ew1T, ew3T, ew1T + (size_t)8 * HIDDEN * 1024, ew3T + (size_t)8 * HIDDEN * 1024,
      1024, HIDDEN, 1024, (long)1024 * HIDDEN, (long)HIDDEN * 1024);
  transpose_cvt_pair<<<dim3(16, 22, 9), 256, 0, stream>>>(
      ew2, sw2, ew2T, ew2T + (size_t)8 * 1024 * HIDP,
      HIDDEN, 1024, HIDP, (long)HIDDEN * 1024, (long)1024 * HIDP, 8);

  // ---- attention path (64-row M-tiles: xPerXcd = 4096/64/8 = 8)
  rmsnorm_kernel<<<TTOK, 256, 0, stream>>>(x, attnw, xn);
  gemm_bt<4><<<8 * 8 * 12, 256, 0, stream>>>(
      xn, wqkvT, TTOK, 1536, 1024, 1024, 1024, 8, nullptr, 0, nullptr, ropeAux);
  vt_kernel<<<dim3(32, 8), 256, 0, stream>>>(vb, vt);
  attn_kernel<<<dim3(16, NHEAD, 2), 256, 0, stream>>>(qb, kb, vt, ao);
  gemm_bt<2><<<8 * 8 * 8, 256, 0, stream>>>(
      ao, woT, TTOK, 1024, 1024, 1024, 1024, 8, hbuf, 1024, x, nil);

  // ---- MoE routing (router also inits slotOf = -1; no memset dispatch)
  rmsnorm_router_kernel<<<TTOK, 256, 0, stream>>>(hbuf, moew, rw, hn, probs, tIdx, tW, slotOf);
  assign_kernel<<<9, 256, 0, stream>>>(tIdx, tW, tokList, gateW, neCnt, cntFull, slotOf);

  // ---- experts (8 routed + shared as expert 8)
  gemm_dual9<<<8 * XBT * 11, 256, 0, stream>>>(hn, ew1T, ew3T, mact, tokList, neCnt);
  gemm_down9<<<8 * XBT * 16, 256, 0, stream>>>(mact, ew2T, eo, gateW, neCnt);
  combine_kernel<<<TTOK, 256, 0, stream>>>(outp, hbuf, eo, slotOf, probs, cntFull, auxp);
}

// Round 12
// 525.773 us; speedup vs baseline: 1.1294x; 1.0219x over previous
//
#include <hip/hip_runtime.h>
#include <hip/hip_bf16.h>
#include <math.h>

typedef __hip_bfloat16 bf16;
typedef __attribute__((ext_vector_type(8))) short short8;
typedef __attribute__((ext_vector_type(4))) float floatx4;

#define SEQ    2048
#define TTOK   4096
#define DM     1024
#define NHEAD  16
#define NKVH   4
#define HD     64
#define NEXP   8
#define HIDDEN 1365
#define HIDP   1408
#define CAPT   1280
#define NSLOT  (NEXP*CAPT)      /* 10240 routed slots */
#define TSLOT  (NSLOT+TTOK)     /* 14336: + shared-expert identity slots */
#define XPE    (CAPT/128)       /* 10 routed 128-row M-blocks per expert */
#define XBT    14               /* per-XCD 128-row M-blocks: 10 routed + 4 shared */

// ---------------------------------------------------------------- utilities
__device__ __forceinline__ void gld16(const void* g, void* l) {
  __builtin_amdgcn_global_load_lds((const __attribute__((address_space(1))) void*)g,
                                   (__attribute__((address_space(3))) void*)l,
                                   16, 0, 0);
}

struct __align__(8) bf4 { bf16 x, y, z, w; };

struct EpiAux {
  const float* cosb; const float* sinb;
  bf16* qb; bf16* kb; bf16* vt; float* newk; float* newv;
};

// ---------------------------------------------------- weight convert+transpose
// Shared body: (K,N) f32 row-major -> (N,Kp) bf16 row-major for one 64x64 tile.
__device__ __forceinline__ void tcvt_body(
    const float* __restrict__ src, bf16* __restrict__ dst,
    int K, int N, int Kp, int k0, int n0, float (*tile)[65]) {
  const int tid = threadIdx.x;
  const int lr = tid >> 4, lc = (tid & 15) * 4;
#pragma unroll
  for (int i = 0; i < 4; ++i) {
    int k = k0 + lr + i * 16;
    int n = n0 + lc;
    float4 v = {0.f, 0.f, 0.f, 0.f};
    if (k < K) {
      if (n + 3 < N) v = *(const float4*)(src + (size_t)k * N + n);
      else {
        float* vp = (float*)&v;
        for (int e = 0; e < 4; ++e) if (n + e < N) vp[e] = src[(size_t)k * N + n + e];
      }
    }
    tile[lr + i * 16][lc] = v.x; tile[lr + i * 16][lc + 1] = v.y;
    tile[lr + i * 16][lc + 2] = v.z; tile[lr + i * 16][lc + 3] = v.w;
  }
  __syncthreads();
  const int n = tid >> 2, kk0 = (tid & 3) * 16;
  if (n0 + n < N) {
    bf16 buf[16];
#pragma unroll
    for (int e = 0; e < 16; ++e) buf[e] = (bf16)tile[kk0 + e][n];
    bf16* dp = dst + (size_t)(n0 + n) * Kp + k0 + kk0;
    *(short8*)dp = *(short8*)buf;
    *(short8*)(dp + 8) = *(short8*)(buf + 8);
  }
}

// Dual-source variant: z<splitZ -> (src0,dst0) slice z; else (src1,dst1) slice z-splitZ.
__global__ __launch_bounds__(256) void transpose_cvt_pair(
    const float* __restrict__ src0, const float* __restrict__ src1,
    bf16* __restrict__ dst0, bf16* __restrict__ dst1,
    int K, int N, int Kp, long srcZ, long dstZ, int splitZ) {
  __shared__ float tile[64][65];
  const float* src; bf16* dst;
  int z = blockIdx.z;
  if (z < splitZ) { src = src0 + (size_t)z * srcZ; dst = dst0 + (size_t)z * dstZ; }
  else { int zz = z - splitZ; src = src1 + (size_t)zz * srcZ; dst = dst1 + (size_t)zz * dstZ; }
  tcvt_body(src, dst, K, N, Kp, blockIdx.y * 64, blockIdx.x * 64, tile);
}

// Quad-source variant: z<8 -> s0 slice z; z<16 -> s1 slice z-8; z==16 -> s2; z==17 -> s3.
__global__ __launch_bounds__(256) void transpose_cvt_quad(
    const float* __restrict__ s0, const float* __restrict__ s1,
    const float* __restrict__ s2, const float* __restrict__ s3,
    bf16* __restrict__ d0, bf16* __restrict__ d1,
    bf16* __restrict__ d2, bf16* __restrict__ d3,
    int K, int N, int Kp, long srcZ, long dstZ) {
  __shared__ float tile[64][65];
  const float* src; bf16* dst;
  int z = blockIdx.z;
  if (z < 8)        { src = s0 + (size_t)z * srcZ;       dst = d0 + (size_t)z * dstZ; }
  else if (z < 16)  { src = s1 + (size_t)(z - 8) * srcZ; dst = d1 + (size_t)(z - 8) * dstZ; }
  else if (z == 16) { src = s2; dst = d2; }
  else              { src = s3; dst = d3; }
  tcvt_body(src, dst, K, N, Kp, blockIdx.y * 64, blockIdx.x * 64, tile);
}

// All four dense weights (wq/wk/wv/wo) in one launch: grid (40,16).
__global__ __launch_bounds__(256) void transpose_cvt_qkvo(
    const float* __restrict__ wq, const float* __restrict__ wk,
    const float* __restrict__ wv, const float* __restrict__ wo,
    bf16* __restrict__ wqkvT, bf16* __restrict__ woT) {
  __shared__ float tile[64][65];
  const float* src; bf16* dst; int N, n0;
  int bx = blockIdx.x;
  if (bx < 16)      { src = wq; dst = wqkvT;                       N = 1024; n0 = bx * 64; }
  else if (bx < 20) { src = wk; dst = wqkvT + (size_t)1024 * 1024; N = 256;  n0 = (bx - 16) * 64; }
  else if (bx < 24) { src = wv; dst = wqkvT + (size_t)1280 * 1024; N = 256;  n0 = (bx - 20) * 64; }
  else              { src = wo; dst = woT;                         N = 1024; n0 = (bx - 24) * 64; }
  tcvt_body(src, dst, 1024, N, 1024, blockIdx.y * 64, n0, tile);
}

// ---------------------------------------------------------------- rmsnorm
__global__ __launch_bounds__(256) void rmsnorm_kernel(
    const float* __restrict__ x, const float* __restrict__ w, bf16* __restrict__ out) {
  int t = blockIdx.x;
  const float* xr = x + (size_t)t * DM;
  float4 xv = *(const float4*)(xr + threadIdx.x * 4);
  float ss = xv.x * xv.x + xv.y * xv.y + xv.z * xv.z + xv.w * xv.w;
#pragma unroll
  for (int off = 1; off < 64; off <<= 1) ss += __shfl_xor(ss, off);
  __shared__ float sred[4];
  if ((threadIdx.x & 63) == 0) sred[threadIdx.x >> 6] = ss;
  __syncthreads();
  float scale = rsqrtf((sred[0] + sred[1] + sred[2] + sred[3]) * (1.f / DM) + 1e-6f);
  float4 wv = *(const float4*)(w + threadIdx.x * 4);
  bf4 o;
  o.x = (bf16)(xv.x * scale * wv.x); o.y = (bf16)(xv.y * scale * wv.y);
  o.z = (bf16)(xv.z * scale * wv.z); o.w = (bf16)(xv.w * scale * wv.w);
  ((bf4*)(out + (size_t)t * DM))[threadIdx.x] = o;
}

// -------------------------------------------- rmsnorm + router (moe path)
// Also initializes slotOf[t*2..t*2+1] = -1 (replaces the hipMemsetAsync dispatch;
// runs before assign_kernel on the same stream).
__global__ __launch_bounds__(256) void rmsnorm_router_kernel(
    const float* __restrict__ x, const float* __restrict__ w, const float* __restrict__ rw,
    bf16* __restrict__ out, float* __restrict__ probs,
    int* __restrict__ tIdx, float* __restrict__ tW, int* __restrict__ slotOf) {
  int t = blockIdx.x;
  int tid = threadIdx.x, lane = tid & 63, wv = tid >> 6;
  const float* xr = x + (size_t)t * DM;
  float4 xv = *(const float4*)(xr + tid * 4);
  float ss = xv.x * xv.x + xv.y * xv.y + xv.z * xv.z + xv.w * xv.w;
#pragma unroll
  for (int off = 1; off < 64; off <<= 1) ss += __shfl_xor(ss, off);
  __shared__ float sred[4];
  __shared__ float red[4][8];
  if (lane == 0) sred[wv] = ss;
  __syncthreads();
  float scale = rsqrtf((sred[0] + sred[1] + sred[2] + sred[3]) * (1.f / DM) + 1e-6f);
  float4 wvv = *(const float4*)(w + tid * 4);
  float y[4] = {xv.x * scale * wvv.x, xv.y * scale * wvv.y,
                xv.z * scale * wvv.z, xv.w * scale * wvv.w};
  bf4 o; o.x = (bf16)y[0]; o.y = (bf16)y[1]; o.z = (bf16)y[2]; o.w = (bf16)y[3];
  ((bf4*)(out + (size_t)t * DM))[tid] = o;
  float acc[8] = {0, 0, 0, 0, 0, 0, 0, 0};
#pragma unroll
  for (int dd = 0; dd < 4; ++dd) {
    const float* rwr = rw + (size_t)(tid * 4 + dd) * 8;
#pragma unroll
    for (int e = 0; e < 8; ++e) acc[e] += y[dd] * rwr[e];
  }
#pragma unroll
  for (int e = 0; e < 8; ++e)
#pragma unroll
    for (int off = 1; off < 64; off <<= 1) acc[e] += __shfl_xor(acc[e], off);
  if (lane == 0)
#pragma unroll
    for (int e = 0; e < 8; ++e) red[wv][e] = acc[e];
  __syncthreads();
  if (tid == 0) {
    float lg[8];
#pragma unroll
    for (int e = 0; e < 8; ++e) lg[e] = red[0][e] + red[1][e] + red[2][e] + red[3][e];
    float mx = lg[0];
#pragma unroll
    for (int e = 1; e < 8; ++e) mx = fmaxf(mx, lg[e]);
    float p[8], se = 0.f;
#pragma unroll
    for (int e = 0; e < 8; ++e) { p[e] = __expf(lg[e] - mx); se += p[e]; }
#pragma unroll
    for (int e = 0; e < 8; ++e) { p[e] /= se; probs[t * 8 + e] = p[e]; }
    int i1 = 0;
#pragma unroll
    for (int e = 1; e < 8; ++e) if (p[e] > p[i1]) i1 = e;
    int i2 = (i1 == 0) ? 1 : 0;
#pragma unroll
    for (int e = 0; e < 8; ++e) if (e != i1 && p[e] > p[i2]) i2 = e;
    float s = p[i1] + p[i2];
    tIdx[t * 2] = i1; tIdx[t * 2 + 1] = i2;
    tW[t * 2] = p[i1] / s; tW[t * 2 + 1] = p[i2] / s;
    slotOf[t * 2] = -1; slotOf[t * 2 + 1] = -1;
  }
}

// ---------------------------------------------------------------- dense GEMM
// 64x128 tile (2 M-frags/wave). EPI: 2 = Cf = resid + acc ; 4 = QKV+rope.
// EPI=4 V branch writes DIRECTLY into the transposed vt layout
// (vt[(b*256+cv)*SEQ + s]) — vt_kernel is fused away.
template <int EPI>
__global__ __launch_bounds__(256) void gemm_bt(
    const bf16* __restrict__ A, const bf16* __restrict__ Bt,
    int M, int N, int K, int lda, int ldb, int xPerXcd,
    float* __restrict__ Cf, int ldc,
    const float* __restrict__ resid, EpiAux aux) {
  __shared__ __align__(16) bf16 As[64 * 64];
  __shared__ __align__(16) bf16 Bs[128 * 64];
  const int tid = threadIdx.x, lane = tid & 63, wave = tid >> 6;
  const int f = blockIdx.x, lo = f >> 3;
  int xb = (f & 7) * xPerXcd + lo % xPerXcd;
  int n0 = (lo / xPerXcd) * 128;
  int m0 = xb * 64;

  const bf16* aSrc[2]; const bf16* bSrc[4];
  bf16* aDst[2]; bf16* bDst[4];
#pragma unroll
  for (int it = 0; it < 2; ++it) {
    int c = it * 256 + tid;
    int r = c >> 3, q = c & 7;
    int kq = q ^ (r & 7);
    aSrc[it] = A + (long)(m0 + r) * lda + kq * 8;
    aDst[it] = As + (size_t)(it * 256 + wave * 64) * 8;
  }
#pragma unroll
  for (int it = 0; it < 4; ++it) {
    int c = it * 256 + tid;
    int r = c >> 3, q = c & 7;
    int kq = q ^ (r & 7);
    bSrc[it] = Bt + (long)(n0 + r) * ldb + kq * 8;
    bDst[it] = Bs + (size_t)(it * 256 + wave * 64) * 8;
  }

  floatx4 acc[2][4];
#pragma unroll
  for (int i = 0; i < 2; ++i)
#pragma unroll
    for (int j = 0; j < 4; ++j) { floatx4 z = {0.f, 0.f, 0.f, 0.f}; acc[i][j] = z; }

  const int wm = (wave & 1) * 32, wn = (wave >> 1) * 64;
  const int l15 = lane & 15, quad = lane >> 4;
  int aOff[2][2], bOff[4][2];
#pragma unroll
  for (int h = 0; h < 2; ++h) {
#pragma unroll
    for (int i = 0; i < 2; ++i) {
      int m = wm + i * 16 + l15;
      aOff[i][h] = (((m << 3) | ((h * 4 + quad) ^ (m & 7))) << 3);
    }
#pragma unroll
    for (int j = 0; j < 4; ++j) {
      int n = wn + j * 16 + l15;
      bOff[j][h] = (((n << 3) | ((h * 4 + quad) ^ (n & 7))) << 3);
    }
  }

  const int kIters = K >> 6;
  for (int kt = 0; kt < kIters; ++kt) {
    __syncthreads();
#pragma unroll
    for (int it = 0; it < 2; ++it) { gld16(aSrc[it], aDst[it]); aSrc[it] += 64; }
#pragma unroll
    for (int it = 0; it < 4; ++it) { gld16(bSrc[it], bDst[it]); bSrc[it] += 64; }
    __syncthreads();
#pragma unroll
    for (int h = 0; h < 2; ++h) {
      short8 af[2], bfr[4];
#pragma unroll
      for (int i = 0; i < 2; ++i) af[i] = *(const short8*)(As + aOff[i][h]);
#pragma unroll
      for (int j = 0; j < 4; ++j) bfr[j] = *(const short8*)(Bs + bOff[j][h]);
#pragma unroll
      for (int i = 0; i < 2; ++i)
#pragma unroll
        for (int j = 0; j < 4; ++j)
          acc[i][j] = __builtin_amdgcn_mfma_f32_16x16x32_bf16(af[i], bfr[j], acc[i][j], 0, 0, 0);
    }
  }

  if constexpr (EPI == 4) {
#pragma unroll
    for (int i = 0; i < 2; ++i) {
#pragma unroll
      for (int r = 0; r < 4; ++r) {
        int row = wm + i * 16 + quad * 4 + r;
        int t = m0 + row;
        int s = t & (SEQ - 1);
        if (n0 < 1024) {
#pragma unroll
          for (int j = 0; j < 2; ++j) {
            int col = n0 + wn + j * 16 + l15;
            int dlo = col & 63;
            float x1 = acc[i][j][r], x2 = acc[i][j + 2][r];
            float ch = aux.cosb[s * 64 + dlo], sh = aux.sinb[s * 64 + dlo];
            aux.qb[(size_t)t * DM + col]      = (bf16)((x1 * ch - x2 * sh) * 0.125f);
            aux.qb[(size_t)t * DM + col + 32] = (bf16)((x1 * sh + x2 * ch) * 0.125f);
          }
        } else if (n0 < 1280) {
#pragma unroll
          for (int j = 0; j < 2; ++j) {
            int ck = n0 + wn + j * 16 + l15 - 1024;
            int dlo = ck & 63;
            float x1 = acc[i][j][r], x2 = acc[i][j + 2][r];
            float ch = aux.cosb[s * 64 + dlo], sh = aux.sinb[s * 64 + dlo];
            float o1 = x1 * ch - x2 * sh, o2 = x1 * sh + x2 * ch;
            aux.kb[(size_t)t * 256 + ck]        = (bf16)o1;
            aux.kb[(size_t)t * 256 + ck + 32]   = (bf16)o2;
            aux.newk[(size_t)t * 256 + ck]      = o1;
            aux.newk[(size_t)t * 256 + ck + 32] = o2;
          }
        } else {
          const int b = t >> 11;  // SEQ = 2048
#pragma unroll
          for (int j = 0; j < 4; ++j) {
            int cv = n0 + wn + j * 16 + l15 - 1280;
            float v = acc[i][j][r];
            // fused V-transpose: vt[bg=b*4+cv/64][d=cv&63][s] — consecutive r
            // gives consecutive s, so each lane writes an 8B contiguous run.
            aux.vt[(size_t)(b * 256 + cv) * SEQ + s] = (bf16)v;
            aux.newv[(size_t)t * 256 + cv] = v;
          }
        }
      }
    }
    return;
  }
#pragma unroll
  for (int i = 0; i < 2; ++i) {
#pragma unroll
    for (int j = 0; j < 4; ++j) {
      int col = n0 + wn + j * 16 + l15;
#pragma unroll
      for (int r = 0; r < 4; ++r) {
        int row = wm + i * 16 + quad * 4 + r;
        size_t o = (size_t)(m0 + row) * ldc + col;
        Cf[o] = resid[o] + acc[i][j][r];
      }
    }
  }
}

// --------------------------------------------------- slot-block decode helper
__device__ __forceinline__ bool slot_block(
    int f, int NY, const int* neCnt, int& expert, int& m0, int& mLimit, int& n0) {
  int xcd = f & 7, lo = f >> 3;
  int xb = lo / NY, y = lo % NY;
  n0 = y * 64;
  if (xb < XPE) {
    expert = xcd;
    int ne = neCnt[xcd];
    if (xb * 128 >= ne) return false;
    m0 = xcd * CAPT + xb * 128;
    mLimit = ne - xb * 128;
    if (mLimit > 128) mLimit = 128;
  } else {
    expert = 8;
    int sb = xcd * 4 + (xb - XPE);
    m0 = NSLOT + sb * 128;
    mLimit = 128;
  }
  return true;
}

// ------------------------------------------------------ MoE dual GEMM + swiglu
// 128x128 tile, dual-B (B1,B3 share the staged A): 48 KB LDS, 256 thr / 4 waves,
// m97-style 2-barrier schedule. ~800 TF measured (r3) — near structural ceiling.
__global__ __launch_bounds__(256, 2) void gemm_dual9(
    const bf16* __restrict__ A, const bf16* __restrict__ B1t, const bf16* __restrict__ B3t,
    bf16* __restrict__ mact,
    const int* __restrict__ tokList, const int* __restrict__ neCnt) {
  __shared__ __align__(16) bf16 As[128 * 64];
  __shared__ __align__(16) bf16 B1s[128 * 64];
  __shared__ __align__(16) bf16 B3s[128 * 64];
  const int tid = threadIdx.x, lane = tid & 63, wave = tid >> 6;
  int expert, m0, mLimit, n0;
  if (!slot_block(blockIdx.x, 11, neCnt, expert, m0, mLimit, n0)) return;
  n0 <<= 1;  // 128-wide N-tiles
  const bf16* B1e = B1t + (long)expert * (HIDDEN * 1024);
  const bf16* B3e = B3t + (long)expert * (HIDDEN * 1024);

  const bf16* aSrc[4]; const bf16* b1Src[4]; const bf16* b3Src[4];
  bf16* aDst[4]; bf16* b1Dst[4]; bf16* b3Dst[4];
#pragma unroll
  for (int it = 0; it < 4; ++it) {
    int c = it * 256 + tid;
    int r = c >> 3, q = c & 7;
    int kq = q ^ (r & 7);
    int rr = r < mLimit ? r : (mLimit - 1);
    aSrc[it] = A + (long)tokList[m0 + rr] * 1024 + kq * 8;
    aDst[it] = As + (size_t)(it * 256 + wave * 64) * 8;
    int nn = n0 + r; if (nn > HIDDEN - 1) nn = HIDDEN - 1;
    b1Src[it] = B1e + (long)nn * 1024 + kq * 8;
    b3Src[it] = B3e + (long)nn * 1024 + kq * 8;
    b1Dst[it] = B1s + (size_t)(it * 256 + wave * 64) * 8;
    b3Dst[it] = B3s + (size_t)(it * 256 + wave * 64) * 8;
  }

  floatx4 acc1[4][4], acc3[4][4];
#pragma unroll
  for (int i = 0; i < 4; ++i)
#pragma unroll
    for (int j = 0; j < 4; ++j) {
      floatx4 z = {0.f, 0.f, 0.f, 0.f};
      acc1[i][j] = z; acc3[i][j] = z;
    }

  const int wm = (wave & 1) * 64, wn = (wave >> 1) * 64;
  const int l15 = lane & 15, quad = lane >> 4;
  int aOff[4][2], bOff[4][2];
#pragma unroll
  for (int h = 0; h < 2; ++h) {
#pragma unroll
    for (int i = 0; i < 4; ++i) {
      int m = wm + i * 16 + l15;
      aOff[i][h] = (((m << 3) | ((h * 4 + quad) ^ (m & 7))) << 3);
    }
#pragma unroll
    for (int j = 0; j < 4; ++j) {
      int n = wn + j * 16 + l15;
      bOff[j][h] = (((n << 3) | ((h * 4 + quad) ^ (n & 7))) << 3);
    }
  }

  for (int kt = 0; kt < 16; ++kt) {
    __syncthreads();
#pragma unroll
    for (int it = 0; it < 4; ++it) { gld16(aSrc[it], aDst[it]); aSrc[it] += 64; }
#pragma unroll
    for (int it = 0; it < 4; ++it) {
      gld16(b1Src[it], b1Dst[it]); b1Src[it] += 64;
      gld16(b3Src[it], b3Dst[it]); b3Src[it] += 64;
    }
    __syncthreads();
#pragma unroll
    for (int h = 0; h < 2; ++h) {
      short8 af[4];
#pragma unroll
      for (int i = 0; i < 4; ++i) af[i] = *(const short8*)(As + aOff[i][h]);
#pragma unroll
      for (int j = 0; j < 4; ++j) {
        short8 b1f = *(const short8*)(B1s + bOff[j][h]);
        short8 b3f = *(const short8*)(B3s + bOff[j][h]);
#pragma unroll
        for (int i = 0; i < 4; ++i) {
          acc1[i][j] = __builtin_amdgcn_mfma_f32_16x16x32_bf16(af[i], b1f, acc1[i][j], 0, 0, 0);
          acc3[i][j] = __builtin_amdgcn_mfma_f32_16x16x32_bf16(af[i], b3f, acc3[i][j], 0, 0, 0);
        }
      }
    }
  }

#pragma unroll
  for (int i = 0; i < 4; ++i) {
#pragma unroll
    for (int j = 0; j < 4; ++j) {
      int col = n0 + wn + j * 16 + l15;
#pragma unroll
      for (int r = 0; r < 4; ++r) {
        int row = wm + i * 16 + quad * 4 + r;
        if (row >= mLimit) continue;
        float a1 = acc1[i][j][r], a3 = acc3[i][j][r];
        float sl = a1 / (1.f + __expf(-a1));
        mact[(size_t)(m0 + row) * HIDP + col] = (col < HIDDEN) ? (bf16)(sl * a3) : (bf16)0.f;
      }
    }
  }
}

// ------------------------------------------------------ MoE down GEMM (gated)
// 128x64 tile (r0 version — best measured); A = mact slots (no gather);
// eo[slot] = gateW[slot] * (A@ew2^T)
__global__ __launch_bounds__(256) void gemm_down9(
    const bf16* __restrict__ A, const bf16* __restrict__ B2t,
    bf16* __restrict__ eo,
    const float* __restrict__ gateW, const int* __restrict__ neCnt) {
  __shared__ __align__(16) bf16 As[128 * 64];
  __shared__ __align__(16) bf16 Bs[64 * 64];
  const int tid = threadIdx.x, lane = tid & 63, wave = tid >> 6;
  int expert, m0, mLimit, n0;
  if (!slot_block(blockIdx.x, 16, neCnt, expert, m0, mLimit, n0)) return;
  const bf16* Be = B2t + (long)expert * (1024 * HIDP);

  const bf16* aSrc[4]; const bf16* bSrc[2];
  bf16* aDst[4]; bf16* bDst[2];
#pragma unroll
  for (int it = 0; it < 4; ++it) {
    int c = it * 256 + tid;
    int r = c >> 3, q = c & 7;
    int kq = q ^ (r & 7);
    int rr = r < mLimit ? r : (mLimit - 1);
    aSrc[it] = A + (long)(m0 + rr) * HIDP + kq * 8;
    aDst[it] = As + (size_t)(it * 256 + wave * 64) * 8;
  }
#pragma unroll
  for (int it = 0; it < 2; ++it) {
    int c = it * 256 + tid;
    int r = c >> 3, q = c & 7;
    int kq = q ^ (r & 7);
    bSrc[it] = Be + (long)(n0 + r) * HIDP + kq * 8;
    bDst[it] = Bs + (size_t)(it * 256 + wave * 64) * 8;
  }

  floatx4 acc[4][2];
#pragma unroll
  for (int i = 0; i < 4; ++i)
#pragma unroll
    for (int j = 0; j < 2; ++j) { floatx4 z = {0.f, 0.f, 0.f, 0.f}; acc[i][j] = z; }

  const int wm = (wave & 1) * 64, wn = (wave >> 1) * 32;
  const int l15 = lane & 15, quad = lane >> 4;
  int aOff[4][2], bOff[2][2];
#pragma unroll
  for (int h = 0; h < 2; ++h) {
#pragma unroll
    for (int i = 0; i < 4; ++i) {
      int m = wm + i * 16 + l15;
      aOff[i][h] = (((m << 3) | ((h * 4 + quad) ^ (m & 7))) << 3);
    }
#pragma unroll
    for (int j = 0; j < 2; ++j) {
      int n = wn + j * 16 + l15;
      bOff[j][h] = (((n << 3) | ((h * 4 + quad) ^ (n & 7))) << 3);
    }
  }

  for (int kt = 0; kt < 22; ++kt) {
    __syncthreads();
#pragma unroll
    for (int it = 0; it < 4; ++it) { gld16(aSrc[it], aDst[it]); aSrc[it] += 64; }
#pragma unroll
    for (int it = 0; it < 2; ++it) { gld16(bSrc[it], bDst[it]); bSrc[it] += 64; }
    __syncthreads();
#pragma unroll
    for (int h = 0; h < 2; ++h) {
      short8 af[4];
#pragma unroll
      for (int i = 0; i < 4; ++i) af[i] = *(const short8*)(As + aOff[i][h]);
#pragma unroll
      for (int j = 0; j < 2; ++j) {
        short8 bf = *(const short8*)(Bs + bOff[j][h]);
#pragma unroll
        for (int i = 0; i < 4; ++i)
          acc[i][j] = __builtin_amdgcn_mfma_f32_16x16x32_bf16(af[i], bf, acc[i][j], 0, 0, 0);
      }
    }
  }

#pragma unroll
  for (int i = 0; i < 4; ++i) {
#pragma unroll
    for (int j = 0; j < 2; ++j) {
      int col = n0 + wn + j * 16 + l15;
#pragma unroll
      for (int r = 0; r < 4; ++r) {
        int row = wm + i * 16 + quad * 4 + r;
        if (row >= mLimit) continue;
        eo[(size_t)(m0 + row) * 1024 + col] = (bf16)(gateW[m0 + row] * acc[i][j][r]);
      }
    }
  }
}

// ---------------------------------------------------------------- flash attention
// (r0 version — best measured; single-buffered K/V, paired q-tiles for perfect
// per-block load balance: pairI + (31-pairI) = 33 key-tiles per block)
__global__ __launch_bounds__(256) void attn_kernel(
    const bf16* __restrict__ Q, const bf16* __restrict__ Kc, const bf16* __restrict__ Vt,
    bf16* __restrict__ AO) {
  __shared__ __align__(16) bf16 Qs[64 * 64];
  __shared__ __align__(16) bf16 Ks[64 * 64];
  __shared__ __align__(16) bf16 Vs[64 * 64];
  __shared__ __align__(16) bf16 Ps[4][16 * 64];
  const int pairI = blockIdx.x, h = blockIdx.y, b = blockIdx.z;
  const int g = h >> 2;
  const int tid = threadIdx.x, lane = tid & 63, wave = tid >> 6;
  const int l15 = lane & 15, quad = lane >> 4;

  const bf16* kSrc[2]; const bf16* vSrc[2]; bf16* kDst[2]; bf16* vDst[2];
#pragma unroll
  for (int it = 0; it < 2; ++it) {
    int c = it * 256 + tid;
    int r = c >> 3, p = c & 7;
    int kq = p ^ (r & 7);
    kSrc[it] = Kc + (size_t)(b * SEQ + r) * 256 + g * 64 + kq * 8;
    vSrc[it] = Vt + ((size_t)(b * 4 + g) * 64 + r) * SEQ + kq * 8;
    kDst[it] = Ks + (size_t)(it * 256 + wave * 64) * 8;
    vDst[it] = Vs + (size_t)(it * 256 + wave * 64) * 8;
  }

  int qOff[2], kvOff[4][2], pOff[2];
#pragma unroll
  for (int hh = 0; hh < 2; ++hh) {
    int m = wave * 16 + l15;
    qOff[hh] = (m << 6) + (((hh * 4 + quad) ^ (m & 7)) << 3);
#pragma unroll
    for (int j = 0; j < 4; ++j) {
      int n = j * 16 + l15;
      kvOff[j][hh] = (n << 6) + (((hh * 4 + quad) ^ (n & 7)) << 3);
    }
    int cblk = (hh * 2 + (quad >> 1)) ^ (l15 >> 2);
    pOff[hh] = (l15 << 6) + (cblk << 4) + ((quad & 1) << 3);
  }
  bf16* pw = &Ps[wave][0];
  const int rowl = wave * 16 + quad * 4;

  short8 onesb;
#pragma unroll
  for (int e = 0; e < 8; ++e) onesb[e] = (short)0x3F80;

  for (int ph = 0; ph < 2; ++ph) {
    const int q0 = (ph == 0 ? pairI : 31 - pairI) * 64;
    __syncthreads();
#pragma unroll
    for (int it = 0; it < 2; ++it) {
      int c = it * 256 + tid;
      int r = c >> 3, p = c & 7;
      int kq = p ^ (r & 7);
      gld16(Q + (size_t)(b * SEQ + q0 + r) * DM + h * 64 + kq * 8,
            Qs + (size_t)(it * 256 + wave * 64) * 8);
    }

    floatx4 oacc[4], sumacc;
#pragma unroll
    for (int r = 0; r < 4; ++r) { floatx4 z = {0.f, 0.f, 0.f, 0.f}; oacc[r] = z; }
    { floatx4 z = {0.f, 0.f, 0.f, 0.f}; sumacc = z; }

    const int nkt = (q0 >> 6) + 1;
    for (int kt = 0; kt < nkt; ++kt) {
      __syncthreads();
#pragma unroll
      for (int it = 0; it < 2; ++it) {
        gld16(kSrc[it] + (size_t)kt * 64 * 256, kDst[it]);
        gld16(vSrc[it] + kt * 64, vDst[it]);
      }
      __syncthreads();

      floatx4 sacc[4];
#pragma unroll
      for (int j = 0; j < 4; ++j) { floatx4 z = {0.f, 0.f, 0.f, 0.f}; sacc[j] = z; }
#pragma unroll
      for (int hh = 0; hh < 2; ++hh) {
        short8 aq = *(const short8*)(Qs + qOff[hh]);
#pragma unroll
        for (int j = 0; j < 4; ++j)
          sacc[j] = __builtin_amdgcn_mfma_f32_16x16x32_bf16(
              aq, *(const short8*)(Ks + kvOff[j][hh]), sacc[j], 0, 0, 0);
      }

      const bool lastTile = (kt == nkt - 1);
#pragma unroll
      for (int j = 0; j < 4; ++j) {
        int sw = ((j ^ quad) << 4) + l15;
        int colg = j * 16 + l15;
#pragma unroll
        for (int r = 0; r < 4; ++r) {
          float p = __expf(sacc[j][r]);
          if (lastTile && colg > rowl + r) p = 0.f;
          pw[(quad * 4 + r) * 64 + sw] = (bf16)p;
        }
      }
      asm volatile("s_waitcnt lgkmcnt(0)" ::: "memory");
#pragma unroll
      for (int hh = 0; hh < 2; ++hh) {
        short8 ap = *(const short8*)(pw + pOff[hh]);
#pragma unroll
        for (int j = 0; j < 4; ++j)
          oacc[j] = __builtin_amdgcn_mfma_f32_16x16x32_bf16(
              ap, *(const short8*)(Vs + kvOff[j][hh]), oacc[j], 0, 0, 0);
        sumacc = __builtin_amdgcn_mfma_f32_16x16x32_bf16(ap, onesb, sumacc, 0, 0, 0);
      }
    }

    float inv[4];
#pragma unroll
    for (int r = 0; r < 4; ++r) inv[r] = 1.f / sumacc[r];
#pragma unroll
    for (int j = 0; j < 4; ++j)
#pragma unroll
      for (int r = 0; r < 4; ++r) {
        int t = b * SEQ + q0 + rowl + r;
        AO[(size_t)t * DM + h * 64 + j * 16 + l15] = (bf16)(oacc[j][r] * inv[r]);
      }
  }
}

// ------------------------------------------------- capacity assignment (9 blocks)
// blocks 0..7: per-expert compaction; block 8: identity fill for shared slots
__global__ __launch_bounds__(256) void assign_kernel(
    const int* __restrict__ tIdx, const float* __restrict__ tW,
    int* __restrict__ tokList, float* __restrict__ gateW,
    int* __restrict__ neCnt, int* __restrict__ cntFull, int* __restrict__ slotOf) {
  int e = blockIdx.x;
  int tid = threadIdx.x, lane = tid & 63, wv = tid >> 6;
  if (e == 8) {
    for (int t = tid; t < TTOK; t += 256) {
      tokList[NSLOT + t] = t;
      gateW[NSLOT + t] = 1.0f;
    }
    if (tid == 0) neCnt[8] = TTOK;
    return;
  }
  __shared__ int waveTot[4];
  __shared__ int offs;
  if (tid == 0) offs = 0;
  __syncthreads();
  for (int base = 0; base < TTOK; base += 256) {
    int t = base + tid;
    int a = tIdx[t * 2], b2 = tIdx[t * 2 + 1];
    bool sel = (a == e) || (b2 == e);
    unsigned long long mask = __ballot(sel);
    int wrank = __popcll(mask & ((1ull << lane) - 1ull));
    if (lane == 0) waveTot[wv] = __popcll(mask);
    __syncthreads();
    int pre = offs;
    for (int w2 = 0; w2 < wv; ++w2) pre += waveTot[w2];
    int rank = pre + wrank;
    if (sel && rank < CAPT) {
      int slot = e * CAPT + rank;
      tokList[slot] = t;
      gateW[slot] = (a == e) ? tW[t * 2] : tW[t * 2 + 1];
      slotOf[t * 2 + ((a == e) ? 0 : 1)] = slot;
    }
    __syncthreads();
    if (tid == 0) offs += waveTot[0] + waveTot[1] + waveTot[2] + waveTot[3];
    __syncthreads();
  }
  if (tid == 0) {
    cntFull[e] = offs;
    neCnt[e] = offs < CAPT ? offs : CAPT;
  }
}

// ------------------------- combine: out = hbuf + shared eo + <=2 gated eo rows
// Block 0 additionally computes aux loss / util (fused former aux_kernel).
__global__ __launch_bounds__(256) void combine_kernel(
    float* __restrict__ outp, const float* __restrict__ hbuf,
    const bf16* __restrict__ eo, const int* __restrict__ slotOf,
    const float* __restrict__ probs, const int* __restrict__ cntFull,
    float* __restrict__ outAux) {
  int t = blockIdx.x, tid = threadIdx.x;
  float4 v = ((const float4*)(hbuf + (size_t)t * DM))[tid];
  bf4 sh = ((const bf4*)(eo + (size_t)(NSLOT + t) * DM))[tid];
  v.x += (float)sh.x; v.y += (float)sh.y; v.z += (float)sh.z; v.w += (float)sh.w;
  int s0 = slotOf[t * 2], s1 = slotOf[t * 2 + 1];
  if (s0 >= 0) {
    bf4 e = ((const bf4*)(eo + (size_t)s0 * DM))[tid];
    v.x += (float)e.x; v.y += (float)e.y; v.z += (float)e.z; v.w += (float)e.w;
  }
  if (s1 >= 0) {
    bf4 e = ((const bf4*)(eo + (size_t)s1 * DM))[tid];
    v.x += (float)e.x; v.y += (float)e.y; v.z += (float)e.z; v.w += (float)e.w;
  }
  ((float4*)(outp + (size_t)t * DM))[tid] = v;

  if (t == 0) {
    __shared__ float psum[8];
    if (tid < 8) psum[tid] = 0.f;
    __syncthreads();
    float lp[8] = {0, 0, 0, 0, 0, 0, 0, 0};
    for (int tt = tid; tt < TTOK; tt += 256) {
#pragma unroll
      for (int e = 0; e < 8; ++e) lp[e] += probs[tt * 8 + e];
    }
#pragma unroll
    for (int e = 0; e < 8; ++e)
#pragma unroll
      for (int off = 1; off < 64; off <<= 1) lp[e] += __shfl_xor(lp[e], off);
    if ((tid & 63) == 0)
#pragma unroll
      for (int e = 0; e < 8; ++e) atomicAdd(&psum[e], lp[e]);
    __syncthreads();
    if (tid == 0) {
      float aux = 0.f; int used = 0;
      for (int e = 0; e < 8; ++e) {
        aux += (psum[e] / (float)TTOK) * ((float)cntFull[e] / (float)TTOK);
        if (cntFull[e] > 0) used++;
      }
      outAux[0] = 8.f * aux;
      outAux[1] = 100.f * (float)used / 8.f;
    }
  }
}

// ---------------------------------------------------------------- launch
extern "C" void kernel_launch(void* const* d_in, const int* in_sizes, int n_in,
                              void* d_out, int out_size, void* d_ws, size_t ws_size,
                              hipStream_t stream) {
  (void)in_sizes; (void)n_in; (void)out_size; (void)ws_size;
  const float* x     = (const float*)d_in[0];
  const float* cosb  = (const float*)d_in[1];
  const float* sinb  = (const float*)d_in[2];
  const float* attnw = (const float*)d_in[4];
  const float* moew  = (const float*)d_in[5];
  const float* wq  = (const float*)d_in[6];
  const float* wk  = (const float*)d_in[7];
  const float* wv  = (const float*)d_in[8];
  const float* wo  = (const float*)d_in[9];
  const float* rw  = (const float*)d_in[10];
  const float* ew1 = (const float*)d_in[11];
  const float* ew2 = (const float*)d_in[12];
  const float* ew3 = (const float*)d_in[13];
  const float* sw1 = (const float*)d_in[14];
  const float* sw2 = (const float*)d_in[15];
  const float* sw3 = (const float*)d_in[16];

  float* outp = (float*)d_out;
  float* auxp = outp + 4194304;
  float* newk = outp + 4194306;
  float* newv = newk + 1048576;

  char* wsp = (char*)d_ws;
  size_t off = 0;
  auto alloc = [&](size_t bytes) -> void* {
    void* p = wsp + off; off += (bytes + 255) & ~(size_t)255; return p;
  };
  bf16* wqkvT = (bf16*)alloc((size_t)1536 * 1024 * 2);
  bf16* woT   = (bf16*)alloc((size_t)1024 * 1024 * 2);
  bf16* ew1T  = (bf16*)alloc((size_t)9 * HIDDEN * 1024 * 2);   // slice 8 = sw1
  bf16* ew3T  = (bf16*)alloc((size_t)9 * HIDDEN * 1024 * 2);   // slice 8 = sw3
  bf16* ew2T  = (bf16*)alloc((size_t)9 * 1024 * HIDP * 2);     // slice 8 = sw2
  bf16* xn    = (bf16*)alloc((size_t)TTOK * DM * 2);
  bf16* qb    = (bf16*)alloc((size_t)TTOK * DM * 2);
  bf16* kb    = (bf16*)alloc((size_t)TTOK * 256 * 2);
  bf16* vt    = (bf16*)alloc((size_t)TTOK * 256 * 2);
  bf16* ao    = (bf16*)alloc((size_t)TTOK * DM * 2);
  float* hbuf = (float*)alloc((size_t)TTOK * DM * 4);
  bf16* hn    = (bf16*)alloc((size_t)TTOK * DM * 2);
  float* probs = (float*)alloc((size_t)TTOK * 8 * 4);
  int*   tIdx  = (int*)alloc((size_t)TTOK * 2 * 4);
  float* tW    = (float*)alloc((size_t)TTOK * 2 * 4);
  int*   tokList = (int*)alloc((size_t)TSLOT * 4);
  float* gateW   = (float*)alloc((size_t)TSLOT * 4);
  int*   neCnt   = (int*)alloc(64);
  int*   cntFull = (int*)alloc(64);
  int*   slotOf  = (int*)alloc((size_t)TTOK * 2 * 4);
  bf16*  mact = (bf16*)alloc((size_t)TSLOT * HIDP * 2);
  bf16*  eo   = (bf16*)alloc((size_t)TSLOT * DM * 2);

  EpiAux nil{};
  EpiAux ropeAux{cosb, sinb, qb, kb, vt, newk, newv};

  // ---- weight convert + transpose (merged: 3 launches)
  transpose_cvt_qkvo<<<dim3(40, 16), 256, 0, stream>>>(wq, wk, wv, wo, wqkvT, woT);
  transpose_cvt_quad<<<dim3(22, 16, 18), 256, 0, stream>>>(
      ew1, ew3, sw1, sw3,
      ew1T, ew3T, ew1T + (size_t)8 * HIDDEN * 1024, ew3T + (size_t)8 * HIDDEN * 1024,
      1024, HIDDEN, 1024, (long)1024 * HIDDEN, (long)HIDDEN * 1024);
  transpose_cvt_pair<<<dim3(16, 22, 9), 256, 0, stream>>>(
      ew2, sw2, ew2T, ew2T + (size_t)8 * 1024 * HIDP,
      HIDDEN, 1024, HIDP, (long)HIDDEN * 1024, (long)1024 * HIDP, 8);

  // ---- attention path (64-row M-tiles; V written pre-transposed by epilogue)
  rmsnorm_kernel<<<TTOK, 256, 0, stream>>>(x, attnw, xn);
  gemm_bt<4><<<8 * 8 * 12, 256, 0, stream>>>(
      xn, wqkvT, TTOK, 1536, 1024, 1024, 1024, 8, nullptr, 0, nullptr, ropeAux);
  attn_kernel<<<dim3(16, NHEAD, 2), 256, 0, stream>>>(qb, kb, vt, ao);
  gemm_bt<2><<<8 * 8 * 8, 256, 0, stream>>>(
      ao, woT, TTOK, 1024, 1024, 1024, 1024, 8, hbuf, 1024, x, nil);

  // ---- MoE routing (router also inits slotOf = -1; no memset dispatch)
  rmsnorm_router_kernel<<<TTOK, 256, 0, stream>>>(hbuf, moew, rw, hn, probs, tIdx, tW, slotOf);
  assign_kernel<<<9, 256, 0, stream>>>(tIdx, tW, tokList, gateW, neCnt, cntFull, slotOf);

  // ---- experts (8 routed + shared as expert 8)
  gemm_dual9<<<8 * XBT * 11, 256, 0, stream>>>(hn, ew1T, ew3T, mact, tokList, neCnt);
  gemm_down9<<<8 * XBT * 16, 256, 0, stream>>>(mact, ew2T, eo, gateW, neCnt);
  combine_kernel<<<TTOK, 256, 0, stream>>>(outp, hbuf, eo, slotOf, probs, cntFull, auxp);
}

// Round 13
// 521.264 us; speedup vs baseline: 1.1392x; 1.0087x over previous
//
#include <hip/hip_runtime.h>
#include <hip/hip_bf16.h>
#include <math.h>

typedef __hip_bfloat16 bf16;
typedef __attribute__((ext_vector_type(8))) short short8;
typedef __attribute__((ext_vector_type(4))) float floatx4;

#define SEQ    2048
#define TTOK   4096
#define DM     1024
#define NHEAD  16
#define NKVH   4
#define HD     64
#define NEXP   8
#define HIDDEN 1365
#define HIDP   1408
#define CAPT   1280
#define NSLOT  (NEXP*CAPT)      /* 10240 routed slots */
#define TSLOT  (NSLOT+TTOK)     /* 14336: + shared-expert identity slots */
#define XPE    (CAPT/128)       /* 10 routed 128-row M-blocks per expert */
#define XBT    14               /* per-XCD 128-row M-blocks: 10 routed + 4 shared */

// ---------------------------------------------------------------- utilities
__device__ __forceinline__ void gld16(const void* g, void* l) {
  __builtin_amdgcn_global_load_lds((const __attribute__((address_space(1))) void*)g,
                                   (__attribute__((address_space(3))) void*)l,
                                   16, 0, 0);
}

struct __align__(8) bf4 { bf16 x, y, z, w; };

struct EpiAux {
  const float* cosb; const float* sinb;
  bf16* qb; bf16* kb; bf16* vt; float* newk; float* newv;
};

// ---------------------------------------------------- weight convert+transpose
// Shared body: (K,N) f32 row-major -> (N,Kp) bf16 row-major for one 64x64 tile.
__device__ __forceinline__ void tcvt_body(
    const float* __restrict__ src, bf16* __restrict__ dst,
    int K, int N, int Kp, int k0, int n0, float (*tile)[65]) {
  const int tid = threadIdx.x;
  const int lr = tid >> 4, lc = (tid & 15) * 4;
#pragma unroll
  for (int i = 0; i < 4; ++i) {
    int k = k0 + lr + i * 16;
    int n = n0 + lc;
    float4 v = {0.f, 0.f, 0.f, 0.f};
    if (k < K) {
      if (n + 3 < N) v = *(const float4*)(src + (size_t)k * N + n);
      else {
        float* vp = (float*)&v;
        for (int e = 0; e < 4; ++e) if (n + e < N) vp[e] = src[(size_t)k * N + n + e];
      }
    }
    tile[lr + i * 16][lc] = v.x; tile[lr + i * 16][lc + 1] = v.y;
    tile[lr + i * 16][lc + 2] = v.z; tile[lr + i * 16][lc + 3] = v.w;
  }
  __syncthreads();
  const int n = tid >> 2, kk0 = (tid & 3) * 16;
  if (n0 + n < N) {
    bf16 buf[16];
#pragma unroll
    for (int e = 0; e < 16; ++e) buf[e] = (bf16)tile[kk0 + e][n];
    bf16* dp = dst + (size_t)(n0 + n) * Kp + k0 + kk0;
    *(short8*)dp = *(short8*)buf;
    *(short8*)(dp + 8) = *(short8*)(buf + 8);
  }
}

// ------------------------------------------------ fused preamble (one launch)
// blocks [0,4096):            rmsnorm of x -> xn
// blocks [4096,4736):         wq/wk/wv/wo transpose (qkvo, 640 blocks)
// blocks [4736,11072):        ew1/ew3/sw1/sw3 transpose (quad, 22*16*18)
// blocks [11072,14240):       ew2/sw2 transpose (pair, 16*22*9)
// All sections are mutually independent; merging removes 3 stream-head gaps
// (r10 measured ~4-5 us each) and overlaps memory-bound rmsnorm with transposes.
__global__ __launch_bounds__(256) void prep_kernel(
    const float* __restrict__ x, const float* __restrict__ attnw, bf16* __restrict__ xn,
    const float* __restrict__ wq, const float* __restrict__ wk,
    const float* __restrict__ wv, const float* __restrict__ wo,
    bf16* __restrict__ wqkvT, bf16* __restrict__ woT,
    const float* __restrict__ ew1, const float* __restrict__ ew3,
    const float* __restrict__ sw1, const float* __restrict__ sw3,
    bf16* __restrict__ ew1T, bf16* __restrict__ ew3T,
    const float* __restrict__ ew2, const float* __restrict__ sw2,
    bf16* __restrict__ ew2T) {
  __shared__ float tile[64][65];
  const int bid = blockIdx.x;
  const int tid = threadIdx.x;

  if (bid < TTOK) {
    // ---- rmsnorm (uses first 4 floats of tile as reduction scratch)
    int t = bid;
    const float* xr = x + (size_t)t * DM;
    float4 xv = *(const float4*)(xr + tid * 4);
    float ss = xv.x * xv.x + xv.y * xv.y + xv.z * xv.z + xv.w * xv.w;
#pragma unroll
    for (int off = 1; off < 64; off <<= 1) ss += __shfl_xor(ss, off);
    if ((tid & 63) == 0) tile[0][tid >> 6] = ss;
    __syncthreads();
    float scale = rsqrtf((tile[0][0] + tile[0][1] + tile[0][2] + tile[0][3]) * (1.f / DM) + 1e-6f);
    float4 wv4 = *(const float4*)(attnw + tid * 4);
    bf4 o;
    o.x = (bf16)(xv.x * scale * wv4.x); o.y = (bf16)(xv.y * scale * wv4.y);
    o.z = (bf16)(xv.z * scale * wv4.z); o.w = (bf16)(xv.w * scale * wv4.w);
    ((bf4*)(xn + (size_t)t * DM))[tid] = o;
    return;
  }
  if (bid < TTOK + 640) {
    // ---- qkvo transpose: f = bx + by*40, bx in [0,40), by in [0,16)
    int f = bid - TTOK;
    int bx = f % 40, by = f / 40;
    const float* src; bf16* dst; int N, n0;
    if (bx < 16)      { src = wq; dst = wqkvT;                       N = 1024; n0 = bx * 64; }
    else if (bx < 20) { src = wk; dst = wqkvT + (size_t)1024 * 1024; N = 256;  n0 = (bx - 16) * 64; }
    else if (bx < 24) { src = wv; dst = wqkvT + (size_t)1280 * 1024; N = 256;  n0 = (bx - 20) * 64; }
    else              { src = wo; dst = woT;                         N = 1024; n0 = (bx - 24) * 64; }
    tcvt_body(src, dst, 1024, N, 1024, by * 64, n0, tile);
    return;
  }
  if (bid < TTOK + 640 + 22 * 16 * 18) {
    // ---- quad transpose (ew1/ew3/sw1/sw3): K=1024, N=HIDDEN, Kp=1024
    int f = bid - (TTOK + 640);
    int bx = f % 22, rem = f / 22;
    int by = rem % 16, z = rem / 16;
    const float* src; bf16* dst;
    const long srcZ = (long)1024 * HIDDEN, dstZ = (long)HIDDEN * 1024;
    if (z < 8)        { src = ew1 + (size_t)z * srcZ;       dst = ew1T + (size_t)z * dstZ; }
    else if (z < 16)  { src = ew3 + (size_t)(z - 8) * srcZ; dst = ew3T + (size_t)(z - 8) * dstZ; }
    else if (z == 16) { src = sw1; dst = ew1T + (size_t)8 * dstZ; }
    else              { src = sw3; dst = ew3T + (size_t)8 * dstZ; }
    tcvt_body(src, dst, 1024, HIDDEN, 1024, by * 64, bx * 64, tile);
    return;
  }
  {
    // ---- pair transpose (ew2/sw2): K=HIDDEN, N=1024, Kp=HIDP
    int f = bid - (TTOK + 640 + 22 * 16 * 18);
    int bx = f % 16, rem = f / 16;
    int by = rem % 22, z = rem / 22;
    const float* src; bf16* dst;
    const long srcZ = (long)HIDDEN * 1024, dstZ = (long)1024 * HIDP;
    if (z < 8) { src = ew2 + (size_t)z * srcZ; dst = ew2T + (size_t)z * dstZ; }
    else       { src = sw2;                    dst = ew2T + (size_t)8 * dstZ; }
    tcvt_body(src, dst, HIDDEN, 1024, HIDP, by * 64, bx * 64, tile);
  }
}

// -------------------------------------------- rmsnorm + router (moe path)
// Also initializes slotOf[t*2..t*2+1] = -1 (replaces the hipMemsetAsync dispatch;
// runs before assign_kernel on the same stream).
__global__ __launch_bounds__(256) void rmsnorm_router_kernel(
    const float* __restrict__ x, const float* __restrict__ w, const float* __restrict__ rw,
    bf16* __restrict__ out, float* __restrict__ probs,
    int* __restrict__ tIdx, float* __restrict__ tW, int* __restrict__ slotOf) {
  int t = blockIdx.x;
  int tid = threadIdx.x, lane = tid & 63, wv = tid >> 6;
  const float* xr = x + (size_t)t * DM;
  float4 xv = *(const float4*)(xr + tid * 4);
  float ss = xv.x * xv.x + xv.y * xv.y + xv.z * xv.z + xv.w * xv.w;
#pragma unroll
  for (int off = 1; off < 64; off <<= 1) ss += __shfl_xor(ss, off);
  __shared__ float sred[4];
  __shared__ float red[4][8];
  if (lane == 0) sred[wv] = ss;
  __syncthreads();
  float scale = rsqrtf((sred[0] + sred[1] + sred[2] + sred[3]) * (1.f / DM) + 1e-6f);
  float4 wvv = *(const float4*)(w + tid * 4);
  float y[4] = {xv.x * scale * wvv.x, xv.y * scale * wvv.y,
                xv.z * scale * wvv.z, xv.w * scale * wvv.w};
  bf4 o; o.x = (bf16)y[0]; o.y = (bf16)y[1]; o.z = (bf16)y[2]; o.w = (bf16)y[3];
  ((bf4*)(out + (size_t)t * DM))[tid] = o;
  float acc[8] = {0, 0, 0, 0, 0, 0, 0, 0};
#pragma unroll
  for (int dd = 0; dd < 4; ++dd) {
    const float* rwr = rw + (size_t)(tid * 4 + dd) * 8;
#pragma unroll
    for (int e = 0; e < 8; ++e) acc[e] += y[dd] * rwr[e];
  }
#pragma unroll
  for (int e = 0; e < 8; ++e)
#pragma unroll
    for (int off = 1; off < 64; off <<= 1) acc[e] += __shfl_xor(acc[e], off);
  if (lane == 0)
#pragma unroll
    for (int e = 0; e < 8; ++e) red[wv][e] = acc[e];
  __syncthreads();
  if (tid == 0) {
    float lg[8];
#pragma unroll
    for (int e = 0; e < 8; ++e) lg[e] = red[0][e] + red[1][e] + red[2][e] + red[3][e];
    float mx = lg[0];
#pragma unroll
    for (int e = 1; e < 8; ++e) mx = fmaxf(mx, lg[e]);
    float p[8], se = 0.f;
#pragma unroll
    for (int e = 0; e < 8; ++e) { p[e] = __expf(lg[e] - mx); se += p[e]; }
#pragma unroll
    for (int e = 0; e < 8; ++e) { p[e] /= se; probs[t * 8 + e] = p[e]; }
    int i1 = 0;
#pragma unroll
    for (int e = 1; e < 8; ++e) if (p[e] > p[i1]) i1 = e;
    int i2 = (i1 == 0) ? 1 : 0;
#pragma unroll
    for (int e = 0; e < 8; ++e) if (e != i1 && p[e] > p[i2]) i2 = e;
    float s = p[i1] + p[i2];
    tIdx[t * 2] = i1; tIdx[t * 2 + 1] = i2;
    tW[t * 2] = p[i1] / s; tW[t * 2 + 1] = p[i2] / s;
    slotOf[t * 2] = -1; slotOf[t * 2 + 1] = -1;
  }
}

// ---------------------------------------------------------------- dense GEMM
// 64x128 tile (2 M-frags/wave). EPI: 2 = Cf = resid + acc ; 4 = QKV+rope.
// EPI=4 V branch writes DIRECTLY into the transposed vt layout
// (vt[(b*256+cv)*SEQ + s]) — vt_kernel is fused away.
template <int EPI>
__global__ __launch_bounds__(256) void gemm_bt(
    const bf16* __restrict__ A, const bf16* __restrict__ Bt,
    int M, int N, int K, int lda, int ldb, int xPerXcd,
    float* __restrict__ Cf, int ldc,
    const float* __restrict__ resid, EpiAux aux) {
  __shared__ __align__(16) bf16 As[64 * 64];
  __shared__ __align__(16) bf16 Bs[128 * 64];
  const int tid = threadIdx.x, lane = tid & 63, wave = tid >> 6;
  const int f = blockIdx.x, lo = f >> 3;
  int xb = (f & 7) * xPerXcd + lo % xPerXcd;
  int n0 = (lo / xPerXcd) * 128;
  int m0 = xb * 64;

  const bf16* aSrc[2]; const bf16* bSrc[4];
  bf16* aDst[2]; bf16* bDst[4];
#pragma unroll
  for (int it = 0; it < 2; ++it) {
    int c = it * 256 + tid;
    int r = c >> 3, q = c & 7;
    int kq = q ^ (r & 7);
    aSrc[it] = A + (long)(m0 + r) * lda + kq * 8;
    aDst[it] = As + (size_t)(it * 256 + wave * 64) * 8;
  }
#pragma unroll
  for (int it = 0; it < 4; ++it) {
    int c = it * 256 + tid;
    int r = c >> 3, q = c & 7;
    int kq = q ^ (r & 7);
    bSrc[it] = Bt + (long)(n0 + r) * ldb + kq * 8;
    bDst[it] = Bs + (size_t)(it * 256 + wave * 64) * 8;
  }

  floatx4 acc[2][4];
#pragma unroll
  for (int i = 0; i < 2; ++i)
#pragma unroll
    for (int j = 0; j < 4; ++j) { floatx4 z = {0.f, 0.f, 0.f, 0.f}; acc[i][j] = z; }

  const int wm = (wave & 1) * 32, wn = (wave >> 1) * 64;
  const int l15 = lane & 15, quad = lane >> 4;
  int aOff[2][2], bOff[4][2];
#pragma unroll
  for (int h = 0; h < 2; ++h) {
#pragma unroll
    for (int i = 0; i < 2; ++i) {
      int m = wm + i * 16 + l15;
      aOff[i][h] = (((m << 3) | ((h * 4 + quad) ^ (m & 7))) << 3);
    }
#pragma unroll
    for (int j = 0; j < 4; ++j) {
      int n = wn + j * 16 + l15;
      bOff[j][h] = (((n << 3) | ((h * 4 + quad) ^ (n & 7))) << 3);
    }
  }

  const int kIters = K >> 6;
  for (int kt = 0; kt < kIters; ++kt) {
    __syncthreads();
#pragma unroll
    for (int it = 0; it < 2; ++it) { gld16(aSrc[it], aDst[it]); aSrc[it] += 64; }
#pragma unroll
    for (int it = 0; it < 4; ++it) { gld16(bSrc[it], bDst[it]); bSrc[it] += 64; }
    __syncthreads();
#pragma unroll
    for (int h = 0; h < 2; ++h) {
      short8 af[2], bfr[4];
#pragma unroll
      for (int i = 0; i < 2; ++i) af[i] = *(const short8*)(As + aOff[i][h]);
#pragma unroll
      for (int j = 0; j < 4; ++j) bfr[j] = *(const short8*)(Bs + bOff[j][h]);
#pragma unroll
      for (int i = 0; i < 2; ++i)
#pragma unroll
        for (int j = 0; j < 4; ++j)
          acc[i][j] = __builtin_amdgcn_mfma_f32_16x16x32_bf16(af[i], bfr[j], acc[i][j], 0, 0, 0);
    }
  }

  if constexpr (EPI == 4) {
#pragma unroll
    for (int i = 0; i < 2; ++i) {
#pragma unroll
      for (int r = 0; r < 4; ++r) {
        int row = wm + i * 16 + quad * 4 + r;
        int t = m0 + row;
        int s = t & (SEQ - 1);
        if (n0 < 1024) {
#pragma unroll
          for (int j = 0; j < 2; ++j) {
            int col = n0 + wn + j * 16 + l15;
            int dlo = col & 63;
            float x1 = acc[i][j][r], x2 = acc[i][j + 2][r];
            float ch = aux.cosb[s * 64 + dlo], sh = aux.sinb[s * 64 + dlo];
            aux.qb[(size_t)t * DM + col]      = (bf16)((x1 * ch - x2 * sh) * 0.125f);
            aux.qb[(size_t)t * DM + col + 32] = (bf16)((x1 * sh + x2 * ch) * 0.125f);
          }
        } else if (n0 < 1280) {
#pragma unroll
          for (int j = 0; j < 2; ++j) {
            int ck = n0 + wn + j * 16 + l15 - 1024;
            int dlo = ck & 63;
            float x1 = acc[i][j][r], x2 = acc[i][j + 2][r];
            float ch = aux.cosb[s * 64 + dlo], sh = aux.sinb[s * 64 + dlo];
            float o1 = x1 * ch - x2 * sh, o2 = x1 * sh + x2 * ch;
            aux.kb[(size_t)t * 256 + ck]        = (bf16)o1;
            aux.kb[(size_t)t * 256 + ck + 32]   = (bf16)o2;
            aux.newk[(size_t)t * 256 + ck]      = o1;
            aux.newk[(size_t)t * 256 + ck + 32] = o2;
          }
        } else {
          const int b = t >> 11;  // SEQ = 2048
#pragma unroll
          for (int j = 0; j < 4; ++j) {
            int cv = n0 + wn + j * 16 + l15 - 1280;
            float v = acc[i][j][r];
            // fused V-transpose: vt[bg=b*4+cv/64][d=cv&63][s] — consecutive r
            // gives consecutive s, so each lane writes an 8B contiguous run.
            aux.vt[(size_t)(b * 256 + cv) * SEQ + s] = (bf16)v;
            aux.newv[(size_t)t * 256 + cv] = v;
          }
        }
      }
    }
    return;
  }
#pragma unroll
  for (int i = 0; i < 2; ++i) {
#pragma unroll
    for (int j = 0; j < 4; ++j) {
      int col = n0 + wn + j * 16 + l15;
#pragma unroll
      for (int r = 0; r < 4; ++r) {
        int row = wm + i * 16 + quad * 4 + r;
        size_t o = (size_t)(m0 + row) * ldc + col;
        Cf[o] = resid[o] + acc[i][j][r];
      }
    }
  }
}

// --------------------------------------------------- slot-block decode helper
__device__ __forceinline__ bool slot_block(
    int f, int NY, const int* neCnt, int& expert, int& m0, int& mLimit, int& n0) {
  int xcd = f & 7, lo = f >> 3;
  int xb = lo / NY, y = lo % NY;
  n0 = y * 64;
  if (xb < XPE) {
    expert = xcd;
    int ne = neCnt[xcd];
    if (xb * 128 >= ne) return false;
    m0 = xcd * CAPT + xb * 128;
    mLimit = ne - xb * 128;
    if (mLimit > 128) mLimit = 128;
  } else {
    expert = 8;
    int sb = xcd * 4 + (xb - XPE);
    m0 = NSLOT + sb * 128;
    mLimit = 128;
  }
  return true;
}

// ------------------------------------------------------ MoE dual GEMM + swiglu
// 128x128 tile, dual-B (B1,B3 share the staged A): 48 KB LDS, 256 thr / 4 waves,
// m97-style 2-barrier schedule. ~800 TF measured (r3) — near structural ceiling.
__global__ __launch_bounds__(256, 2) void gemm_dual9(
    const bf16* __restrict__ A, const bf16* __restrict__ B1t, const bf16* __restrict__ B3t,
    bf16* __restrict__ mact,
    const int* __restrict__ tokList, const int* __restrict__ neCnt) {
  __shared__ __align__(16) bf16 As[128 * 64];
  __shared__ __align__(16) bf16 B1s[128 * 64];
  __shared__ __align__(16) bf16 B3s[128 * 64];
  const int tid = threadIdx.x, lane = tid & 63, wave = tid >> 6;
  int expert, m0, mLimit, n0;
  if (!slot_block(blockIdx.x, 11, neCnt, expert, m0, mLimit, n0)) return;
  n0 <<= 1;  // 128-wide N-tiles
  const bf16* B1e = B1t + (long)expert * (HIDDEN * 1024);
  const bf16* B3e = B3t + (long)expert * (HIDDEN * 1024);

  const bf16* aSrc[4]; const bf16* b1Src[4]; const bf16* b3Src[4];
  bf16* aDst[4]; bf16* b1Dst[4]; bf16* b3Dst[4];
#pragma unroll
  for (int it = 0; it < 4; ++it) {
    int c = it * 256 + tid;
    int r = c >> 3, q = c & 7;
    int kq = q ^ (r & 7);
    int rr = r < mLimit ? r : (mLimit - 1);
    aSrc[it] = A + (long)tokList[m0 + rr] * 1024 + kq * 8;
    aDst[it] = As + (size_t)(it * 256 + wave * 64) * 8;
    int nn = n0 + r; if (nn > HIDDEN - 1) nn = HIDDEN - 1;
    b1Src[it] = B1e + (long)nn * 1024 + kq * 8;
    b3Src[it] = B3e + (long)nn * 1024 + kq * 8;
    b1Dst[it] = B1s + (size_t)(it * 256 + wave * 64) * 8;
    b3Dst[it] = B3s + (size_t)(it * 256 + wave * 64) * 8;
  }

  floatx4 acc1[4][4], acc3[4][4];
#pragma unroll
  for (int i = 0; i < 4; ++i)
#pragma unroll
    for (int j = 0; j < 4; ++j) {
      floatx4 z = {0.f, 0.f, 0.f, 0.f};
      acc1[i][j] = z; acc3[i][j] = z;
    }

  const int wm = (wave & 1) * 64, wn = (wave >> 1) * 64;
  const int l15 = lane & 15, quad = lane >> 4;
  int aOff[4][2], bOff[4][2];
#pragma unroll
  for (int h = 0; h < 2; ++h) {
#pragma unroll
    for (int i = 0; i < 4; ++i) {
      int m = wm + i * 16 + l15;
      aOff[i][h] = (((m << 3) | ((h * 4 + quad) ^ (m & 7))) << 3);
    }
#pragma unroll
    for (int j = 0; j < 4; ++j) {
      int n = wn + j * 16 + l15;
      bOff[j][h] = (((n << 3) | ((h * 4 + quad) ^ (n & 7))) << 3);
    }
  }

  for (int kt = 0; kt < 16; ++kt) {
    __syncthreads();
#pragma unroll
    for (int it = 0; it < 4; ++it) { gld16(aSrc[it], aDst[it]); aSrc[it] += 64; }
#pragma unroll
    for (int it = 0; it < 4; ++it) {
      gld16(b1Src[it], b1Dst[it]); b1Src[it] += 64;
      gld16(b3Src[it], b3Dst[it]); b3Src[it] += 64;
    }
    __syncthreads();
#pragma unroll
    for (int h = 0; h < 2; ++h) {
      short8 af[4];
#pragma unroll
      for (int i = 0; i < 4; ++i) af[i] = *(const short8*)(As + aOff[i][h]);
#pragma unroll
      for (int j = 0; j < 4; ++j) {
        short8 b1f = *(const short8*)(B1s + bOff[j][h]);
        short8 b3f = *(const short8*)(B3s + bOff[j][h]);
#pragma unroll
        for (int i = 0; i < 4; ++i) {
          acc1[i][j] = __builtin_amdgcn_mfma_f32_16x16x32_bf16(af[i], b1f, acc1[i][j], 0, 0, 0);
          acc3[i][j] = __builtin_amdgcn_mfma_f32_16x16x32_bf16(af[i], b3f, acc3[i][j], 0, 0, 0);
        }
      }
    }
  }

#pragma unroll
  for (int i = 0; i < 4; ++i) {
#pragma unroll
    for (int j = 0; j < 4; ++j) {
      int col = n0 + wn + j * 16 + l15;
#pragma unroll
      for (int r = 0; r < 4; ++r) {
        int row = wm + i * 16 + quad * 4 + r;
        if (row >= mLimit) continue;
        float a1 = acc1[i][j][r], a3 = acc3[i][j][r];
        float sl = a1 / (1.f + __expf(-a1));
        mact[(size_t)(m0 + row) * HIDP + col] = (col < HIDDEN) ? (bf16)(sl * a3) : (bf16)0.f;
      }
    }
  }
}

// ------------------------------------------------------ MoE down GEMM (gated)
// 128x64 tile (r0 version — best measured); A = mact slots (no gather);
// eo[slot] = gateW[slot] * (A@ew2^T)
__global__ __launch_bounds__(256) void gemm_down9(
    const bf16* __restrict__ A, const bf16* __restrict__ B2t,
    bf16* __restrict__ eo,
    const float* __restrict__ gateW, const int* __restrict__ neCnt) {
  __shared__ __align__(16) bf16 As[128 * 64];
  __shared__ __align__(16) bf16 Bs[64 * 64];
  const int tid = threadIdx.x, lane = tid & 63, wave = tid >> 6;
  int expert, m0, mLimit, n0;
  if (!slot_block(blockIdx.x, 16, neCnt, expert, m0, mLimit, n0)) return;
  const bf16* Be = B2t + (long)expert * (1024 * HIDP);

  const bf16* aSrc[4]; const bf16* bSrc[2];
  bf16* aDst[4]; bf16* bDst[2];
#pragma unroll
  for (int it = 0; it < 4; ++it) {
    int c = it * 256 + tid;
    int r = c >> 3, q = c & 7;
    int kq = q ^ (r & 7);
    int rr = r < mLimit ? r : (mLimit - 1);
    aSrc[it] = A + (long)(m0 + rr) * HIDP + kq * 8;
    aDst[it] = As + (size_t)(it * 256 + wave * 64) * 8;
  }
#pragma unroll
  for (int it = 0; it < 2; ++it) {
    int c = it * 256 + tid;
    int r = c >> 3, q = c & 7;
    int kq = q ^ (r & 7);
    bSrc[it] = Be + (long)(n0 + r) * HIDP + kq * 8;
    bDst[it] = Bs + (size_t)(it * 256 + wave * 64) * 8;
  }

  floatx4 acc[4][2];
#pragma unroll
  for (int i = 0; i < 4; ++i)
#pragma unroll
    for (int j = 0; j < 2; ++j) { floatx4 z = {0.f, 0.f, 0.f, 0.f}; acc[i][j] = z; }

  const int wm = (wave & 1) * 64, wn = (wave >> 1) * 32;
  const int l15 = lane & 15, quad = lane >> 4;
  int aOff[4][2], bOff[2][2];
#pragma unroll
  for (int h = 0; h < 2; ++h) {
#pragma unroll
    for (int i = 0; i < 4; ++i) {
      int m = wm + i * 16 + l15;
      aOff[i][h] = (((m << 3) | ((h * 4 + quad) ^ (m & 7))) << 3);
    }
#pragma unroll
    for (int j = 0; j < 2; ++j) {
      int n = wn + j * 16 + l15;
      bOff[j][h] = (((n << 3) | ((h * 4 + quad) ^ (n & 7))) << 3);
    }
  }

  for (int kt = 0; kt < 22; ++kt) {
    __syncthreads();
#pragma unroll
    for (int it = 0; it < 4; ++it) { gld16(aSrc[it], aDst[it]); aSrc[it] += 64; }
#pragma unroll
    for (int it = 0; it < 2; ++it) { gld16(bSrc[it], bDst[it]); bSrc[it] += 64; }
    __syncthreads();
#pragma unroll
    for (int h = 0; h < 2; ++h) {
      short8 af[4];
#pragma unroll
      for (int i = 0; i < 4; ++i) af[i] = *(const short8*)(As + aOff[i][h]);
#pragma unroll
      for (int j = 0; j < 2; ++j) {
        short8 bf = *(const short8*)(Bs + bOff[j][h]);
#pragma unroll
        for (int i = 0; i < 4; ++i)
          acc[i][j] = __builtin_amdgcn_mfma_f32_16x16x32_bf16(af[i], bf, acc[i][j], 0, 0, 0);
      }
    }
  }

#pragma unroll
  for (int i = 0; i < 4; ++i) {
#pragma unroll
    for (int j = 0; j < 2; ++j) {
      int col = n0 + wn + j * 16 + l15;
#pragma unroll
      for (int r = 0; r < 4; ++r) {
        int row = wm + i * 16 + quad * 4 + r;
        if (row >= mLimit) continue;
        eo[(size_t)(m0 + row) * 1024 + col] = (bf16)(gateW[m0 + row] * acc[i][j][r]);
      }
    }
  }
}

// ---------------------------------------------------------------- flash attention
// (r0 version — best measured; single-buffered K/V, paired q-tiles for perfect
// per-block load balance: pairI + (31-pairI) = 33 key-tiles per block)
__global__ __launch_bounds__(256) void attn_kernel(
    const bf16* __restrict__ Q, const bf16* __restrict__ Kc, const bf16* __restrict__ Vt,
    bf16* __restrict__ AO) {
  __shared__ __align__(16) bf16 Qs[64 * 64];
  __shared__ __align__(16) bf16 Ks[64 * 64];
  __shared__ __align__(16) bf16 Vs[64 * 64];
  __shared__ __align__(16) bf16 Ps[4][16 * 64];
  const int pairI = blockIdx.x, h = blockIdx.y, b = blockIdx.z;
  const int g = h >> 2;
  const int tid = threadIdx.x, lane = tid & 63, wave = tid >> 6;
  const int l15 = lane & 15, quad = lane >> 4;

  const bf16* kSrc[2]; const bf16* vSrc[2]; bf16* kDst[2]; bf16* vDst[2];
#pragma unroll
  for (int it = 0; it < 2; ++it) {
    int c = it * 256 + tid;
    int r = c >> 3, p = c & 7;
    int kq = p ^ (r & 7);
    kSrc[it] = Kc + (size_t)(b * SEQ + r) * 256 + g * 64 + kq * 8;
    vSrc[it] = Vt + ((size_t)(b * 4 + g) * 64 + r) * SEQ + kq * 8;
    kDst[it] = Ks + (size_t)(it * 256 + wave * 64) * 8;
    vDst[it] = Vs + (size_t)(it * 256 + wave * 64) * 8;
  }

  int qOff[2], kvOff[4][2], pOff[2];
#pragma unroll
  for (int hh = 0; hh < 2; ++hh) {
    int m = wave * 16 + l15;
    qOff[hh] = (m << 6) + (((hh * 4 + quad) ^ (m & 7)) << 3);
#pragma unroll
    for (int j = 0; j < 4; ++j) {
      int n = j * 16 + l15;
      kvOff[j][hh] = (n << 6) + (((hh * 4 + quad) ^ (n & 7)) << 3);
    }
    int cblk = (hh * 2 + (quad >> 1)) ^ (l15 >> 2);
    pOff[hh] = (l15 << 6) + (cblk << 4) + ((quad & 1) << 3);
  }
  bf16* pw = &Ps[wave][0];
  const int rowl = wave * 16 + quad * 4;

  short8 onesb;
#pragma unroll
  for (int e = 0; e < 8; ++e) onesb[e] = (short)0x3F80;

  for (int ph = 0; ph < 2; ++ph) {
    const int q0 = (ph == 0 ? pairI : 31 - pairI) * 64;
    __syncthreads();
#pragma unroll
    for (int it = 0; it < 2; ++it) {
      int c = it * 256 + tid;
      int r = c >> 3, p = c & 7;
      int kq = p ^ (r & 7);
      gld16(Q + (size_t)(b * SEQ + q0 + r) * DM + h * 64 + kq * 8,
            Qs + (size_t)(it * 256 + wave * 64) * 8);
    }

    floatx4 oacc[4], sumacc;
#pragma unroll
    for (int r = 0; r < 4; ++r) { floatx4 z = {0.f, 0.f, 0.f, 0.f}; oacc[r] = z; }
    { floatx4 z = {0.f, 0.f, 0.f, 0.f}; sumacc = z; }

    const int nkt = (q0 >> 6) + 1;
    for (int kt = 0; kt < nkt; ++kt) {
      __syncthreads();
#pragma unroll
      for (int it = 0; it < 2; ++it) {
        gld16(kSrc[it] + (size_t)kt * 64 * 256, kDst[it]);
        gld16(vSrc[it] + kt * 64, vDst[it]);
      }
      __syncthreads();

      floatx4 sacc[4];
#pragma unroll
      for (int j = 0; j < 4; ++j) { floatx4 z = {0.f, 0.f, 0.f, 0.f}; sacc[j] = z; }
#pragma unroll
      for (int hh = 0; hh < 2; ++hh) {
        short8 aq = *(const short8*)(Qs + qOff[hh]);
#pragma unroll
        for (int j = 0; j < 4; ++j)
          sacc[j] = __builtin_amdgcn_mfma_f32_16x16x32_bf16(
              aq, *(const short8*)(Ks + kvOff[j][hh]), sacc[j], 0, 0, 0);
      }

      const bool lastTile = (kt == nkt - 1);
#pragma unroll
      for (int j = 0; j < 4; ++j) {
        int sw = ((j ^ quad) << 4) + l15;
        int colg = j * 16 + l15;
#pragma unroll
        for (int r = 0; r < 4; ++r) {
          float p = __expf(sacc[j][r]);
          if (lastTile && colg > rowl + r) p = 0.f;
          pw[(quad * 4 + r) * 64 + sw] = (bf16)p;
        }
      }
      asm volatile("s_waitcnt lgkmcnt(0)" ::: "memory");
#pragma unroll
      for (int hh = 0; hh < 2; ++hh) {
        short8 ap = *(const short8*)(pw + pOff[hh]);
#pragma unroll
        for (int j = 0; j < 4; ++j)
          oacc[j] = __builtin_amdgcn_mfma_f32_16x16x32_bf16(
              ap, *(const short8*)(Vs + kvOff[j][hh]), oacc[j], 0, 0, 0);
        sumacc = __builtin_amdgcn_mfma_f32_16x16x32_bf16(ap, onesb, sumacc, 0, 0, 0);
      }
    }

    float inv[4];
#pragma unroll
    for (int r = 0; r < 4; ++r) inv[r] = 1.f / sumacc[r];
#pragma unroll
    for (int j = 0; j < 4; ++j)
#pragma unroll
      for (int r = 0; r < 4; ++r) {
        int t = b * SEQ + q0 + rowl + r;
        AO[(size_t)t * DM + h * 64 + j * 16 + l15] = (bf16)(oacc[j][r] * inv[r]);
      }
  }
}

// ------------------------------------------------- capacity assignment (9 blocks)
// blocks 0..7: per-expert compaction; block 8: identity fill for shared slots
__global__ __launch_bounds__(256) void assign_kernel(
    const int* __restrict__ tIdx, const float* __restrict__ tW,
    int* __restrict__ tokList, float* __restrict__ gateW,
    int* __restrict__ neCnt, int* __restrict__ cntFull, int* __restrict__ slotOf) {
  int e = blockIdx.x;
  int tid = threadIdx.x, lane = tid & 63, wv = tid >> 6;
  if (e == 8) {
    for (int t = tid; t < TTOK; t += 256) {
      tokList[NSLOT + t] = t;
      gateW[NSLOT + t] = 1.0f;
    }
    if (tid == 0) neCnt[8] = TTOK;
    return;
  }
  __shared__ int waveTot[4];
  __shared__ int offs;
  if (tid == 0) offs = 0;
  __syncthreads();
  for (int base = 0; base < TTOK; base += 256) {
    int t = base + tid;
    int a = tIdx[t * 2], b2 = tIdx[t * 2 + 1];
    bool sel = (a == e) || (b2 == e);
    unsigned long long mask = __ballot(sel);
    int wrank = __popcll(mask & ((1ull << lane) - 1ull));
    if (lane == 0) waveTot[wv] = __popcll(mask);
    __syncthreads();
    int pre = offs;
    for (int w2 = 0; w2 < wv; ++w2) pre += waveTot[w2];
    int rank = pre + wrank;
    if (sel && rank < CAPT) {
      int slot = e * CAPT + rank;
      tokList[slot] = t;
      gateW[slot] = (a == e) ? tW[t * 2] : tW[t * 2 + 1];
      slotOf[t * 2 + ((a == e) ? 0 : 1)] = slot;
    }
    __syncthreads();
    if (tid == 0) offs += waveTot[0] + waveTot[1] + waveTot[2] + waveTot[3];
    __syncthreads();
  }
  if (tid == 0) {
    cntFull[e] = offs;
    neCnt[e] = offs < CAPT ? offs : CAPT;
  }
}

// ------------------------- combine: out = hbuf + shared eo + <=2 gated eo rows
// Block 0 additionally computes aux loss / util (fused former aux_kernel).
__global__ __launch_bounds__(256) void combine_kernel(
    float* __restrict__ outp, const float* __restrict__ hbuf,
    const bf16* __restrict__ eo, const int* __restrict__ slotOf,
    const float* __restrict__ probs, const int* __restrict__ cntFull,
    float* __restrict__ outAux) {
  int t = blockIdx.x, tid = threadIdx.x;
  float4 v = ((const float4*)(hbuf + (size_t)t * DM))[tid];
  bf4 sh = ((const bf4*)(eo + (size_t)(NSLOT + t) * DM))[tid];
  v.x += (float)sh.x; v.y += (float)sh.y; v.z += (float)sh.z; v.w += (float)sh.w;
  int s0 = slotOf[t * 2], s1 = slotOf[t * 2 + 1];
  if (s0 >= 0) {
    bf4 e = ((const bf4*)(eo + (size_t)s0 * DM))[tid];
    v.x += (float)e.x; v.y += (float)e.y; v.z += (float)e.z; v.w += (float)e.w;
  }
  if (s1 >= 0) {
    bf4 e = ((const bf4*)(eo + (size_t)s1 * DM))[tid];
    v.x += (float)e.x; v.y += (float)e.y; v.z += (float)e.z; v.w += (float)e.w;
  }
  ((float4*)(outp + (size_t)t * DM))[tid] = v;

  if (t == 0) {
    __shared__ float psum[8];
    if (tid < 8) psum[tid] = 0.f;
    __syncthreads();
    float lp[8] = {0, 0, 0, 0, 0, 0, 0, 0};
    for (int tt = tid; tt < TTOK; tt += 256) {
#pragma unroll
      for (int e = 0; e < 8; ++e) lp[e] += probs[tt * 8 + e];
    }
#pragma unroll
    for (int e = 0; e < 8; ++e)
#pragma unroll
      for (int off = 1; off < 64; off <<= 1) lp[e] += __shfl_xor(lp[e], off);
    if ((tid & 63) == 0)
#pragma unroll
      for (int e = 0; e < 8; ++e) atomicAdd(&psum[e], lp[e]);
    __syncthreads();
    if (tid == 0) {
      float aux = 0.f; int used = 0;
      for (int e = 0; e < 8; ++e) {
        aux += (psum[e] / (float)TTOK) * ((float)cntFull[e] / (float)TTOK);
        if (cntFull[e] > 0) used++;
      }
      outAux[0] = 8.f * aux;
      outAux[1] = 100.f * (float)used / 8.f;
    }
  }
}

// ---------------------------------------------------------------- launch
extern "C" void kernel_launch(void* const* d_in, const int* in_sizes, int n_in,
                              void* d_out, int out_size, void* d_ws, size_t ws_size,
                              hipStream_t stream) {
  (void)in_sizes; (void)n_in; (void)out_size; (void)ws_size;
  const float* x     = (const float*)d_in[0];
  const float* cosb  = (const float*)d_in[1];
  const float* sinb  = (const float*)d_in[2];
  const float* attnw = (const float*)d_in[4];
  const float* moew  = (const float*)d_in[5];
  const float* wq  = (const float*)d_in[6];
  const float* wk  = (const float*)d_in[7];
  const float* wv  = (const float*)d_in[8];
  const float* wo  = (const float*)d_in[9];
  const float* rw  = (const float*)d_in[10];
  const float* ew1 = (const float*)d_in[11];
  const float* ew2 = (const float*)d_in[12];
  const float* ew3 = (const float*)d_in[13];
  const float* sw1 = (const float*)d_in[14];
  const float* sw2 = (const float*)d_in[15];
  const float* sw3 = (const float*)d_in[16];

  float* outp = (float*)d_out;
  float* auxp = outp + 4194304;
  float* newk = outp + 4194306;
  float* newv = newk + 1048576;

  char* wsp = (char*)d_ws;
  size_t off = 0;
  auto alloc = [&](size_t bytes) -> void* {
    void* p = wsp + off; off += (bytes + 255) & ~(size_t)255; return p;
  };
  bf16* wqkvT = (bf16*)alloc((size_t)1536 * 1024 * 2);
  bf16* woT   = (bf16*)alloc((size_t)1024 * 1024 * 2);
  bf16* ew1T  = (bf16*)alloc((size_t)9 * HIDDEN * 1024 * 2);   // slice 8 = sw1
  bf16* ew3T  = (bf16*)alloc((size_t)9 * HIDDEN * 1024 * 2);   // slice 8 = sw3
  bf16* ew2T  = (bf16*)alloc((size_t)9 * 1024 * HIDP * 2);     // slice 8 = sw2
  bf16* xn    = (bf16*)alloc((size_t)TTOK * DM * 2);
  bf16* qb    = (bf16*)alloc((size_t)TTOK * DM * 2);
  bf16* kb    = (bf16*)alloc((size_t)TTOK * 256 * 2);
  bf16* vt    = (bf16*)alloc((size_t)TTOK * 256 * 2);
  bf16* ao    = (bf16*)alloc((size_t)TTOK * DM * 2);
  float* hbuf = (float*)alloc((size_t)TTOK * DM * 4);
  bf16* hn    = (bf16*)alloc((size_t)TTOK * DM * 2);
  float* probs = (float*)alloc((size_t)TTOK * 8 * 4);
  int*   tIdx  = (int*)alloc((size_t)TTOK * 2 * 4);
  float* tW    = (float*)alloc((size_t)TTOK * 2 * 4);
  int*   tokList = (int*)alloc((size_t)TSLOT * 4);
  float* gateW   = (float*)alloc((size_t)TSLOT * 4);
  int*   neCnt   = (int*)alloc(64);
  int*   cntFull = (int*)alloc(64);
  int*   slotOf  = (int*)alloc((size_t)TTOK * 2 * 4);
  bf16*  mact = (bf16*)alloc((size_t)TSLOT * HIDP * 2);
  bf16*  eo   = (bf16*)alloc((size_t)TSLOT * DM * 2);

  EpiAux nil{};
  EpiAux ropeAux{cosb, sinb, qb, kb, vt, newk, newv};

  // ---- fused preamble: rmsnorm + all weight transposes in ONE launch
  prep_kernel<<<TTOK + 640 + 22 * 16 * 18 + 16 * 22 * 9, 256, 0, stream>>>(
      x, attnw, xn,
      wq, wk, wv, wo, wqkvT, woT,
      ew1, ew3, sw1, sw3, ew1T, ew3T,
      ew2, sw2, ew2T);

  // ---- attention path (64-row M-tiles; V written pre-transposed by epilogue)
  gemm_bt<4><<<8 * 8 * 12, 256, 0, stream>>>(
      xn, wqkvT, TTOK, 1536, 1024, 1024, 1024, 8, nullptr, 0, nullptr, ropeAux);
  attn_kernel<<<dim3(16, NHEAD, 2), 256, 0, stream>>>(qb, kb, vt, ao);
  gemm_bt<2><<<8 * 8 * 8, 256, 0, stream>>>(
      ao, woT, TTOK, 1024, 1024, 1024, 1024, 8, hbuf, 1024, x, nil);

  // ---- MoE routing (router also inits slotOf = -1; no memset dispatch)
  rmsnorm_router_kernel<<<TTOK, 256, 0, stream>>>(hbuf, moew, rw, hn, probs, tIdx, tW, slotOf);
  assign_kernel<<<9, 256, 0, stream>>>(tIdx, tW, tokList, gateW, neCnt, cntFull, slotOf);

  // ---- experts (8 routed + shared as expert 8)
  gemm_dual9<<<8 * XBT * 11, 256, 0, stream>>>(hn, ew1T, ew3T, mact, tokList, neCnt);
  gemm_down9<<<8 * XBT * 16, 256, 0, stream>>>(mact, ew2T, eo, gateW, neCnt);
  combine_kernel<<<TTOK, 256, 0, stream>>>(outp, hbuf, eo, slotOf, probs, cntFull, auxp);
}